// Round 2
// baseline (5414.125 us; speedup 1.0000x reference)
//
#include <hip/hip_runtime.h>
#include <hip/hip_bf16.h>

// Problem constants
#define BB 4
#define NN 4096
#define DIMM 512
#define HH 8
#define DD 64
#define MM 256
#define LL 16
#define BHH 32
#define NROW (BB*NN)      // 16384
#define KS 33

// ---------------------------------------------------------------------------
// LayerNorm: one block per row of [16384, 512]
__launch_bounds__(256)
__global__ void ln_kernel(const float* __restrict__ x,
                          const float* __restrict__ w,
                          const float* __restrict__ bvec,
                          float* __restrict__ xn) {
    int row = blockIdx.x;
    int t = threadIdx.x;
    const float* xr = x + (long)row * DIMM;
    float v0 = xr[t];
    float v1 = xr[t + 256];
    __shared__ float red[256];
    red[t] = v0 + v1;
    __syncthreads();
    for (int off = 128; off > 0; off >>= 1) { if (t < off) red[t] += red[t + off]; __syncthreads(); }
    float mu = red[0] * (1.0f / DIMM);
    __syncthreads();
    float d0 = v0 - mu, d1 = v1 - mu;
    red[t] = d0 * d0 + d1 * d1;
    __syncthreads();
    for (int off = 128; off > 0; off >>= 1) { if (t < off) red[t] += red[t + off]; __syncthreads(); }
    float var = red[0] * (1.0f / DIMM);
    float rs = rsqrtf(var + 1e-5f);
    xn[(long)row * DIMM + t]       = d0 * rs * w[t]       + bvec[t];
    xn[(long)row * DIMM + t + 256] = d1 * rs * w[t + 256] + bvec[t + 256];
}

// ---------------------------------------------------------------------------
// Generic fp32 tiled GEMM: C[M,N] = alpha * A[M,K] @ B[K,N]  (or B^T as [N,K])
// Block tile 64x64, BK=16, 256 threads, 4x4 per thread. All dims % tile == 0.
enum { EPI_NONE = 0, EPI_QKV = 1, EPI_OUT = 2 };

template<int EPI, bool TRANSB>
__launch_bounds__(256)
__global__ void gemm64(const float* __restrict__ A, const float* __restrict__ Bm,
                       float* __restrict__ C,
                       int M, int N, int K, long sA, long sB, long sC, float alpha,
                       const float* __restrict__ bias,
                       const float* __restrict__ resid,
                       float* __restrict__ qp, float* __restrict__ kp, float* __restrict__ vp) {
    const int bz = blockIdx.z;
    const float* Ab = A + (long)bz * sA;
    const float* Bb = Bm + (long)bz * sB;
    float* Cb = C + (long)bz * sC;

    __shared__ float As[16][64];
    __shared__ float Bs[16][64];

    const int tid = threadIdx.x;
    const int tx = tid & 15;
    const int ty = tid >> 4;
    const int m0 = blockIdx.y * 64;
    const int n0 = blockIdx.x * 64;

    float acc[4][4] = {};

    for (int k0 = 0; k0 < K; k0 += 16) {
        {   // A tile: 64 rows x 16 k
            int r  = tid >> 2;
            int kk = (tid & 3) * 4;
            float4 va = *(const float4*)(Ab + (long)(m0 + r) * K + k0 + kk);
            As[kk + 0][r] = va.x; As[kk + 1][r] = va.y; As[kk + 2][r] = va.z; As[kk + 3][r] = va.w;
        }
        if (!TRANSB) {
            int kk = tid >> 4;
            int j  = (tid & 15) * 4;
            float4 vb = *(const float4*)(Bb + (long)(k0 + kk) * N + n0 + j);
            Bs[kk][j + 0] = vb.x; Bs[kk][j + 1] = vb.y; Bs[kk][j + 2] = vb.z; Bs[kk][j + 3] = vb.w;
        } else {
            int j  = tid >> 2;
            int kk = (tid & 3) * 4;
            float4 vb = *(const float4*)(Bb + (long)(n0 + j) * K + k0 + kk);
            Bs[kk + 0][j] = vb.x; Bs[kk + 1][j] = vb.y; Bs[kk + 2][j] = vb.z; Bs[kk + 3][j] = vb.w;
        }
        __syncthreads();
        #pragma unroll
        for (int kk = 0; kk < 16; ++kk) {
            float a0 = As[kk][ty * 4 + 0], a1 = As[kk][ty * 4 + 1];
            float a2 = As[kk][ty * 4 + 2], a3 = As[kk][ty * 4 + 3];
            float b0 = Bs[kk][tx * 4 + 0], b1 = Bs[kk][tx * 4 + 1];
            float b2 = Bs[kk][tx * 4 + 2], b3 = Bs[kk][tx * 4 + 3];
            acc[0][0] += a0 * b0; acc[0][1] += a0 * b1; acc[0][2] += a0 * b2; acc[0][3] += a0 * b3;
            acc[1][0] += a1 * b0; acc[1][1] += a1 * b1; acc[1][2] += a1 * b2; acc[1][3] += a1 * b3;
            acc[2][0] += a2 * b0; acc[2][1] += a2 * b1; acc[2][2] += a2 * b2; acc[2][3] += a2 * b3;
            acc[3][0] += a3 * b0; acc[3][1] += a3 * b1; acc[3][2] += a3 * b2; acc[3][3] += a3 * b3;
        }
        __syncthreads();
    }

    #pragma unroll
    for (int r = 0; r < 4; ++r) {
        #pragma unroll
        for (int c = 0; c < 4; ++c) {
            int row = m0 + ty * 4 + r;
            int col = n0 + tx * 4 + c;
            float val = acc[r][c] * alpha;
            if (EPI == EPI_NONE) {
                Cb[(long)row * N + col] = val;
            } else if (EPI == EPI_QKV) {
                // row -> (b, i); col in [0,1536) -> (which, h, dd)
                int b = row >> 12, i = row & (NN - 1);
                int which = col >> 9;
                int rem = col & 511;
                int h = rem >> 6, dd = rem & 63;
                long dst = (((long)(b * HH + h) * NN + i) * DD + dd);
                if (which == 0) qp[dst] = val * 0.125f;   // q * DHEAD^-0.5
                else if (which == 1) kp[dst] = val;
                else vp[dst] = val;
            } else { // EPI_OUT
                float o = val + bias[col] + resid[(long)row * N + col];
                C[(long)row * N + col] = o;
            }
        }
    }
}

// ---------------------------------------------------------------------------
// Landmark means: q_l/k_l[bh, m, d] = mean over 16 consecutive seq rows
__global__ void landmark_kernel(const float* __restrict__ qq, const float* __restrict__ kk,
                                float* __restrict__ q_l, float* __restrict__ k_l) {
    int bh = blockIdx.x >> 8;
    int m  = blockIdx.x & 255;
    int d  = threadIdx.x;     // 64
    const float* src = (blockIdx.y ? kk : qq) + ((long)bh * NN + m * LL) * DD + d;
    float s = 0.f;
    #pragma unroll
    for (int t = 0; t < LL; ++t) s += src[(long)t * DD];
    float* dst = blockIdx.y ? k_l : q_l;
    dst[((long)bh * MM + m) * DD + d] = s * (1.0f / LL);
}

// ---------------------------------------------------------------------------
// In-place softmax over rows of length 256 ([32*256, 256])
__launch_bounds__(256)
__global__ void softmax256_kernel(float* __restrict__ a) {
    long row = blockIdx.x;
    int t = threadIdx.x;
    float* r = a + row * 256;
    float v = r[t];
    __shared__ float red[256];
    red[t] = v;
    __syncthreads();
    for (int off = 128; off > 0; off >>= 1) { if (t < off) red[t] = fmaxf(red[t], red[t + off]); __syncthreads(); }
    float mx = red[0];
    __syncthreads();
    float e = __expf(v - mx);
    red[t] = e;
    __syncthreads();
    for (int off = 128; off > 0; off >>= 1) { if (t < off) red[t] += red[t + off]; __syncthreads(); }
    r[t] = e / red[0];
}

// ---------------------------------------------------------------------------
// pinv norm: per-bh max row-sum and max col-sum of a2 (a2 > 0, so |.| = .)
__launch_bounds__(256)
__global__ void redmax_kernel(const float* __restrict__ a2, float* __restrict__ red) {
    int bh = blockIdx.x;
    int t = threadIdx.x;
    const float* Ab = a2 + ((long)bh << 16);
    float rs = 0.f, cs = 0.f;
    for (int c = 0; c < 256; ++c) rs += Ab[t * 256 + c];
    for (int r = 0; r < 256; ++r) cs += Ab[r * 256 + t];
    __shared__ float m1[256], m2[256];
    m1[t] = rs; m2[t] = cs;
    __syncthreads();
    for (int off = 128; off > 0; off >>= 1) {
        if (t < off) { m1[t] = fmaxf(m1[t], m1[t + off]); m2[t] = fmaxf(m2[t], m2[t + off]); }
        __syncthreads();
    }
    if (t == 0) { red[bh] = m1[0]; red[32 + bh] = m2[0]; }
}

__global__ void scale_kernel(const float* __restrict__ red, float* __restrict__ scl) {
    __shared__ float a[32], b[32];
    int t = threadIdx.x;  // 32
    a[t] = red[t]; b[t] = red[32 + t];
    __syncthreads();
    for (int off = 16; off > 0; off >>= 1) {
        if (t < off) { a[t] = fmaxf(a[t], a[t + off]); b[t] = fmaxf(b[t], b[t + off]); }
        __syncthreads();
    }
    if (t == 0) scl[0] = 1.0f / (a[0] * b[0]);
}

// z0 = a2^T * scale (per bh)
__launch_bounds__(256)
__global__ void transpose_scale_kernel(const float* __restrict__ a2, const float* __restrict__ scl,
                                       float* __restrict__ z) {
    int bh = blockIdx.x >> 8;
    int i  = blockIdx.x & 255;
    int j  = threadIdx.x;
    float s = scl[0];
    z[((long)bh << 16) + i * 256 + j] = a2[((long)bh << 16) + j * 256 + i] * s;
}

// Y = alpha*I - X  over [32, 256, 256]
__global__ void ew_aI_minus_kernel(const float* __restrict__ X, float* __restrict__ Y, float alpha) {
    long idx = (long)blockIdx.x * 256 + threadIdx.x;
    int e = (int)(idx & 65535);
    int i = e >> 8, j = e & 255;
    Y[idx] = ((i == j) ? alpha : 0.0f) - X[idx];
}

// ---------------------------------------------------------------------------
// a3v[bh, m, :] = softmax(q_l[bh,m] . k[bh,:]^T) @ v[bh]   (row softmax over n=4096)
__launch_bounds__(256)
__global__ void a3v_kernel(const float* __restrict__ q_l, const float* __restrict__ kk,
                           const float* __restrict__ vv, float* __restrict__ a3v) {
    int m  = blockIdx.x & 255;
    int bh = blockIdx.x >> 8;
    int t  = threadIdx.x;   // 256
    __shared__ __align__(16) float ql[64];
    __shared__ float sc[4096];
    __shared__ float red[256];
    __shared__ float op[256];
    if (t < 64) ql[t] = q_l[((long)bh * MM + m) * DD + t];
    __syncthreads();
    const float4* ql4 = (const float4*)ql;
    float lmax = -1e30f;
    for (int rep = 0; rep < 16; ++rep) {
        int j = t + rep * 256;
        const float4* kr = (const float4*)(kk + ((long)bh * NN + j) * DD);
        float s = 0.f;
        #pragma unroll
        for (int u = 0; u < 16; ++u) {
            float4 a = ql4[u]; float4 b = kr[u];
            s += a.x * b.x + a.y * b.y + a.z * b.z + a.w * b.w;
        }
        sc[j] = s;
        lmax = fmaxf(lmax, s);
    }
    red[t] = lmax;
    __syncthreads();
    for (int off = 128; off > 0; off >>= 1) { if (t < off) red[t] = fmaxf(red[t], red[t + off]); __syncthreads(); }
    float mx = red[0];
    __syncthreads();
    float lsum = 0.f;
    for (int rep = 0; rep < 16; ++rep) {
        int j = t + rep * 256;
        float e = __expf(sc[j] - mx);
        sc[j] = e;
        lsum += e;
    }
    red[t] = lsum;
    __syncthreads();
    for (int off = 128; off > 0; off >>= 1) { if (t < off) red[t] += red[t + off]; __syncthreads(); }
    float inv = 1.0f / red[0];
    __syncthreads();
    int d = t & 63, ch = t >> 6;
    float acc = 0.f;
    const float* vb = vv + ((long)bh * NN) * DD + d;
    for (int j = ch * 1024; j < ch * 1024 + 1024; ++j) acc += sc[j] * vb[(long)j * DD];
    op[t] = acc;
    __syncthreads();
    if (t < 64) {
        float o = (op[t] + op[t + 64] + op[t + 128] + op[t + 192]) * inv;
        a3v[((long)bh * MM + m) * DD + t] = o;
    }
}

// ---------------------------------------------------------------------------
// Per output row: out_i = softmax(q_i . k_l^T) @ w  + depthwise conv(v); write into ctx [b,n,h*d]
__launch_bounds__(128)
__global__ void attn_out_kernel(const float* __restrict__ qq, const float* __restrict__ k_l,
                                const float* __restrict__ wmat, const float* __restrict__ vv,
                                const float* __restrict__ convw, float* __restrict__ ctx) {
    int i  = blockIdx.x;
    int bh = blockIdx.y;
    int b = bh >> 3, h = bh & 7;
    int t = threadIdx.x;   // 128
    __shared__ __align__(16) float qi[64];
    __shared__ float sc[256];
    __shared__ float red[128];
    __shared__ float cw[KS];
    __shared__ float op[128];
    if (t < 64) qi[t] = qq[((long)bh * NN + i) * DD + t];
    if (t >= 64 && t < 64 + KS) cw[t - 64] = convw[h * KS + (t - 64)];
    __syncthreads();
    const float4* q4 = (const float4*)qi;
    float lmax = -1e30f;
    #pragma unroll
    for (int rep = 0; rep < 2; ++rep) {
        int j = t + rep * 128;
        const float4* kr = (const float4*)(k_l + ((long)bh * MM + j) * DD);
        float s = 0.f;
        #pragma unroll
        for (int u = 0; u < 16; ++u) {
            float4 a = q4[u]; float4 bb = kr[u];
            s += a.x * bb.x + a.y * bb.y + a.z * bb.z + a.w * bb.w;
        }
        sc[j] = s;
        lmax = fmaxf(lmax, s);
    }
    red[t] = lmax;
    __syncthreads();
    for (int off = 64; off > 0; off >>= 1) { if (t < off) red[t] = fmaxf(red[t], red[t + off]); __syncthreads(); }
    float mx = red[0];
    __syncthreads();
    float ls = 0.f;
    #pragma unroll
    for (int rep = 0; rep < 2; ++rep) {
        int j = t + rep * 128;
        float e = __expf(sc[j] - mx);
        sc[j] = e;
        ls += e;
    }
    red[t] = ls;
    __syncthreads();
    for (int off = 64; off > 0; off >>= 1) { if (t < off) red[t] += red[t + off]; __syncthreads(); }
    float inv = 1.0f / red[0];
    __syncthreads();
    int d = t & 63, half = t >> 6;
    float acc = 0.f;
    const float* wb = wmat + ((long)bh * MM) * DD + d;
    for (int j = half * 128; j < half * 128 + 128; ++j) acc += sc[j] * wb[(long)j * DD];
    op[t] = acc;
    __syncthreads();
    if (t < 64) {
        float o = (op[t] + op[t + 64]) * inv;
        // fused depthwise conv over seq axis of v
        const float* vb = vv + ((long)bh * NN) * DD + t;
        #pragma unroll
        for (int kkk = 0; kkk < KS; ++kkk) {
            int s2 = i + kkk - KS / 2;
            if (s2 >= 0 && s2 < NN) o += cw[kkk] * vb[(long)s2 * DD];
        }
        ctx[((long)b * NN + i) * DIMM + h * DD + t] = o;
    }
}

// ---------------------------------------------------------------------------
extern "C" void kernel_launch(void* const* d_in, const int* in_sizes, int n_in,
                              void* d_out, int out_size, void* d_ws, size_t ws_size,
                              hipStream_t stream) {
    const float* x      = (const float*)d_in[0];
    const float* norm_w = (const float*)d_in[1];
    const float* norm_b = (const float*)d_in[2];
    const float* Wqkv   = (const float*)d_in[3];
    const float* Wout   = (const float*)d_in[4];
    const float* bout   = (const float*)d_in[5];
    const float* conv_w = (const float*)d_in[6];
    float* out = (float*)d_out;

    float* ws = (float*)d_ws;
    size_t o = 0;
    auto alloc = [&](size_t n) { float* p = ws + o; o += n; return p; };
    float* xn   = alloc((size_t)NROW * DIMM);        // 8.4M floats, reused as ctx later
    float* qq   = alloc((size_t)BHH * NN * DD);      // 8.4M
    float* kk   = alloc((size_t)BHH * NN * DD);      // 8.4M
    float* vv   = alloc((size_t)BHH * NN * DD);      // 8.4M
    float* q_l  = alloc((size_t)BHH * MM * DD);      // 0.5M
    float* k_l  = alloc((size_t)BHH * MM * DD);
    float* a2   = alloc((size_t)BHH * MM * MM);      // 2M
    float* zb   = alloc((size_t)BHH * MM * MM);
    float* az   = alloc((size_t)BHH * MM * MM);
    float* gb   = alloc((size_t)BHH * MM * MM);
    float* tb   = alloc((size_t)BHH * MM * MM);
    float* z2   = alloc((size_t)BHH * MM * MM);
    float* a3v  = alloc((size_t)BHH * MM * DD);
    float* wm   = alloc((size_t)BHH * MM * DD);
    float* red  = alloc(64);
    float* scl  = alloc(64);
    float* ctx  = xn;   // xn dead after QKV GEMM

    // 1. LayerNorm
    ln_kernel<<<NROW, 256, 0, stream>>>(x, norm_w, norm_b, xn);

    // 2. QKV GEMM with scatter epilogue (q scaled by 0.125)
    gemm64<EPI_QKV, false><<<dim3(3 * DIMM / 64, NROW / 64, 1), 256, 0, stream>>>(
        xn, Wqkv, nullptr, NROW, 3 * DIMM, DIMM, 0, 0, 0, 1.0f,
        nullptr, nullptr, qq, kk, vv);

    // 3. Landmarks
    landmark_kernel<<<dim3(BHH * MM, 2), 64, 0, stream>>>(qq, kk, q_l, k_l);

    // 4. sim2 = q_l @ k_l^T  (batched 32, 256x256x64)
    gemm64<EPI_NONE, true><<<dim3(4, 4, BHH), 256, 0, stream>>>(
        q_l, k_l, a2, MM, MM, DD, (long)MM * DD, (long)MM * DD, (long)MM * MM, 1.0f,
        nullptr, nullptr, nullptr, nullptr, nullptr);

    // 5. softmax rows -> a2
    softmax256_kernel<<<BHH * MM, 256, 0, stream>>>(a2);

    // 6-7. pinv normalization scalar
    redmax_kernel<<<BHH, 256, 0, stream>>>(a2, red);
    scale_kernel<<<1, 32, 0, stream>>>(red, scl);

    // 8. z0 = a2^T * scale
    transpose_scale_kernel<<<BHH * MM, 256, 0, stream>>>(a2, scl, zb);

    // 9. Newton-Schulz iterations
    const long sM = (long)MM * MM;
    const int ewBlocks = BHH * MM * MM / 256;
    float* zcur = zb;
    float* znew = z2;
    for (int it = 0; it < 6; ++it) {
        gemm64<EPI_NONE, false><<<dim3(4, 4, BHH), 256, 0, stream>>>(
            a2, zcur, az, MM, MM, MM, sM, sM, sM, 1.0f,
            nullptr, nullptr, nullptr, nullptr, nullptr);
        ew_aI_minus_kernel<<<ewBlocks, 256, 0, stream>>>(az, gb, 7.0f);
        gemm64<EPI_NONE, false><<<dim3(4, 4, BHH), 256, 0, stream>>>(
            az, gb, tb, MM, MM, MM, sM, sM, sM, 1.0f,
            nullptr, nullptr, nullptr, nullptr, nullptr);
        ew_aI_minus_kernel<<<ewBlocks, 256, 0, stream>>>(tb, gb, 15.0f);
        gemm64<EPI_NONE, false><<<dim3(4, 4, BHH), 256, 0, stream>>>(
            az, gb, tb, MM, MM, MM, sM, sM, sM, 1.0f,
            nullptr, nullptr, nullptr, nullptr, nullptr);
        ew_aI_minus_kernel<<<ewBlocks, 256, 0, stream>>>(tb, gb, 13.0f);
        gemm64<EPI_NONE, false><<<dim3(4, 4, BHH), 256, 0, stream>>>(
            zcur, gb, znew, MM, MM, MM, sM, sM, sM, 0.25f,
            nullptr, nullptr, nullptr, nullptr, nullptr);
        float* tmp = zcur; zcur = znew; znew = tmp;
    }
    // zcur == a2_inv

    // 10. a3v = softmax(q_l . k^T) @ v
    a3v_kernel<<<BHH * MM, 256, 0, stream>>>(q_l, kk, vv, a3v);

    // 11. w = a2_inv @ a3v  (batched 32, 256x64x256)
    gemm64<EPI_NONE, false><<<dim3(1, 4, BHH), 256, 0, stream>>>(
        zcur, a3v, wm, MM, DD, MM, sM, (long)MM * DD, (long)MM * DD, 1.0f,
        nullptr, nullptr, nullptr, nullptr, nullptr);

    // 12. out rows + fused conv -> ctx [b, n, h*d]
    attn_out_kernel<<<dim3(NN, BHH), 128, 0, stream>>>(qq, k_l, wm, vv, conv_w, ctx);

    // 13. final: out = x + ctx @ Wout + bout
    gemm64<EPI_OUT, false><<<dim3(DIMM / 64, NROW / 64, 1), 256, 0, stream>>>(
        ctx, Wout, out, NROW, DIMM, DIMM, 0, 0, 0, 1.0f,
        bout, x, nullptr, nullptr, nullptr);
}

// Round 3
// 2990.148 us; speedup vs baseline: 1.8107x; 1.8107x over previous
//
#include <hip/hip_runtime.h>
#include <hip/hip_bf16.h>

// Problem constants
#define BB 4
#define NN 4096
#define DIMM 512
#define HH 8
#define DD 64
#define MM 256
#define LL 16
#define BHH 32
#define NROW (BB*NN)      // 16384
#define KS 33

// ---------------------------------------------------------------------------
// LayerNorm: one block per row of [16384, 512]
__launch_bounds__(256)
__global__ void ln_kernel(const float* __restrict__ x,
                          const float* __restrict__ w,
                          const float* __restrict__ bvec,
                          float* __restrict__ xn) {
    int row = blockIdx.x;
    int t = threadIdx.x;
    const float* xr = x + (long)row * DIMM;
    float v0 = xr[t];
    float v1 = xr[t + 256];
    __shared__ float red[256];
    red[t] = v0 + v1;
    __syncthreads();
    for (int off = 128; off > 0; off >>= 1) { if (t < off) red[t] += red[t + off]; __syncthreads(); }
    float mu = red[0] * (1.0f / DIMM);
    __syncthreads();
    float d0 = v0 - mu, d1 = v1 - mu;
    red[t] = d0 * d0 + d1 * d1;
    __syncthreads();
    for (int off = 128; off > 0; off >>= 1) { if (t < off) red[t] += red[t + off]; __syncthreads(); }
    float var = red[0] * (1.0f / DIMM);
    float rs = rsqrtf(var + 1e-5f);
    xn[(long)row * DIMM + t]       = d0 * rs * w[t]       + bvec[t];
    xn[(long)row * DIMM + t + 256] = d1 * rs * w[t + 256] + bvec[t + 256];
}

// ---------------------------------------------------------------------------
// Generic fp32 tiled GEMM: C[M,N] = alpha * A[M,K] @ B[K,N]  (or B^T as [N,K])
// Block tile 64x64, BK=16, 256 threads, 4x4 per thread. All dims % tile == 0.
enum { EPI_NONE = 0, EPI_QKV = 1, EPI_OUT = 2 };

template<int EPI, bool TRANSB>
__launch_bounds__(256)
__global__ void gemm64(const float* __restrict__ A, const float* __restrict__ Bm,
                       float* __restrict__ C,
                       int M, int N, int K, long sA, long sB, long sC, float alpha,
                       const float* __restrict__ bias,
                       const float* __restrict__ resid,
                       float* __restrict__ qp, float* __restrict__ kp, float* __restrict__ vp) {
    const int bz = blockIdx.z;
    const float* Ab = A + (long)bz * sA;
    const float* Bb = Bm + (long)bz * sB;
    float* Cb = C + (long)bz * sC;

    __shared__ float As[16][64];
    __shared__ float Bs[16][64];

    const int tid = threadIdx.x;
    const int tx = tid & 15;
    const int ty = tid >> 4;
    const int m0 = blockIdx.y * 64;
    const int n0 = blockIdx.x * 64;

    float acc[4][4] = {};

    for (int k0 = 0; k0 < K; k0 += 16) {
        {   // A tile: 64 rows x 16 k
            int r  = tid >> 2;
            int kk = (tid & 3) * 4;
            float4 va = *(const float4*)(Ab + (long)(m0 + r) * K + k0 + kk);
            As[kk + 0][r] = va.x; As[kk + 1][r] = va.y; As[kk + 2][r] = va.z; As[kk + 3][r] = va.w;
        }
        if (!TRANSB) {
            int kk = tid >> 4;
            int j  = (tid & 15) * 4;
            float4 vb = *(const float4*)(Bb + (long)(k0 + kk) * N + n0 + j);
            Bs[kk][j + 0] = vb.x; Bs[kk][j + 1] = vb.y; Bs[kk][j + 2] = vb.z; Bs[kk][j + 3] = vb.w;
        } else {
            int j  = tid >> 2;
            int kk = (tid & 3) * 4;
            float4 vb = *(const float4*)(Bb + (long)(n0 + j) * K + k0 + kk);
            Bs[kk + 0][j] = vb.x; Bs[kk + 1][j] = vb.y; Bs[kk + 2][j] = vb.z; Bs[kk + 3][j] = vb.w;
        }
        __syncthreads();
        #pragma unroll
        for (int kk = 0; kk < 16; ++kk) {
            float a0 = As[kk][ty * 4 + 0], a1 = As[kk][ty * 4 + 1];
            float a2 = As[kk][ty * 4 + 2], a3 = As[kk][ty * 4 + 3];
            float b0 = Bs[kk][tx * 4 + 0], b1 = Bs[kk][tx * 4 + 1];
            float b2 = Bs[kk][tx * 4 + 2], b3 = Bs[kk][tx * 4 + 3];
            acc[0][0] += a0 * b0; acc[0][1] += a0 * b1; acc[0][2] += a0 * b2; acc[0][3] += a0 * b3;
            acc[1][0] += a1 * b0; acc[1][1] += a1 * b1; acc[1][2] += a1 * b2; acc[1][3] += a1 * b3;
            acc[2][0] += a2 * b0; acc[2][1] += a2 * b1; acc[2][2] += a2 * b2; acc[2][3] += a2 * b3;
            acc[3][0] += a3 * b0; acc[3][1] += a3 * b1; acc[3][2] += a3 * b2; acc[3][3] += a3 * b3;
        }
        __syncthreads();
    }

    #pragma unroll
    for (int r = 0; r < 4; ++r) {
        #pragma unroll
        for (int c = 0; c < 4; ++c) {
            int row = m0 + ty * 4 + r;
            int col = n0 + tx * 4 + c;
            float val = acc[r][c] * alpha;
            if (EPI == EPI_NONE) {
                Cb[(long)row * N + col] = val;
            } else if (EPI == EPI_QKV) {
                // row -> (b, i); col in [0,1536) -> (which, h, dd)
                int b = row >> 12, i = row & (NN - 1);
                int which = col >> 9;
                int rem = col & 511;
                int h = rem >> 6, dd = rem & 63;
                long dst = (((long)(b * HH + h) * NN + i) * DD + dd);
                if (which == 0) qp[dst] = val * 0.125f;   // q * DHEAD^-0.5
                else if (which == 1) kp[dst] = val;
                else vp[dst] = val;
            } else { // EPI_OUT
                float o = val + bias[col] + resid[(long)row * N + col];
                C[(long)row * N + col] = o;
            }
        }
    }
}

// ---------------------------------------------------------------------------
// Landmark means: q_l/k_l[bh, m, d] = mean over 16 consecutive seq rows
__global__ void landmark_kernel(const float* __restrict__ qq, const float* __restrict__ kk,
                                float* __restrict__ q_l, float* __restrict__ k_l) {
    int bh = blockIdx.x >> 8;
    int m  = blockIdx.x & 255;
    int d  = threadIdx.x;     // 64
    const float* src = (blockIdx.y ? kk : qq) + ((long)bh * NN + m * LL) * DD + d;
    float s = 0.f;
    #pragma unroll
    for (int t = 0; t < LL; ++t) s += src[(long)t * DD];
    float* dst = blockIdx.y ? k_l : q_l;
    dst[((long)bh * MM + m) * DD + d] = s * (1.0f / LL);
}

// ---------------------------------------------------------------------------
// In-place softmax over rows of length 256 ([32*256, 256])
__launch_bounds__(256)
__global__ void softmax256_kernel(float* __restrict__ a) {
    long row = blockIdx.x;
    int t = threadIdx.x;
    float* r = a + row * 256;
    float v = r[t];
    __shared__ float red[256];
    red[t] = v;
    __syncthreads();
    for (int off = 128; off > 0; off >>= 1) { if (t < off) red[t] = fmaxf(red[t], red[t + off]); __syncthreads(); }
    float mx = red[0];
    __syncthreads();
    float e = __expf(v - mx);
    red[t] = e;
    __syncthreads();
    for (int off = 128; off > 0; off >>= 1) { if (t < off) red[t] += red[t + off]; __syncthreads(); }
    r[t] = e / red[0];
}

// ---------------------------------------------------------------------------
// pinv norm: per-bh max row-sum and max col-sum of a2 (a2 > 0, so |.| = .)
__launch_bounds__(256)
__global__ void redmax_kernel(const float* __restrict__ a2, float* __restrict__ red) {
    int bh = blockIdx.x;
    int t = threadIdx.x;
    const float* Ab = a2 + ((long)bh << 16);
    float rs = 0.f, cs = 0.f;
    for (int c = 0; c < 256; ++c) rs += Ab[t * 256 + c];
    for (int r = 0; r < 256; ++r) cs += Ab[r * 256 + t];
    __shared__ float m1[256], m2[256];
    m1[t] = rs; m2[t] = cs;
    __syncthreads();
    for (int off = 128; off > 0; off >>= 1) {
        if (t < off) { m1[t] = fmaxf(m1[t], m1[t + off]); m2[t] = fmaxf(m2[t], m2[t + off]); }
        __syncthreads();
    }
    if (t == 0) { red[bh] = m1[0]; red[32 + bh] = m2[0]; }
}

__global__ void scale_kernel(const float* __restrict__ red, float* __restrict__ scl) {
    __shared__ float a[32], b[32];
    int t = threadIdx.x;  // 32
    a[t] = red[t]; b[t] = red[32 + t];
    __syncthreads();
    for (int off = 16; off > 0; off >>= 1) {
        if (t < off) { a[t] = fmaxf(a[t], a[t + off]); b[t] = fmaxf(b[t], b[t + off]); }
        __syncthreads();
    }
    if (t == 0) scl[0] = 1.0f / (a[0] * b[0]);
}

// z0 = a2^T * scale (per bh)
__launch_bounds__(256)
__global__ void transpose_scale_kernel(const float* __restrict__ a2, const float* __restrict__ scl,
                                       float* __restrict__ z) {
    int bh = blockIdx.x >> 8;
    int i  = blockIdx.x & 255;
    int j  = threadIdx.x;
    float s = scl[0];
    z[((long)bh << 16) + i * 256 + j] = a2[((long)bh << 16) + j * 256 + i] * s;
}

// Y = alpha*I - X  over [32, 256, 256]
__global__ void ew_aI_minus_kernel(const float* __restrict__ X, float* __restrict__ Y, float alpha) {
    long idx = (long)blockIdx.x * 256 + threadIdx.x;
    int e = (int)(idx & 65535);
    int i = e >> 8, j = e & 255;
    Y[idx] = ((i == j) ? alpha : 0.0f) - X[idx];
}

// ---------------------------------------------------------------------------
// a3v flash-style, stage 1.
// Scores sim3 = q_l . k have |.| ~ 1 (q pre-scaled by 1/8, q_l a 16-row mean),
// so exp() cannot overflow -> skip max subtraction; softmax partials are then
// plain sums: numerator O_p = exp(S_chunk) @ V_chunk, denominator l_p.
// Block: 64 landmark rows (mt) x 1024 seq positions (ns). 4x4 regs/thread.
__launch_bounds__(256)
__global__ void a3v_flash(const float* __restrict__ q_l, const float* __restrict__ kk,
                          const float* __restrict__ vv,
                          float* __restrict__ opart, float* __restrict__ lpart) {
    const int bh = blockIdx.y;
    const int mt = blockIdx.x >> 2;
    const int ns = blockIdx.x & 3;
    const int t  = threadIdx.x;
    const int tx = t & 15;
    const int ty = t >> 4;

    __shared__ float qs[64][64];   // q^T: qs[d][r]
    __shared__ float Ks[64][64];   // K^T: Ks[d][c]
    __shared__ float Vs[64][64];   // V natural: Vs[c][d]
    __shared__ float Ps[64][64];   // P natural: Ps[r][c]
    __shared__ float lred[64][16];

    // load q tile (64 rows) transposed into LDS, once
    const float* qbase = q_l + ((long)bh * MM + mt * 64) * DD;
    #pragma unroll
    for (int i = 0; i < 4; ++i) {
        int idx4 = t + 256 * i;
        int r = idx4 >> 4, d4 = (idx4 & 15) << 2;
        float4 v4 = *(const float4*)(qbase + r * DD + d4);
        qs[d4 + 0][r] = v4.x; qs[d4 + 1][r] = v4.y; qs[d4 + 2][r] = v4.z; qs[d4 + 3][r] = v4.w;
    }

    float acc_o[4][4] = {};
    float lacc[4] = {};
    const float* kbase = kk + ((long)bh * NN + ns * 1024) * DD;
    const float* vbase = vv + ((long)bh * NN + ns * 1024) * DD;
    __syncthreads();

    for (int ch = 0; ch < 16; ++ch) {
        // stage K chunk (transposed) and V chunk (natural)
        #pragma unroll
        for (int i = 0; i < 4; ++i) {
            int idx4 = t + 256 * i;
            int c = idx4 >> 4, d4 = (idx4 & 15) << 2;
            float4 kv = *(const float4*)(kbase + (long)(ch * 64 + c) * DD + d4);
            float4 vv4 = *(const float4*)(vbase + (long)(ch * 64 + c) * DD + d4);
            Ks[d4 + 0][c] = kv.x; Ks[d4 + 1][c] = kv.y; Ks[d4 + 2][c] = kv.z; Ks[d4 + 3][c] = kv.w;
            *(float4*)&Vs[c][d4] = vv4;
        }
        __syncthreads();

        // S = q @ K^T  (64x64), 4x4 per thread
        float s[4][4] = {};
        #pragma unroll 16
        for (int d = 0; d < 64; ++d) {
            float a0 = qs[d][ty * 4 + 0], a1 = qs[d][ty * 4 + 1];
            float a2 = qs[d][ty * 4 + 2], a3 = qs[d][ty * 4 + 3];
            float b0 = Ks[d][tx * 4 + 0], b1 = Ks[d][tx * 4 + 1];
            float b2 = Ks[d][tx * 4 + 2], b3 = Ks[d][tx * 4 + 3];
            s[0][0] += a0 * b0; s[0][1] += a0 * b1; s[0][2] += a0 * b2; s[0][3] += a0 * b3;
            s[1][0] += a1 * b0; s[1][1] += a1 * b1; s[1][2] += a1 * b2; s[1][3] += a1 * b3;
            s[2][0] += a2 * b0; s[2][1] += a2 * b1; s[2][2] += a2 * b2; s[2][3] += a2 * b3;
            s[3][0] += a3 * b0; s[3][1] += a3 * b1; s[3][2] += a3 * b2; s[3][3] += a3 * b3;
        }
        // P = exp(S); accumulate denominator; stash P in LDS (natural, float4 rows)
        #pragma unroll
        for (int i = 0; i < 4; ++i) {
            float e0 = __expf(s[i][0]), e1 = __expf(s[i][1]);
            float e2 = __expf(s[i][2]), e3 = __expf(s[i][3]);
            lacc[i] += e0 + e1 + e2 + e3;
            float4 p4; p4.x = e0; p4.y = e1; p4.z = e2; p4.w = e3;
            *(float4*)&Ps[ty * 4 + i][tx * 4] = p4;
        }
        __syncthreads();

        // O += P @ V  (64 rows x 64 dims), 4x4 per thread
        #pragma unroll 16
        for (int c = 0; c < 64; ++c) {
            float a0 = Ps[ty * 4 + 0][c], a1 = Ps[ty * 4 + 1][c];
            float a2 = Ps[ty * 4 + 2][c], a3 = Ps[ty * 4 + 3][c];
            float b0 = Vs[c][tx * 4 + 0], b1 = Vs[c][tx * 4 + 1];
            float b2 = Vs[c][tx * 4 + 2], b3 = Vs[c][tx * 4 + 3];
            acc_o[0][0] += a0 * b0; acc_o[0][1] += a0 * b1; acc_o[0][2] += a0 * b2; acc_o[0][3] += a0 * b3;
            acc_o[1][0] += a1 * b0; acc_o[1][1] += a1 * b1; acc_o[1][2] += a1 * b2; acc_o[1][3] += a1 * b3;
            acc_o[2][0] += a2 * b0; acc_o[2][1] += a2 * b1; acc_o[2][2] += a2 * b2; acc_o[2][3] += a2 * b3;
            acc_o[3][0] += a3 * b0; acc_o[3][1] += a3 * b1; acc_o[3][2] += a3 * b2; acc_o[3][3] += a3 * b3;
        }
        __syncthreads();
    }

    // write partials
    const long pbase = ((long)((bh * 4 + mt) * 4 + ns)) << 12;
    #pragma unroll
    for (int i = 0; i < 4; ++i) {
        float4 w4; w4.x = acc_o[i][0]; w4.y = acc_o[i][1]; w4.z = acc_o[i][2]; w4.w = acc_o[i][3];
        *(float4*)(opart + pbase + (ty * 4 + i) * 64 + tx * 4) = w4;
        lred[ty * 4 + i][tx] = lacc[i];
    }
    __syncthreads();
    if (t < 64) {
        float sum = 0.f;
        #pragma unroll
        for (int u = 0; u < 16; ++u) sum += lred[t][u];
        lpart[((bh * 4 + mt) * 4 + ns) * 64 + t] = sum;
    }
}

// stage 2: combine 4 n-split partials
__global__ void a3v_combine(const float* __restrict__ opart, const float* __restrict__ lpart,
                            float* __restrict__ a3v) {
    int idx = blockIdx.x * 256 + threadIdx.x;  // 524288 total
    int d  = idx & 63;
    int m  = (idx >> 6) & 255;
    int bh = idx >> 14;
    int mt = m >> 6, r = m & 63;
    int pb = (bh * 4 + mt) * 4;
    float osum = 0.f, lsum = 0.f;
    #pragma unroll
    for (int ns = 0; ns < 4; ++ns) {
        osum += opart[(((long)(pb + ns)) << 12) + r * 64 + d];
        lsum += lpart[(pb + ns) * 64 + r];
    }
    a3v[((long)bh * MM + m) * DD + d] = osum / lsum;
}

// ---------------------------------------------------------------------------
// Per output row: out_i = softmax(q_i . k_l^T) @ w  + depthwise conv(v); write into ctx [b,n,h*d]
__launch_bounds__(128)
__global__ void attn_out_kernel(const float* __restrict__ qq, const float* __restrict__ k_l,
                                const float* __restrict__ wmat, const float* __restrict__ vv,
                                const float* __restrict__ convw, float* __restrict__ ctx) {
    int i  = blockIdx.x;
    int bh = blockIdx.y;
    int b = bh >> 3, h = bh & 7;
    int t = threadIdx.x;   // 128
    __shared__ __align__(16) float qi[64];
    __shared__ float sc[256];
    __shared__ float red[128];
    __shared__ float cw[KS];
    __shared__ float op[128];
    if (t < 64) qi[t] = qq[((long)bh * NN + i) * DD + t];
    if (t >= 64 && t < 64 + KS) cw[t - 64] = convw[h * KS + (t - 64)];
    __syncthreads();
    const float4* q4 = (const float4*)qi;
    float lmax = -1e30f;
    #pragma unroll
    for (int rep = 0; rep < 2; ++rep) {
        int j = t + rep * 128;
        const float4* kr = (const float4*)(k_l + ((long)bh * MM + j) * DD);
        float s = 0.f;
        #pragma unroll
        for (int u = 0; u < 16; ++u) {
            float4 a = q4[u]; float4 bb = kr[u];
            s += a.x * bb.x + a.y * bb.y + a.z * bb.z + a.w * bb.w;
        }
        sc[j] = s;
        lmax = fmaxf(lmax, s);
    }
    red[t] = lmax;
    __syncthreads();
    for (int off = 64; off > 0; off >>= 1) { if (t < off) red[t] = fmaxf(red[t], red[t + off]); __syncthreads(); }
    float mx = red[0];
    __syncthreads();
    float ls = 0.f;
    #pragma unroll
    for (int rep = 0; rep < 2; ++rep) {
        int j = t + rep * 128;
        float e = __expf(sc[j] - mx);
        sc[j] = e;
        ls += e;
    }
    red[t] = ls;
    __syncthreads();
    for (int off = 64; off > 0; off >>= 1) { if (t < off) red[t] += red[t + off]; __syncthreads(); }
    float inv = 1.0f / red[0];
    __syncthreads();
    int d = t & 63, half = t >> 6;
    float acc = 0.f;
    const float* wb = wmat + ((long)bh * MM) * DD + d;
    for (int j = half * 128; j < half * 128 + 128; ++j) acc += sc[j] * wb[(long)j * DD];
    op[t] = acc;
    __syncthreads();
    if (t < 64) {
        float o = (op[t] + op[t + 64]) * inv;
        // fused depthwise conv over seq axis of v
        const float* vb = vv + ((long)bh * NN) * DD + t;
        #pragma unroll
        for (int kkk = 0; kkk < KS; ++kkk) {
            int s2 = i + kkk - KS / 2;
            if (s2 >= 0 && s2 < NN) o += cw[kkk] * vb[(long)s2 * DD];
        }
        ctx[((long)b * NN + i) * DIMM + h * DD + t] = o;
    }
}

// ---------------------------------------------------------------------------
extern "C" void kernel_launch(void* const* d_in, const int* in_sizes, int n_in,
                              void* d_out, int out_size, void* d_ws, size_t ws_size,
                              hipStream_t stream) {
    const float* x      = (const float*)d_in[0];
    const float* norm_w = (const float*)d_in[1];
    const float* norm_b = (const float*)d_in[2];
    const float* Wqkv   = (const float*)d_in[3];
    const float* Wout   = (const float*)d_in[4];
    const float* bout   = (const float*)d_in[5];
    const float* conv_w = (const float*)d_in[6];
    float* out = (float*)d_out;

    float* ws = (float*)d_ws;
    size_t o = 0;
    auto alloc = [&](size_t n) { float* p = ws + o; o += n; return p; };
    float* xn   = alloc((size_t)NROW * DIMM);        // reused as ctx later
    float* qq   = alloc((size_t)BHH * NN * DD);
    float* kk   = alloc((size_t)BHH * NN * DD);
    float* vv   = alloc((size_t)BHH * NN * DD);
    float* q_l  = alloc((size_t)BHH * MM * DD);
    float* k_l  = alloc((size_t)BHH * MM * DD);
    float* a2   = alloc((size_t)BHH * MM * MM);
    float* zb   = alloc((size_t)BHH * MM * MM);
    float* az   = alloc((size_t)BHH * MM * MM);
    float* gb   = alloc((size_t)BHH * MM * MM);
    float* tb   = alloc((size_t)BHH * MM * MM);
    float* z2   = alloc((size_t)BHH * MM * MM);
    float* a3v  = alloc((size_t)BHH * MM * DD);
    float* wm   = alloc((size_t)BHH * MM * DD);
    float* opart = alloc((size_t)BHH * 4 * 4 * 64 * 64);   // 2.1M floats
    float* lpart = alloc((size_t)BHH * 4 * 4 * 64);
    float* red  = alloc(64);
    float* scl  = alloc(64);
    float* ctx  = xn;   // xn dead after QKV GEMM

    // 1. LayerNorm
    ln_kernel<<<NROW, 256, 0, stream>>>(x, norm_w, norm_b, xn);

    // 2. QKV GEMM with scatter epilogue (q scaled by 0.125)
    gemm64<EPI_QKV, false><<<dim3(3 * DIMM / 64, NROW / 64, 1), 256, 0, stream>>>(
        xn, Wqkv, nullptr, NROW, 3 * DIMM, DIMM, 0, 0, 0, 1.0f,
        nullptr, nullptr, qq, kk, vv);

    // 3. Landmarks
    landmark_kernel<<<dim3(BHH * MM, 2), 64, 0, stream>>>(qq, kk, q_l, k_l);

    // 4. sim2 = q_l @ k_l^T  (batched 32, 256x256x64)
    gemm64<EPI_NONE, true><<<dim3(4, 4, BHH), 256, 0, stream>>>(
        q_l, k_l, a2, MM, MM, DD, (long)MM * DD, (long)MM * DD, (long)MM * MM, 1.0f,
        nullptr, nullptr, nullptr, nullptr, nullptr);

    // 5. softmax rows -> a2
    softmax256_kernel<<<BHH * MM, 256, 0, stream>>>(a2);

    // 6-7. pinv normalization scalar
    redmax_kernel<<<BHH, 256, 0, stream>>>(a2, red);
    scale_kernel<<<1, 32, 0, stream>>>(red, scl);

    // 8. z0 = a2^T * scale
    transpose_scale_kernel<<<BHH * MM, 256, 0, stream>>>(a2, scl, zb);

    // 9. Newton-Schulz iterations
    const long sM = (long)MM * MM;
    const int ewBlocks = BHH * MM * MM / 256;
    float* zcur = zb;
    float* znew = z2;
    for (int it = 0; it < 6; ++it) {
        gemm64<EPI_NONE, false><<<dim3(4, 4, BHH), 256, 0, stream>>>(
            a2, zcur, az, MM, MM, MM, sM, sM, sM, 1.0f,
            nullptr, nullptr, nullptr, nullptr, nullptr);
        ew_aI_minus_kernel<<<ewBlocks, 256, 0, stream>>>(az, gb, 7.0f);
        gemm64<EPI_NONE, false><<<dim3(4, 4, BHH), 256, 0, stream>>>(
            az, gb, tb, MM, MM, MM, sM, sM, sM, 1.0f,
            nullptr, nullptr, nullptr, nullptr, nullptr);
        ew_aI_minus_kernel<<<ewBlocks, 256, 0, stream>>>(tb, gb, 15.0f);
        gemm64<EPI_NONE, false><<<dim3(4, 4, BHH), 256, 0, stream>>>(
            az, gb, tb, MM, MM, MM, sM, sM, sM, 1.0f,
            nullptr, nullptr, nullptr, nullptr, nullptr);
        ew_aI_minus_kernel<<<ewBlocks, 256, 0, stream>>>(tb, gb, 13.0f);
        gemm64<EPI_NONE, false><<<dim3(4, 4, BHH), 256, 0, stream>>>(
            zcur, gb, znew, MM, MM, MM, sM, sM, sM, 0.25f,
            nullptr, nullptr, nullptr, nullptr, nullptr);
        float* tmp = zcur; zcur = znew; znew = tmp;
    }
    // zcur == a2_inv

    // 10. a3v = softmax(q_l . k^T) @ v   (flash-style, no max subtraction)
    a3v_flash<<<dim3(16, BHH), 256, 0, stream>>>(q_l, kk, vv, opart, lpart);
    a3v_combine<<<BHH * MM * DD / 256, 256, 0, stream>>>(opart, lpart, a3v);

    // 11. w = a2_inv @ a3v  (batched 32, 256x64x256)
    gemm64<EPI_NONE, false><<<dim3(1, 4, BHH), 256, 0, stream>>>(
        zcur, a3v, wm, MM, DD, MM, sM, (long)MM * DD, (long)MM * DD, 1.0f,
        nullptr, nullptr, nullptr, nullptr, nullptr);

    // 12. out rows + fused conv -> ctx [b, n, h*d]
    attn_out_kernel<<<dim3(NN, BHH), 128, 0, stream>>>(qq, k_l, wm, vv, conv_w, ctx);

    // 13. final: out = x + ctx @ Wout + bout
    gemm64<EPI_OUT, false><<<dim3(DIMM / 64, NROW / 64, 1), 256, 0, stream>>>(
        ctx, Wout, out, NROW, DIMM, DIMM, 0, 0, 0, 1.0f,
        bout, x, nullptr, nullptr, nullptr);
}

// Round 4
// 1759.057 us; speedup vs baseline: 3.0779x; 1.6999x over previous
//
#include <hip/hip_runtime.h>
#include <hip/hip_bf16.h>

// Problem constants
#define BB 4
#define NN 4096
#define DIMM 512
#define HH 8
#define DD 64
#define MM 256
#define LL 16
#define BHH 32
#define NROW (BB*NN)      // 16384
#define KS 33

// ---------------------------------------------------------------------------
// LayerNorm: one block per row of [16384, 512]
__launch_bounds__(256)
__global__ void ln_kernel(const float* __restrict__ x,
                          const float* __restrict__ w,
                          const float* __restrict__ bvec,
                          float* __restrict__ xn) {
    int row = blockIdx.x;
    int t = threadIdx.x;
    const float* xr = x + (long)row * DIMM;
    float v0 = xr[t];
    float v1 = xr[t + 256];
    __shared__ float red[256];
    red[t] = v0 + v1;
    __syncthreads();
    for (int off = 128; off > 0; off >>= 1) { if (t < off) red[t] += red[t + off]; __syncthreads(); }
    float mu = red[0] * (1.0f / DIMM);
    __syncthreads();
    float d0 = v0 - mu, d1 = v1 - mu;
    red[t] = d0 * d0 + d1 * d1;
    __syncthreads();
    for (int off = 128; off > 0; off >>= 1) { if (t < off) red[t] += red[t + off]; __syncthreads(); }
    float var = red[0] * (1.0f / DIMM);
    float rs = rsqrtf(var + 1e-5f);
    xn[(long)row * DIMM + t]       = d0 * rs * w[t]       + bvec[t];
    xn[(long)row * DIMM + t + 256] = d1 * rs * w[t + 256] + bvec[t + 256];
}

// ---------------------------------------------------------------------------
// Generic fp32 tiled GEMM: C[M,N] = alpha * A[M,K] @ B[K,N]  (or B^T as [N,K])
// Block tile 64x64, BK=16, 256 threads, 4x4 per thread. All dims % tile == 0.
enum { EPI_NONE = 0, EPI_QKV = 1, EPI_OUT = 2 };

template<int EPI, bool TRANSB>
__launch_bounds__(256)
__global__ void gemm64(const float* __restrict__ A, const float* __restrict__ Bm,
                       float* __restrict__ C,
                       int M, int N, int K, long sA, long sB, long sC, float alpha,
                       const float* __restrict__ bias,
                       const float* __restrict__ resid,
                       float* __restrict__ qp, float* __restrict__ kp, float* __restrict__ vp) {
    const int bz = blockIdx.z;
    const float* Ab = A + (long)bz * sA;
    const float* Bb = Bm + (long)bz * sB;
    float* Cb = C + (long)bz * sC;

    __shared__ float As[16][64];
    __shared__ float Bs[16][64];

    const int tid = threadIdx.x;
    const int tx = tid & 15;
    const int ty = tid >> 4;
    const int m0 = blockIdx.y * 64;
    const int n0 = blockIdx.x * 64;

    float acc[4][4] = {};

    for (int k0 = 0; k0 < K; k0 += 16) {
        {   // A tile: 64 rows x 16 k
            int r  = tid >> 2;
            int kk = (tid & 3) * 4;
            float4 va = *(const float4*)(Ab + (long)(m0 + r) * K + k0 + kk);
            As[kk + 0][r] = va.x; As[kk + 1][r] = va.y; As[kk + 2][r] = va.z; As[kk + 3][r] = va.w;
        }
        if (!TRANSB) {
            int kk = tid >> 4;
            int j  = (tid & 15) * 4;
            float4 vb = *(const float4*)(Bb + (long)(k0 + kk) * N + n0 + j);
            Bs[kk][j + 0] = vb.x; Bs[kk][j + 1] = vb.y; Bs[kk][j + 2] = vb.z; Bs[kk][j + 3] = vb.w;
        } else {
            int j  = tid >> 2;
            int kk = (tid & 3) * 4;
            float4 vb = *(const float4*)(Bb + (long)(n0 + j) * K + k0 + kk);
            Bs[kk + 0][j] = vb.x; Bs[kk + 1][j] = vb.y; Bs[kk + 2][j] = vb.z; Bs[kk + 3][j] = vb.w;
        }
        __syncthreads();
        #pragma unroll
        for (int kk = 0; kk < 16; ++kk) {
            float a0 = As[kk][ty * 4 + 0], a1 = As[kk][ty * 4 + 1];
            float a2 = As[kk][ty * 4 + 2], a3 = As[kk][ty * 4 + 3];
            float b0 = Bs[kk][tx * 4 + 0], b1 = Bs[kk][tx * 4 + 1];
            float b2 = Bs[kk][tx * 4 + 2], b3 = Bs[kk][tx * 4 + 3];
            acc[0][0] += a0 * b0; acc[0][1] += a0 * b1; acc[0][2] += a0 * b2; acc[0][3] += a0 * b3;
            acc[1][0] += a1 * b0; acc[1][1] += a1 * b1; acc[1][2] += a1 * b2; acc[1][3] += a1 * b3;
            acc[2][0] += a2 * b0; acc[2][1] += a2 * b1; acc[2][2] += a2 * b2; acc[2][3] += a2 * b3;
            acc[3][0] += a3 * b0; acc[3][1] += a3 * b1; acc[3][2] += a3 * b2; acc[3][3] += a3 * b3;
        }
        __syncthreads();
    }

    #pragma unroll
    for (int r = 0; r < 4; ++r) {
        #pragma unroll
        for (int c = 0; c < 4; ++c) {
            int row = m0 + ty * 4 + r;
            int col = n0 + tx * 4 + c;
            float val = acc[r][c] * alpha;
            if (EPI == EPI_NONE) {
                Cb[(long)row * N + col] = val;
            } else if (EPI == EPI_QKV) {
                // row -> (b, i); col in [0,1536) -> (which, h, dd)
                int b = row >> 12, i = row & (NN - 1);
                int which = col >> 9;
                int rem = col & 511;
                int h = rem >> 6, dd = rem & 63;
                long dst = (((long)(b * HH + h) * NN + i) * DD + dd);
                if (which == 0) qp[dst] = val * 0.125f;   // q * DHEAD^-0.5
                else if (which == 1) kp[dst] = val;
                else vp[dst] = val;
            } else { // EPI_OUT
                float o = val + bias[col] + resid[(long)row * N + col];
                C[(long)row * N + col] = o;
            }
        }
    }
}

// ---------------------------------------------------------------------------
// Landmark means: q_l/k_l[bh, m, d] = mean over 16 consecutive seq rows
__global__ void landmark_kernel(const float* __restrict__ qq, const float* __restrict__ kk,
                                float* __restrict__ q_l, float* __restrict__ k_l) {
    int bh = blockIdx.x >> 8;
    int m  = blockIdx.x & 255;
    int d  = threadIdx.x;     // 64
    const float* src = (blockIdx.y ? kk : qq) + ((long)bh * NN + m * LL) * DD + d;
    float s = 0.f;
    #pragma unroll
    for (int t = 0; t < LL; ++t) s += src[(long)t * DD];
    float* dst = blockIdx.y ? k_l : q_l;
    dst[((long)bh * MM + m) * DD + d] = s * (1.0f / LL);
}

// ---------------------------------------------------------------------------
// In-place softmax over rows of length 256 ([32*256, 256])
__launch_bounds__(256)
__global__ void softmax256_kernel(float* __restrict__ a) {
    long row = blockIdx.x;
    int t = threadIdx.x;
    float* r = a + row * 256;
    float v = r[t];
    __shared__ float red[256];
    red[t] = v;
    __syncthreads();
    for (int off = 128; off > 0; off >>= 1) { if (t < off) red[t] = fmaxf(red[t], red[t + off]); __syncthreads(); }
    float mx = red[0];
    __syncthreads();
    float e = __expf(v - mx);
    red[t] = e;
    __syncthreads();
    for (int off = 128; off > 0; off >>= 1) { if (t < off) red[t] += red[t + off]; __syncthreads(); }
    r[t] = e / red[0];
}

// ---------------------------------------------------------------------------
// pinv norm: per-bh max row-sum and max col-sum of a2 (a2 > 0, so |.| = .)
__launch_bounds__(256)
__global__ void redmax_kernel(const float* __restrict__ a2, float* __restrict__ red) {
    int bh = blockIdx.x;
    int t = threadIdx.x;
    const float* Ab = a2 + ((long)bh << 16);
    float rs = 0.f, cs = 0.f;
    for (int c = 0; c < 256; ++c) rs += Ab[t * 256 + c];
    for (int r = 0; r < 256; ++r) cs += Ab[r * 256 + t];
    __shared__ float m1[256], m2[256];
    m1[t] = rs; m2[t] = cs;
    __syncthreads();
    for (int off = 128; off > 0; off >>= 1) {
        if (t < off) { m1[t] = fmaxf(m1[t], m1[t + off]); m2[t] = fmaxf(m2[t], m2[t + off]); }
        __syncthreads();
    }
    if (t == 0) { red[bh] = m1[0]; red[32 + bh] = m2[0]; }
}

__global__ void scale_kernel(const float* __restrict__ red, float* __restrict__ scl) {
    __shared__ float a[32], b[32];
    int t = threadIdx.x;  // 32
    a[t] = red[t]; b[t] = red[32 + t];
    __syncthreads();
    for (int off = 16; off > 0; off >>= 1) {
        if (t < off) { a[t] = fmaxf(a[t], a[t + off]); b[t] = fmaxf(b[t], b[t + off]); }
        __syncthreads();
    }
    if (t == 0) scl[0] = 1.0f / (a[0] * b[0]);
}

// z0 = a2^T * scale (per bh)
__launch_bounds__(256)
__global__ void transpose_scale_kernel(const float* __restrict__ a2, const float* __restrict__ scl,
                                       float* __restrict__ z) {
    int bh = blockIdx.x >> 8;
    int i  = blockIdx.x & 255;
    int j  = threadIdx.x;
    float s = scl[0];
    z[((long)bh << 16) + i * 256 + j] = a2[((long)bh << 16) + j * 256 + i] * s;
}

// Y = alpha*I - X  over [32, 256, 256]
__global__ void ew_aI_minus_kernel(const float* __restrict__ X, float* __restrict__ Y, float alpha) {
    long idx = (long)blockIdx.x * 256 + threadIdx.x;
    int e = (int)(idx & 65535);
    int i = e >> 8, j = e & 255;
    Y[idx] = ((i == j) ? alpha : 0.0f) - X[idx];
}

// ---------------------------------------------------------------------------
// a3v flash-style, stage 1. (unchanged from round 3 — verified)
__launch_bounds__(256)
__global__ void a3v_flash(const float* __restrict__ q_l, const float* __restrict__ kk,
                          const float* __restrict__ vv,
                          float* __restrict__ opart, float* __restrict__ lpart) {
    const int bh = blockIdx.y;
    const int mt = blockIdx.x >> 2;
    const int ns = blockIdx.x & 3;
    const int t  = threadIdx.x;
    const int tx = t & 15;
    const int ty = t >> 4;

    __shared__ float qs[64][64];   // q^T: qs[d][r]
    __shared__ float Ks[64][64];   // K^T: Ks[d][c]
    __shared__ float Vs[64][64];   // V natural: Vs[c][d]
    __shared__ float Ps[64][64];   // P natural: Ps[r][c]
    __shared__ float lred[64][16];

    const float* qbase = q_l + ((long)bh * MM + mt * 64) * DD;
    #pragma unroll
    for (int i = 0; i < 4; ++i) {
        int idx4 = t + 256 * i;
        int r = idx4 >> 4, d4 = (idx4 & 15) << 2;
        float4 v4 = *(const float4*)(qbase + r * DD + d4);
        qs[d4 + 0][r] = v4.x; qs[d4 + 1][r] = v4.y; qs[d4 + 2][r] = v4.z; qs[d4 + 3][r] = v4.w;
    }

    float acc_o[4][4] = {};
    float lacc[4] = {};
    const float* kbase = kk + ((long)bh * NN + ns * 1024) * DD;
    const float* vbase = vv + ((long)bh * NN + ns * 1024) * DD;
    __syncthreads();

    for (int ch = 0; ch < 16; ++ch) {
        #pragma unroll
        for (int i = 0; i < 4; ++i) {
            int idx4 = t + 256 * i;
            int c = idx4 >> 4, d4 = (idx4 & 15) << 2;
            float4 kv = *(const float4*)(kbase + (long)(ch * 64 + c) * DD + d4);
            float4 vv4 = *(const float4*)(vbase + (long)(ch * 64 + c) * DD + d4);
            Ks[d4 + 0][c] = kv.x; Ks[d4 + 1][c] = kv.y; Ks[d4 + 2][c] = kv.z; Ks[d4 + 3][c] = kv.w;
            *(float4*)&Vs[c][d4] = vv4;
        }
        __syncthreads();

        float s[4][4] = {};
        #pragma unroll 16
        for (int d = 0; d < 64; ++d) {
            float a0 = qs[d][ty * 4 + 0], a1 = qs[d][ty * 4 + 1];
            float a2 = qs[d][ty * 4 + 2], a3 = qs[d][ty * 4 + 3];
            float b0 = Ks[d][tx * 4 + 0], b1 = Ks[d][tx * 4 + 1];
            float b2 = Ks[d][tx * 4 + 2], b3 = Ks[d][tx * 4 + 3];
            s[0][0] += a0 * b0; s[0][1] += a0 * b1; s[0][2] += a0 * b2; s[0][3] += a0 * b3;
            s[1][0] += a1 * b0; s[1][1] += a1 * b1; s[1][2] += a1 * b2; s[1][3] += a1 * b3;
            s[2][0] += a2 * b0; s[2][1] += a2 * b1; s[2][2] += a2 * b2; s[2][3] += a2 * b3;
            s[3][0] += a3 * b0; s[3][1] += a3 * b1; s[3][2] += a3 * b2; s[3][3] += a3 * b3;
        }
        #pragma unroll
        for (int i = 0; i < 4; ++i) {
            float e0 = __expf(s[i][0]), e1 = __expf(s[i][1]);
            float e2 = __expf(s[i][2]), e3 = __expf(s[i][3]);
            lacc[i] += e0 + e1 + e2 + e3;
            float4 p4; p4.x = e0; p4.y = e1; p4.z = e2; p4.w = e3;
            *(float4*)&Ps[ty * 4 + i][tx * 4] = p4;
        }
        __syncthreads();

        #pragma unroll 16
        for (int c = 0; c < 64; ++c) {
            float a0 = Ps[ty * 4 + 0][c], a1 = Ps[ty * 4 + 1][c];
            float a2 = Ps[ty * 4 + 2][c], a3 = Ps[ty * 4 + 3][c];
            float b0 = Vs[c][tx * 4 + 0], b1 = Vs[c][tx * 4 + 1];
            float b2 = Vs[c][tx * 4 + 2], b3 = Vs[c][tx * 4 + 3];
            acc_o[0][0] += a0 * b0; acc_o[0][1] += a0 * b1; acc_o[0][2] += a0 * b2; acc_o[0][3] += a0 * b3;
            acc_o[1][0] += a1 * b0; acc_o[1][1] += a1 * b1; acc_o[1][2] += a1 * b2; acc_o[1][3] += a1 * b3;
            acc_o[2][0] += a2 * b0; acc_o[2][1] += a2 * b1; acc_o[2][2] += a2 * b2; acc_o[2][3] += a2 * b3;
            acc_o[3][0] += a3 * b0; acc_o[3][1] += a3 * b1; acc_o[3][2] += a3 * b2; acc_o[3][3] += a3 * b3;
        }
        __syncthreads();
    }

    const long pbase = ((long)((bh * 4 + mt) * 4 + ns)) << 12;
    #pragma unroll
    for (int i = 0; i < 4; ++i) {
        float4 w4; w4.x = acc_o[i][0]; w4.y = acc_o[i][1]; w4.z = acc_o[i][2]; w4.w = acc_o[i][3];
        *(float4*)(opart + pbase + (ty * 4 + i) * 64 + tx * 4) = w4;
        lred[ty * 4 + i][tx] = lacc[i];
    }
    __syncthreads();
    if (t < 64) {
        float sum = 0.f;
        #pragma unroll
        for (int u = 0; u < 16; ++u) sum += lred[t][u];
        lpart[((bh * 4 + mt) * 4 + ns) * 64 + t] = sum;
    }
}

// stage 2: combine 4 n-split partials
__global__ void a3v_combine(const float* __restrict__ opart, const float* __restrict__ lpart,
                            float* __restrict__ a3v) {
    int idx = blockIdx.x * 256 + threadIdx.x;  // 524288 total
    int d  = idx & 63;
    int m  = (idx >> 6) & 255;
    int bh = idx >> 14;
    int mt = m >> 6, r = m & 63;
    int pb = (bh * 4 + mt) * 4;
    float osum = 0.f, lsum = 0.f;
    #pragma unroll
    for (int ns = 0; ns < 4; ++ns) {
        osum += opart[(((long)(pb + ns)) << 12) + r * 64 + d];
        lsum += lpart[(pb + ns) * 64 + r];
    }
    a3v[((long)bh * MM + m) * DD + d] = osum / lsum;
}

// ---------------------------------------------------------------------------
// attn_out flash-style: 64 seq rows per block, full m=256 landmarks in 4 chunks.
// Scores q.k_l^T have sigma~0.25 -> skip max subtraction (same argument/evidence
// as a3v_flash). O = exp(S) @ wm / rowsum. Fused 33-tap depthwise conv epilogue.
__launch_bounds__(256)
__global__ void attn_out_flash(const float* __restrict__ qq, const float* __restrict__ k_l,
                               const float* __restrict__ wmat, const float* __restrict__ vv,
                               const float* __restrict__ convw, float* __restrict__ ctx) {
    const int bh = blockIdx.y;
    const int b  = bh >> 3, h = bh & 7;
    const int i0 = blockIdx.x * 64;
    const int t  = threadIdx.x;
    const int tx = t & 15;
    const int ty = t >> 4;

    __shared__ float qs[64][64];     // q^T tile: qs[d][r]
    __shared__ float KP[64][64];     // k_l^T chunk -> P chunk -> O tile
    __shared__ float Ws[64][64];     // wm chunk, natural [c][d]
    __shared__ float lred[64][16];
    __shared__ float dsum[64];
    __shared__ float cw[KS];

    if (t < KS) cw[t] = convw[h * KS + t];

    const float* qbase = qq + ((long)bh * NN + i0) * DD;
    #pragma unroll
    for (int i = 0; i < 4; ++i) {
        int idx4 = t + 256 * i;
        int r = idx4 >> 4, d4 = (idx4 & 15) << 2;
        float4 v4 = *(const float4*)(qbase + r * DD + d4);
        qs[d4 + 0][r] = v4.x; qs[d4 + 1][r] = v4.y; qs[d4 + 2][r] = v4.z; qs[d4 + 3][r] = v4.w;
    }

    float acc_o[4][4] = {};
    float lacc[4] = {};
    const float* klbase = k_l + ((long)bh * MM) * DD;
    const float* wbase  = wmat + ((long)bh * MM) * DD;

    for (int ch = 0; ch < 4; ++ch) {
        __syncthreads();
        #pragma unroll
        for (int i = 0; i < 4; ++i) {
            int idx4 = t + 256 * i;
            int c = idx4 >> 4, d4 = (idx4 & 15) << 2;
            float4 kv = *(const float4*)(klbase + (long)(ch * 64 + c) * DD + d4);
            float4 wv = *(const float4*)(wbase  + (long)(ch * 64 + c) * DD + d4);
            KP[d4 + 0][c] = kv.x; KP[d4 + 1][c] = kv.y; KP[d4 + 2][c] = kv.z; KP[d4 + 3][c] = kv.w;
            *(float4*)&Ws[c][d4] = wv;
        }
        __syncthreads();

        // S = q @ k_l^T chunk (64x64)
        float s[4][4] = {};
        #pragma unroll 16
        for (int d = 0; d < 64; ++d) {
            float a0 = qs[d][ty * 4 + 0], a1 = qs[d][ty * 4 + 1];
            float a2 = qs[d][ty * 4 + 2], a3 = qs[d][ty * 4 + 3];
            float b0 = KP[d][tx * 4 + 0], b1 = KP[d][tx * 4 + 1];
            float b2 = KP[d][tx * 4 + 2], b3 = KP[d][tx * 4 + 3];
            s[0][0] += a0 * b0; s[0][1] += a0 * b1; s[0][2] += a0 * b2; s[0][3] += a0 * b3;
            s[1][0] += a1 * b0; s[1][1] += a1 * b1; s[1][2] += a1 * b2; s[1][3] += a1 * b3;
            s[2][0] += a2 * b0; s[2][1] += a2 * b1; s[2][2] += a2 * b2; s[2][3] += a2 * b3;
            s[3][0] += a3 * b0; s[3][1] += a3 * b1; s[3][2] += a3 * b2; s[3][3] += a3 * b3;
        }
        __syncthreads();   // all threads done reading KP as K

        // P = exp(S), stash into KP (natural [r][c]); accumulate denominator
        #pragma unroll
        for (int i = 0; i < 4; ++i) {
            float e0 = __expf(s[i][0]), e1 = __expf(s[i][1]);
            float e2 = __expf(s[i][2]), e3 = __expf(s[i][3]);
            lacc[i] += e0 + e1 + e2 + e3;
            float4 p4; p4.x = e0; p4.y = e1; p4.z = e2; p4.w = e3;
            *(float4*)&KP[ty * 4 + i][tx * 4] = p4;
        }
        __syncthreads();

        // O += P @ W chunk
        #pragma unroll 16
        for (int c = 0; c < 64; ++c) {
            float a0 = KP[ty * 4 + 0][c], a1 = KP[ty * 4 + 1][c];
            float a2 = KP[ty * 4 + 2][c], a3 = KP[ty * 4 + 3][c];
            float b0 = Ws[c][tx * 4 + 0], b1 = Ws[c][tx * 4 + 1];
            float b2 = Ws[c][tx * 4 + 2], b3 = Ws[c][tx * 4 + 3];
            acc_o[0][0] += a0 * b0; acc_o[0][1] += a0 * b1; acc_o[0][2] += a0 * b2; acc_o[0][3] += a0 * b3;
            acc_o[1][0] += a1 * b0; acc_o[1][1] += a1 * b1; acc_o[1][2] += a1 * b2; acc_o[1][3] += a1 * b3;
            acc_o[2][0] += a2 * b0; acc_o[2][1] += a2 * b1; acc_o[2][2] += a2 * b2; acc_o[2][3] += a2 * b3;
            acc_o[3][0] += a3 * b0; acc_o[3][1] += a3 * b1; acc_o[3][2] += a3 * b2; acc_o[3][3] += a3 * b3;
        }
    }
    __syncthreads();

    // denominators
    #pragma unroll
    for (int i = 0; i < 4; ++i) lred[ty * 4 + i][tx] = lacc[i];
    __syncthreads();
    if (t < 64) {
        float ssum = 0.f;
        #pragma unroll
        for (int u = 0; u < 16; ++u) ssum += lred[t][u];
        dsum[t] = 1.0f / ssum;
    }
    __syncthreads();

    // normalized O -> KP[r][d]
    #pragma unroll
    for (int i = 0; i < 4; ++i) {
        float inv = dsum[ty * 4 + i];
        float4 o4; o4.x = acc_o[i][0] * inv; o4.y = acc_o[i][1] * inv;
        o4.z = acc_o[i][2] * inv; o4.w = acc_o[i][3] * inv;
        *(float4*)&KP[ty * 4 + i][tx * 4] = o4;
    }
    __syncthreads();

    // epilogue: fused depthwise conv + write ctx [b, n, h*d]
    const int d = t & 63, rsub = t >> 6;
    const float* vb = vv + ((long)bh * NN) * DD + d;
    float* cbase = ctx + ((long)b * NN + i0) * DIMM + h * DD + d;
    for (int p = 0; p < 16; ++p) {
        int r = p * 4 + rsub;
        int i = i0 + r;
        float o = KP[r][d];
        #pragma unroll
        for (int k = 0; k < KS; ++k) {
            int s2 = i + k - KS / 2;
            if (s2 >= 0 && s2 < NN) o += cw[k] * vb[(long)s2 * DD];
        }
        cbase[(long)r * DIMM] = o;
    }
}

// ---------------------------------------------------------------------------
extern "C" void kernel_launch(void* const* d_in, const int* in_sizes, int n_in,
                              void* d_out, int out_size, void* d_ws, size_t ws_size,
                              hipStream_t stream) {
    const float* x      = (const float*)d_in[0];
    const float* norm_w = (const float*)d_in[1];
    const float* norm_b = (const float*)d_in[2];
    const float* Wqkv   = (const float*)d_in[3];
    const float* Wout   = (const float*)d_in[4];
    const float* bout   = (const float*)d_in[5];
    const float* conv_w = (const float*)d_in[6];
    float* out = (float*)d_out;

    float* ws = (float*)d_ws;
    size_t o = 0;
    auto alloc = [&](size_t n) { float* p = ws + o; o += n; return p; };
    float* xn   = alloc((size_t)NROW * DIMM);        // reused as ctx later
    float* qq   = alloc((size_t)BHH * NN * DD);
    float* kk   = alloc((size_t)BHH * NN * DD);
    float* vv   = alloc((size_t)BHH * NN * DD);
    float* q_l  = alloc((size_t)BHH * MM * DD);
    float* k_l  = alloc((size_t)BHH * MM * DD);
    float* a2   = alloc((size_t)BHH * MM * MM);
    float* zb   = alloc((size_t)BHH * MM * MM);
    float* az   = alloc((size_t)BHH * MM * MM);
    float* gb   = alloc((size_t)BHH * MM * MM);
    float* tb   = alloc((size_t)BHH * MM * MM);
    float* z2   = alloc((size_t)BHH * MM * MM);
    float* a3v  = alloc((size_t)BHH * MM * DD);
    float* wm   = alloc((size_t)BHH * MM * DD);
    float* opart = alloc((size_t)BHH * 4 * 4 * 64 * 64);
    float* lpart = alloc((size_t)BHH * 4 * 4 * 64);
    float* red  = alloc(64);
    float* scl  = alloc(64);
    float* ctx  = xn;   // xn dead after QKV GEMM

    // 1. LayerNorm
    ln_kernel<<<NROW, 256, 0, stream>>>(x, norm_w, norm_b, xn);

    // 2. QKV GEMM with scatter epilogue (q scaled by 0.125)
    gemm64<EPI_QKV, false><<<dim3(3 * DIMM / 64, NROW / 64, 1), 256, 0, stream>>>(
        xn, Wqkv, nullptr, NROW, 3 * DIMM, DIMM, 0, 0, 0, 1.0f,
        nullptr, nullptr, qq, kk, vv);

    // 3. Landmarks
    landmark_kernel<<<dim3(BHH * MM, 2), 64, 0, stream>>>(qq, kk, q_l, k_l);

    // 4. sim2 = q_l @ k_l^T  (batched 32, 256x256x64)
    gemm64<EPI_NONE, true><<<dim3(4, 4, BHH), 256, 0, stream>>>(
        q_l, k_l, a2, MM, MM, DD, (long)MM * DD, (long)MM * DD, (long)MM * MM, 1.0f,
        nullptr, nullptr, nullptr, nullptr, nullptr);

    // 5. softmax rows -> a2
    softmax256_kernel<<<BHH * MM, 256, 0, stream>>>(a2);

    // 6-7. pinv normalization scalar
    redmax_kernel<<<BHH, 256, 0, stream>>>(a2, red);
    scale_kernel<<<1, 32, 0, stream>>>(red, scl);

    // 8. z0 = a2^T * scale
    transpose_scale_kernel<<<BHH * MM, 256, 0, stream>>>(a2, scl, zb);

    // 9. Newton-Schulz iterations
    const long sM = (long)MM * MM;
    const int ewBlocks = BHH * MM * MM / 256;
    float* zcur = zb;
    float* znew = z2;
    for (int it = 0; it < 6; ++it) {
        gemm64<EPI_NONE, false><<<dim3(4, 4, BHH), 256, 0, stream>>>(
            a2, zcur, az, MM, MM, MM, sM, sM, sM, 1.0f,
            nullptr, nullptr, nullptr, nullptr, nullptr);
        ew_aI_minus_kernel<<<ewBlocks, 256, 0, stream>>>(az, gb, 7.0f);
        gemm64<EPI_NONE, false><<<dim3(4, 4, BHH), 256, 0, stream>>>(
            az, gb, tb, MM, MM, MM, sM, sM, sM, 1.0f,
            nullptr, nullptr, nullptr, nullptr, nullptr);
        ew_aI_minus_kernel<<<ewBlocks, 256, 0, stream>>>(tb, gb, 15.0f);
        gemm64<EPI_NONE, false><<<dim3(4, 4, BHH), 256, 0, stream>>>(
            az, gb, tb, MM, MM, MM, sM, sM, sM, 1.0f,
            nullptr, nullptr, nullptr, nullptr, nullptr);
        ew_aI_minus_kernel<<<ewBlocks, 256, 0, stream>>>(tb, gb, 13.0f);
        gemm64<EPI_NONE, false><<<dim3(4, 4, BHH), 256, 0, stream>>>(
            zcur, gb, znew, MM, MM, MM, sM, sM, sM, 0.25f,
            nullptr, nullptr, nullptr, nullptr, nullptr);
        float* tmp = zcur; zcur = znew; znew = tmp;
    }
    // zcur == a2_inv

    // 10. a3v = softmax(q_l . k^T) @ v   (flash-style, no max subtraction)
    a3v_flash<<<dim3(16, BHH), 256, 0, stream>>>(q_l, kk, vv, opart, lpart);
    a3v_combine<<<BHH * MM * DD / 256, 256, 0, stream>>>(opart, lpart, a3v);

    // 11. w = a2_inv @ a3v  (batched 32, 256x64x256)
    gemm64<EPI_NONE, false><<<dim3(1, 4, BHH), 256, 0, stream>>>(
        zcur, a3v, wm, MM, DD, MM, sM, (long)MM * DD, (long)MM * DD, 1.0f,
        nullptr, nullptr, nullptr, nullptr, nullptr);

    // 12. out rows + fused conv -> ctx [b, n, h*d]  (flash-style)
    attn_out_flash<<<dim3(NN / 64, BHH), 256, 0, stream>>>(qq, k_l, wm, vv, conv_w, ctx);

    // 13. final: out = x + ctx @ Wout + bout
    gemm64<EPI_OUT, false><<<dim3(DIMM / 64, NROW / 64, 1), 256, 0, stream>>>(
        ctx, Wout, out, NROW, DIMM, DIMM, 0, 0, 0, 1.0f,
        bout, x, nullptr, nullptr, nullptr);
}

// Round 5
// 1204.892 us; speedup vs baseline: 4.4935x; 1.4599x over previous
//
#include <hip/hip_runtime.h>
#include <hip/hip_bf16.h>

// Problem constants
#define BB 4
#define NN 4096
#define DIMM 512
#define HH 8
#define DD 64
#define MM 256
#define LL 16
#define BHH 32
#define NROW (BB*NN)      // 16384
#define KS 33

typedef __attribute__((ext_vector_type(8))) short short8;   // 8 bf16 = 4 VGPR
typedef __attribute__((ext_vector_type(4))) float float4v;  // MFMA C/D

// ---------------------------------------------------------------------------
// LayerNorm: one block per row of [16384, 512] -> bf16 output
__launch_bounds__(256)
__global__ void ln_kernel(const float* __restrict__ x,
                          const float* __restrict__ w,
                          const float* __restrict__ bvec,
                          __hip_bfloat16* __restrict__ xn) {
    int row = blockIdx.x;
    int t = threadIdx.x;
    const float* xr = x + (long)row * DIMM;
    float v0 = xr[t];
    float v1 = xr[t + 256];
    __shared__ float red[256];
    red[t] = v0 + v1;
    __syncthreads();
    for (int off = 128; off > 0; off >>= 1) { if (t < off) red[t] += red[t + off]; __syncthreads(); }
    float mu = red[0] * (1.0f / DIMM);
    __syncthreads();
    float d0 = v0 - mu, d1 = v1 - mu;
    red[t] = d0 * d0 + d1 * d1;
    __syncthreads();
    for (int off = 128; off > 0; off >>= 1) { if (t < off) red[t] += red[t + off]; __syncthreads(); }
    float var = red[0] * (1.0f / DIMM);
    float rs = rsqrtf(var + 1e-5f);
    xn[(long)row * DIMM + t]       = __float2bfloat16(d0 * rs * w[t]       + bvec[t]);
    xn[(long)row * DIMM + t + 256] = __float2bfloat16(d1 * rs * w[t + 256] + bvec[t + 256]);
}

// ---------------------------------------------------------------------------
// Transpose + fp32->bf16: out[N][K] = bf16(in[K][N])
__launch_bounds__(256)
__global__ void transpose_bf16(const float* __restrict__ in, __hip_bfloat16* __restrict__ outp,
                               int K, int N) {
    __shared__ float tile[32][33];
    int k0 = blockIdx.y * 32, n0 = blockIdx.x * 32;
    int tx = threadIdx.x & 31, ty = threadIdx.x >> 5;  // ty 0..7
    #pragma unroll
    for (int i = 0; i < 32; i += 8)
        tile[ty + i][tx] = in[(long)(k0 + ty + i) * N + n0 + tx];
    __syncthreads();
    #pragma unroll
    for (int i = 0; i < 32; i += 8)
        outp[(long)(n0 + ty + i) * K + k0 + tx] = __float2bfloat16(tile[tx][ty + i]);
}

// ---------------------------------------------------------------------------
// bf16 MFMA GEMM: C[M,N] = A[M,K]bf16 @ Bt[N,K]bf16^T, fp32 epilogues.
// 128x128 tile, BK=64, 256 threads = 4 waves (2x2), 4x4 16x16x32 frags/wave.
enum { EPI_NONE = 0, EPI_QKV = 1, EPI_OUT = 2 };

template<int EPI>
__launch_bounds__(256)
__global__ void gemm_mfma(const __hip_bfloat16* __restrict__ A,
                          const __hip_bfloat16* __restrict__ Bt,
                          float* __restrict__ C, int M, int N, int K,
                          const float* __restrict__ bias,
                          const float* __restrict__ resid,
                          float* __restrict__ qp, float* __restrict__ kp, float* __restrict__ vp) {
    __shared__ __hip_bfloat16 As[128][64];
    __shared__ __hip_bfloat16 Bs[128][64];
    const int t = threadIdx.x;
    const int m0 = blockIdx.y * 128, n0 = blockIdx.x * 128;
    const int wave = t >> 6, lane = t & 63;
    const int wrow = wave >> 1, wcol = wave & 1;
    const int lm = lane & 15, quad = lane >> 4;

    float4v acc[4][4] = {};

    for (int k0 = 0; k0 < K; k0 += 64) {
        #pragma unroll
        for (int p = 0; p < 4; ++p) {
            int idx = t + p * 256;
            int r = idx >> 3, c8 = (idx & 7) * 8;
            *(uint4*)&As[r][c8] = *(const uint4*)&A[(long)(m0 + r) * K + k0 + c8];
            *(uint4*)&Bs[r][c8] = *(const uint4*)&Bt[(long)(n0 + r) * K + k0 + c8];
        }
        __syncthreads();
        #pragma unroll
        for (int ks = 0; ks < 64; ks += 32) {
            short8 af[4], bfr[4];
            #pragma unroll
            for (int i = 0; i < 4; ++i) {
                af[i]  = *(const short8*)&As[wrow * 64 + i * 16 + lm][ks + quad * 8];
                bfr[i] = *(const short8*)&Bs[wcol * 64 + i * 16 + lm][ks + quad * 8];
            }
            #pragma unroll
            for (int i = 0; i < 4; ++i)
                #pragma unroll
                for (int j = 0; j < 4; ++j)
                    acc[i][j] = __builtin_amdgcn_mfma_f32_16x16x32_bf16(af[i], bfr[j], acc[i][j], 0, 0, 0);
        }
        __syncthreads();
    }

    #pragma unroll
    for (int i = 0; i < 4; ++i) {
        #pragma unroll
        for (int j = 0; j < 4; ++j) {
            #pragma unroll
            for (int r = 0; r < 4; ++r) {
                int row = m0 + wrow * 64 + i * 16 + quad * 4 + r;
                int col = n0 + wcol * 64 + j * 16 + lm;
                float val = acc[i][j][r];
                if (EPI == EPI_QKV) {
                    int b = row >> 12, ii = row & (NN - 1);
                    int which = col >> 9, rem = col & 511;
                    int h = rem >> 6, dd = rem & 63;
                    long dst = (((long)(b * HH + h) * NN + ii) * DD + dd);
                    if (which == 0) qp[dst] = val * 0.125f;   // q * DHEAD^-0.5
                    else if (which == 1) kp[dst] = val;
                    else vp[dst] = val;
                } else { // EPI_OUT
                    C[(long)row * N + col] = val + bias[col] + resid[(long)row * N + col];
                }
            }
        }
    }
}

// ---------------------------------------------------------------------------
// Generic fp32 tiled GEMM (kept for sim2 / pinv / wm). 64x64 tile, BK=16.
template<int EPI, bool TRANSB>
__launch_bounds__(256)
__global__ void gemm64(const float* __restrict__ A, const float* __restrict__ Bm,
                       float* __restrict__ C,
                       int M, int N, int K, long sA, long sB, long sC, float alpha) {
    const int bz = blockIdx.z;
    const float* Ab = A + (long)bz * sA;
    const float* Bb = Bm + (long)bz * sB;
    float* Cb = C + (long)bz * sC;

    __shared__ float As[16][64];
    __shared__ float Bs[16][64];

    const int tid = threadIdx.x;
    const int tx = tid & 15;
    const int ty = tid >> 4;
    const int m0 = blockIdx.y * 64;
    const int n0 = blockIdx.x * 64;

    float acc[4][4] = {};

    for (int k0 = 0; k0 < K; k0 += 16) {
        {
            int r  = tid >> 2;
            int kk = (tid & 3) * 4;
            float4 va = *(const float4*)(Ab + (long)(m0 + r) * K + k0 + kk);
            As[kk + 0][r] = va.x; As[kk + 1][r] = va.y; As[kk + 2][r] = va.z; As[kk + 3][r] = va.w;
        }
        if (!TRANSB) {
            int kk = tid >> 4;
            int j  = (tid & 15) * 4;
            float4 vb = *(const float4*)(Bb + (long)(k0 + kk) * N + n0 + j);
            Bs[kk][j + 0] = vb.x; Bs[kk][j + 1] = vb.y; Bs[kk][j + 2] = vb.z; Bs[kk][j + 3] = vb.w;
        } else {
            int j  = tid >> 2;
            int kk = (tid & 3) * 4;
            float4 vb = *(const float4*)(Bb + (long)(n0 + j) * K + k0 + kk);
            Bs[kk + 0][j] = vb.x; Bs[kk + 1][j] = vb.y; Bs[kk + 2][j] = vb.z; Bs[kk + 3][j] = vb.w;
        }
        __syncthreads();
        #pragma unroll
        for (int kk = 0; kk < 16; ++kk) {
            float a0 = As[kk][ty * 4 + 0], a1 = As[kk][ty * 4 + 1];
            float a2 = As[kk][ty * 4 + 2], a3 = As[kk][ty * 4 + 3];
            float b0 = Bs[kk][tx * 4 + 0], b1 = Bs[kk][tx * 4 + 1];
            float b2 = Bs[kk][tx * 4 + 2], b3 = Bs[kk][tx * 4 + 3];
            acc[0][0] += a0 * b0; acc[0][1] += a0 * b1; acc[0][2] += a0 * b2; acc[0][3] += a0 * b3;
            acc[1][0] += a1 * b0; acc[1][1] += a1 * b1; acc[1][2] += a1 * b2; acc[1][3] += a1 * b3;
            acc[2][0] += a2 * b0; acc[2][1] += a2 * b1; acc[2][2] += a2 * b2; acc[2][3] += a2 * b3;
            acc[3][0] += a3 * b0; acc[3][1] += a3 * b1; acc[3][2] += a3 * b2; acc[3][3] += a3 * b3;
        }
        __syncthreads();
    }

    #pragma unroll
    for (int r = 0; r < 4; ++r)
        #pragma unroll
        for (int c = 0; c < 4; ++c)
            Cb[(long)(m0 + ty * 4 + r) * N + n0 + tx * 4 + c] = acc[r][c] * alpha;
}

// ---------------------------------------------------------------------------
// Landmark means
__global__ void landmark_kernel(const float* __restrict__ qq, const float* __restrict__ kk,
                                float* __restrict__ q_l, float* __restrict__ k_l) {
    int bh = blockIdx.x >> 8;
    int m  = blockIdx.x & 255;
    int d  = threadIdx.x;     // 64
    const float* src = (blockIdx.y ? kk : qq) + ((long)bh * NN + m * LL) * DD + d;
    float s = 0.f;
    #pragma unroll
    for (int t = 0; t < LL; ++t) s += src[(long)t * DD];
    float* dst = blockIdx.y ? k_l : q_l;
    dst[((long)bh * MM + m) * DD + d] = s * (1.0f / LL);
}

// ---------------------------------------------------------------------------
__launch_bounds__(256)
__global__ void softmax256_kernel(float* __restrict__ a) {
    long row = blockIdx.x;
    int t = threadIdx.x;
    float* r = a + row * 256;
    float v = r[t];
    __shared__ float red[256];
    red[t] = v;
    __syncthreads();
    for (int off = 128; off > 0; off >>= 1) { if (t < off) red[t] = fmaxf(red[t], red[t + off]); __syncthreads(); }
    float mx = red[0];
    __syncthreads();
    float e = __expf(v - mx);
    red[t] = e;
    __syncthreads();
    for (int off = 128; off > 0; off >>= 1) { if (t < off) red[t] += red[t + off]; __syncthreads(); }
    r[t] = e / red[0];
}

// ---------------------------------------------------------------------------
__launch_bounds__(256)
__global__ void redmax_kernel(const float* __restrict__ a2, float* __restrict__ red) {
    int bh = blockIdx.x;
    int t = threadIdx.x;
    const float* Ab = a2 + ((long)bh << 16);
    float rs = 0.f, cs = 0.f;
    for (int c = 0; c < 256; ++c) rs += Ab[t * 256 + c];
    for (int r = 0; r < 256; ++r) cs += Ab[r * 256 + t];
    __shared__ float m1[256], m2[256];
    m1[t] = rs; m2[t] = cs;
    __syncthreads();
    for (int off = 128; off > 0; off >>= 1) {
        if (t < off) { m1[t] = fmaxf(m1[t], m1[t + off]); m2[t] = fmaxf(m2[t], m2[t + off]); }
        __syncthreads();
    }
    if (t == 0) { red[bh] = m1[0]; red[32 + bh] = m2[0]; }
}

__global__ void scale_kernel(const float* __restrict__ red, float* __restrict__ scl) {
    __shared__ float a[32], b[32];
    int t = threadIdx.x;  // 32
    a[t] = red[t]; b[t] = red[32 + t];
    __syncthreads();
    for (int off = 16; off > 0; off >>= 1) {
        if (t < off) { a[t] = fmaxf(a[t], a[t + off]); b[t] = fmaxf(b[t], b[t + off]); }
        __syncthreads();
    }
    if (t == 0) scl[0] = 1.0f / (a[0] * b[0]);
}

__launch_bounds__(256)
__global__ void transpose_scale_kernel(const float* __restrict__ a2, const float* __restrict__ scl,
                                       float* __restrict__ z) {
    int bh = blockIdx.x >> 8;
    int i  = blockIdx.x & 255;
    int j  = threadIdx.x;
    float s = scl[0];
    z[((long)bh << 16) + i * 256 + j] = a2[((long)bh << 16) + j * 256 + i] * s;
}

__global__ void ew_aI_minus_kernel(const float* __restrict__ X, float* __restrict__ Y, float alpha) {
    long idx = (long)blockIdx.x * 256 + threadIdx.x;
    int e = (int)(idx & 65535);
    int i = e >> 8, j = e & 255;
    Y[idx] = ((i == j) ? alpha : 0.0f) - X[idx];
}

// ---------------------------------------------------------------------------
// a3v flash-style, stage 1. (verified rounds 3-4)
__launch_bounds__(256)
__global__ void a3v_flash(const float* __restrict__ q_l, const float* __restrict__ kk,
                          const float* __restrict__ vv,
                          float* __restrict__ opart, float* __restrict__ lpart) {
    const int bh = blockIdx.y;
    const int mt = blockIdx.x >> 2;
    const int ns = blockIdx.x & 3;
    const int t  = threadIdx.x;
    const int tx = t & 15;
    const int ty = t >> 4;

    __shared__ float qs[64][64];
    __shared__ float Ks[64][64];
    __shared__ float Vs[64][64];
    __shared__ float Ps[64][64];
    __shared__ float lred[64][16];

    const float* qbase = q_l + ((long)bh * MM + mt * 64) * DD;
    #pragma unroll
    for (int i = 0; i < 4; ++i) {
        int idx4 = t + 256 * i;
        int r = idx4 >> 4, d4 = (idx4 & 15) << 2;
        float4 v4 = *(const float4*)(qbase + r * DD + d4);
        qs[d4 + 0][r] = v4.x; qs[d4 + 1][r] = v4.y; qs[d4 + 2][r] = v4.z; qs[d4 + 3][r] = v4.w;
    }

    float acc_o[4][4] = {};
    float lacc[4] = {};
    const float* kbase = kk + ((long)bh * NN + ns * 1024) * DD;
    const float* vbase = vv + ((long)bh * NN + ns * 1024) * DD;
    __syncthreads();

    for (int ch = 0; ch < 16; ++ch) {
        #pragma unroll
        for (int i = 0; i < 4; ++i) {
            int idx4 = t + 256 * i;
            int c = idx4 >> 4, d4 = (idx4 & 15) << 2;
            float4 kv = *(const float4*)(kbase + (long)(ch * 64 + c) * DD + d4);
            float4 vv4 = *(const float4*)(vbase + (long)(ch * 64 + c) * DD + d4);
            Ks[d4 + 0][c] = kv.x; Ks[d4 + 1][c] = kv.y; Ks[d4 + 2][c] = kv.z; Ks[d4 + 3][c] = kv.w;
            *(float4*)&Vs[c][d4] = vv4;
        }
        __syncthreads();

        float s[4][4] = {};
        #pragma unroll 16
        for (int d = 0; d < 64; ++d) {
            float a0 = qs[d][ty * 4 + 0], a1 = qs[d][ty * 4 + 1];
            float a2 = qs[d][ty * 4 + 2], a3 = qs[d][ty * 4 + 3];
            float b0 = Ks[d][tx * 4 + 0], b1 = Ks[d][tx * 4 + 1];
            float b2 = Ks[d][tx * 4 + 2], b3 = Ks[d][tx * 4 + 3];
            s[0][0] += a0 * b0; s[0][1] += a0 * b1; s[0][2] += a0 * b2; s[0][3] += a0 * b3;
            s[1][0] += a1 * b0; s[1][1] += a1 * b1; s[1][2] += a1 * b2; s[1][3] += a1 * b3;
            s[2][0] += a2 * b0; s[2][1] += a2 * b1; s[2][2] += a2 * b2; s[2][3] += a2 * b3;
            s[3][0] += a3 * b0; s[3][1] += a3 * b1; s[3][2] += a3 * b2; s[3][3] += a3 * b3;
        }
        #pragma unroll
        for (int i = 0; i < 4; ++i) {
            float e0 = __expf(s[i][0]), e1 = __expf(s[i][1]);
            float e2 = __expf(s[i][2]), e3 = __expf(s[i][3]);
            lacc[i] += e0 + e1 + e2 + e3;
            float4 p4; p4.x = e0; p4.y = e1; p4.z = e2; p4.w = e3;
            *(float4*)&Ps[ty * 4 + i][tx * 4] = p4;
        }
        __syncthreads();

        #pragma unroll 16
        for (int c = 0; c < 64; ++c) {
            float a0 = Ps[ty * 4 + 0][c], a1 = Ps[ty * 4 + 1][c];
            float a2 = Ps[ty * 4 + 2][c], a3 = Ps[ty * 4 + 3][c];
            float b0 = Vs[c][tx * 4 + 0], b1 = Vs[c][tx * 4 + 1];
            float b2 = Vs[c][tx * 4 + 2], b3 = Vs[c][tx * 4 + 3];
            acc_o[0][0] += a0 * b0; acc_o[0][1] += a0 * b1; acc_o[0][2] += a0 * b2; acc_o[0][3] += a0 * b3;
            acc_o[1][0] += a1 * b0; acc_o[1][1] += a1 * b1; acc_o[1][2] += a1 * b2; acc_o[1][3] += a1 * b3;
            acc_o[2][0] += a2 * b0; acc_o[2][1] += a2 * b1; acc_o[2][2] += a2 * b2; acc_o[2][3] += a2 * b3;
            acc_o[3][0] += a3 * b0; acc_o[3][1] += a3 * b1; acc_o[3][2] += a3 * b2; acc_o[3][3] += a3 * b3;
        }
        __syncthreads();
    }

    const long pbase = ((long)((bh * 4 + mt) * 4 + ns)) << 12;
    #pragma unroll
    for (int i = 0; i < 4; ++i) {
        float4 w4; w4.x = acc_o[i][0]; w4.y = acc_o[i][1]; w4.z = acc_o[i][2]; w4.w = acc_o[i][3];
        *(float4*)(opart + pbase + (ty * 4 + i) * 64 + tx * 4) = w4;
        lred[ty * 4 + i][tx] = lacc[i];
    }
    __syncthreads();
    if (t < 64) {
        float sum = 0.f;
        #pragma unroll
        for (int u = 0; u < 16; ++u) sum += lred[t][u];
        lpart[((bh * 4 + mt) * 4 + ns) * 64 + t] = sum;
    }
}

__global__ void a3v_combine(const float* __restrict__ opart, const float* __restrict__ lpart,
                            float* __restrict__ a3v) {
    int idx = blockIdx.x * 256 + threadIdx.x;
    int d  = idx & 63;
    int m  = (idx >> 6) & 255;
    int bh = idx >> 14;
    int mt = m >> 6, r = m & 63;
    int pb = (bh * 4 + mt) * 4;
    float osum = 0.f, lsum = 0.f;
    #pragma unroll
    for (int ns = 0; ns < 4; ++ns) {
        osum += opart[(((long)(pb + ns)) << 12) + r * 64 + d];
        lsum += lpart[(pb + ns) * 64 + r];
    }
    a3v[((long)bh * MM + m) * DD + d] = osum / lsum;
}

// ---------------------------------------------------------------------------
// attn_out flash-style (conv removed): writes bf16 ctx.
__launch_bounds__(256)
__global__ void attn_out_flash(const float* __restrict__ qq, const float* __restrict__ k_l,
                               const float* __restrict__ wmat,
                               __hip_bfloat16* __restrict__ ctx) {
    const int bh = blockIdx.y;
    const int b  = bh >> 3, h = bh & 7;
    const int i0 = blockIdx.x * 64;
    const int t  = threadIdx.x;
    const int tx = t & 15;
    const int ty = t >> 4;

    __shared__ float qs[64][64];
    __shared__ float KP[64][64];
    __shared__ float Ws[64][64];
    __shared__ float lred[64][16];
    __shared__ float dsum[64];

    const float* qbase = qq + ((long)bh * NN + i0) * DD;
    #pragma unroll
    for (int i = 0; i < 4; ++i) {
        int idx4 = t + 256 * i;
        int r = idx4 >> 4, d4 = (idx4 & 15) << 2;
        float4 v4 = *(const float4*)(qbase + r * DD + d4);
        qs[d4 + 0][r] = v4.x; qs[d4 + 1][r] = v4.y; qs[d4 + 2][r] = v4.z; qs[d4 + 3][r] = v4.w;
    }

    float acc_o[4][4] = {};
    float lacc[4] = {};
    const float* klbase = k_l + ((long)bh * MM) * DD;
    const float* wbase  = wmat + ((long)bh * MM) * DD;

    for (int ch = 0; ch < 4; ++ch) {
        __syncthreads();
        #pragma unroll
        for (int i = 0; i < 4; ++i) {
            int idx4 = t + 256 * i;
            int c = idx4 >> 4, d4 = (idx4 & 15) << 2;
            float4 kv = *(const float4*)(klbase + (long)(ch * 64 + c) * DD + d4);
            float4 wv = *(const float4*)(wbase  + (long)(ch * 64 + c) * DD + d4);
            KP[d4 + 0][c] = kv.x; KP[d4 + 1][c] = kv.y; KP[d4 + 2][c] = kv.z; KP[d4 + 3][c] = kv.w;
            *(float4*)&Ws[c][d4] = wv;
        }
        __syncthreads();

        float s[4][4] = {};
        #pragma unroll 16
        for (int d = 0; d < 64; ++d) {
            float a0 = qs[d][ty * 4 + 0], a1 = qs[d][ty * 4 + 1];
            float a2 = qs[d][ty * 4 + 2], a3 = qs[d][ty * 4 + 3];
            float b0 = KP[d][tx * 4 + 0], b1 = KP[d][tx * 4 + 1];
            float b2 = KP[d][tx * 4 + 2], b3 = KP[d][tx * 4 + 3];
            s[0][0] += a0 * b0; s[0][1] += a0 * b1; s[0][2] += a0 * b2; s[0][3] += a0 * b3;
            s[1][0] += a1 * b0; s[1][1] += a1 * b1; s[1][2] += a1 * b2; s[1][3] += a1 * b3;
            s[2][0] += a2 * b0; s[2][1] += a2 * b1; s[2][2] += a2 * b2; s[2][3] += a2 * b3;
            s[3][0] += a3 * b0; s[3][1] += a3 * b1; s[3][2] += a3 * b2; s[3][3] += a3 * b3;
        }
        __syncthreads();

        #pragma unroll
        for (int i = 0; i < 4; ++i) {
            float e0 = __expf(s[i][0]), e1 = __expf(s[i][1]);
            float e2 = __expf(s[i][2]), e3 = __expf(s[i][3]);
            lacc[i] += e0 + e1 + e2 + e3;
            float4 p4; p4.x = e0; p4.y = e1; p4.z = e2; p4.w = e3;
            *(float4*)&KP[ty * 4 + i][tx * 4] = p4;
        }
        __syncthreads();

        #pragma unroll 16
        for (int c = 0; c < 64; ++c) {
            float a0 = KP[ty * 4 + 0][c], a1 = KP[ty * 4 + 1][c];
            float a2 = KP[ty * 4 + 2][c], a3 = KP[ty * 4 + 3][c];
            float b0 = Ws[c][tx * 4 + 0], b1 = Ws[c][tx * 4 + 1];
            float b2 = Ws[c][tx * 4 + 2], b3 = Ws[c][tx * 4 + 3];
            acc_o[0][0] += a0 * b0; acc_o[0][1] += a0 * b1; acc_o[0][2] += a0 * b2; acc_o[0][3] += a0 * b3;
            acc_o[1][0] += a1 * b0; acc_o[1][1] += a1 * b1; acc_o[1][2] += a1 * b2; acc_o[1][3] += a1 * b3;
            acc_o[2][0] += a2 * b0; acc_o[2][1] += a2 * b1; acc_o[2][2] += a2 * b2; acc_o[2][3] += a2 * b3;
            acc_o[3][0] += a3 * b0; acc_o[3][1] += a3 * b1; acc_o[3][2] += a3 * b2; acc_o[3][3] += a3 * b3;
        }
    }
    __syncthreads();

    #pragma unroll
    for (int i = 0; i < 4; ++i) lred[ty * 4 + i][tx] = lacc[i];
    __syncthreads();
    if (t < 64) {
        float ssum = 0.f;
        #pragma unroll
        for (int u = 0; u < 16; ++u) ssum += lred[t][u];
        dsum[t] = 1.0f / ssum;
    }
    __syncthreads();

    #pragma unroll
    for (int i = 0; i < 4; ++i) {
        float inv = dsum[ty * 4 + i];
        float4 o4; o4.x = acc_o[i][0] * inv; o4.y = acc_o[i][1] * inv;
        o4.z = acc_o[i][2] * inv; o4.w = acc_o[i][3] * inv;
        *(float4*)&KP[ty * 4 + i][tx * 4] = o4;
    }
    __syncthreads();

    const int d = t & 63, rsub = t >> 6;
    __hip_bfloat16* cbase = ctx + ((long)b * NN + i0) * DIMM + h * DD + d;
    #pragma unroll
    for (int p = 0; p < 16; ++p) {
        int r = p * 4 + rsub;
        cbase[(long)r * DIMM] = __float2bfloat16(KP[r][d]);
    }
}

// ---------------------------------------------------------------------------
// Depthwise 33-tap seq conv on v, added into bf16 ctx.
// Block = (bh, 256-seq chunk); stage 288 v rows in LDS (conflict-free).
__launch_bounds__(256)
__global__ void conv_kernel(const float* __restrict__ vv, const float* __restrict__ convw,
                            __hip_bfloat16* __restrict__ ctx) {
    __shared__ float vs[256 + 32][DD];   // 73.7 KB
    __shared__ float cw[KS];
    const int bh = blockIdx.y;
    const int b = bh >> 3, h = bh & 7;
    const int s0 = blockIdx.x * 256;
    const int t = threadIdx.x;
    if (t < KS) cw[t] = convw[h * KS + t];
    const int d = t & 63, sub = t >> 6;
    const float* vb = vv + (long)bh * NN * DD;
    for (int r = sub; r < 256 + 32; r += 4) {
        int s = s0 - 16 + r;
        vs[r][d] = (s >= 0 && s < NN) ? vb[(long)s * DD + d] : 0.0f;
    }
    __syncthreads();
    __hip_bfloat16* cb = ctx + ((long)b * NN + s0) * DIMM + h * DD + d;
    for (int r0 = sub * 64; r0 < sub * 64 + 64; ++r0) {
        float o = 0.f;
        #pragma unroll
        for (int k = 0; k < KS; ++k) o += cw[k] * vs[r0 + k][d];
        long off = (long)r0 * DIMM;
        cb[off] = __float2bfloat16(__bfloat162float(cb[off]) + o);
    }
}

// ---------------------------------------------------------------------------
extern "C" void kernel_launch(void* const* d_in, const int* in_sizes, int n_in,
                              void* d_out, int out_size, void* d_ws, size_t ws_size,
                              hipStream_t stream) {
    const float* x      = (const float*)d_in[0];
    const float* norm_w = (const float*)d_in[1];
    const float* norm_b = (const float*)d_in[2];
    const float* Wqkv   = (const float*)d_in[3];
    const float* Wout   = (const float*)d_in[4];
    const float* bout   = (const float*)d_in[5];
    const float* conv_w = (const float*)d_in[6];
    float* out = (float*)d_out;

    float* ws = (float*)d_ws;
    size_t o = 0;
    auto alloc = [&](size_t n) { float* p = ws + o; o += n; return p; };
    auto allocb = [&](size_t n) { return (__hip_bfloat16*)alloc((n + 1) / 2); };

    __hip_bfloat16* xn_bf  = allocb((size_t)NROW * DIMM);
    __hip_bfloat16* wqt_bf = allocb((size_t)3 * DIMM * DIMM);   // [1536][512]
    __hip_bfloat16* wot_bf = allocb((size_t)DIMM * DIMM);       // [512][512]
    __hip_bfloat16* ctx_bf = allocb((size_t)NROW * DIMM);
    float* qq   = alloc((size_t)BHH * NN * DD);
    float* kk   = alloc((size_t)BHH * NN * DD);
    float* vv   = alloc((size_t)BHH * NN * DD);
    float* q_l  = alloc((size_t)BHH * MM * DD);
    float* k_l  = alloc((size_t)BHH * MM * DD);
    float* a2   = alloc((size_t)BHH * MM * MM);
    float* zb   = alloc((size_t)BHH * MM * MM);
    float* az   = alloc((size_t)BHH * MM * MM);
    float* gb   = alloc((size_t)BHH * MM * MM);
    float* tb   = alloc((size_t)BHH * MM * MM);
    float* z2   = alloc((size_t)BHH * MM * MM);
    float* a3v  = alloc((size_t)BHH * MM * DD);
    float* wm   = alloc((size_t)BHH * MM * DD);
    float* opart = alloc((size_t)BHH * 4 * 4 * 64 * 64);
    float* lpart = alloc((size_t)BHH * 4 * 4 * 64);
    float* red  = alloc(64);
    float* scl  = alloc(64);

    // 1. LayerNorm -> bf16
    ln_kernel<<<NROW, 256, 0, stream>>>(x, norm_w, norm_b, xn_bf);

    // 1b. transpose+convert weights
    transpose_bf16<<<dim3(3 * DIMM / 32, DIMM / 32), 256, 0, stream>>>(Wqkv, wqt_bf, DIMM, 3 * DIMM);
    transpose_bf16<<<dim3(DIMM / 32, DIMM / 32), 256, 0, stream>>>(Wout, wot_bf, DIMM, DIMM);

    // 2. QKV GEMM (MFMA) with scatter epilogue
    gemm_mfma<EPI_QKV><<<dim3(3 * DIMM / 128, NROW / 128), 256, 0, stream>>>(
        xn_bf, wqt_bf, nullptr, NROW, 3 * DIMM, DIMM,
        nullptr, nullptr, qq, kk, vv);

    // 3. Landmarks
    landmark_kernel<<<dim3(BHH * MM, 2), 64, 0, stream>>>(qq, kk, q_l, k_l);

    // 4. sim2 = q_l @ k_l^T
    gemm64<EPI_NONE, true><<<dim3(4, 4, BHH), 256, 0, stream>>>(
        q_l, k_l, a2, MM, MM, DD, (long)MM * DD, (long)MM * DD, (long)MM * MM, 1.0f);

    // 5. softmax rows -> a2
    softmax256_kernel<<<BHH * MM, 256, 0, stream>>>(a2);

    // 6-7. pinv normalization scalar
    redmax_kernel<<<BHH, 256, 0, stream>>>(a2, red);
    scale_kernel<<<1, 32, 0, stream>>>(red, scl);

    // 8. z0 = a2^T * scale
    transpose_scale_kernel<<<BHH * MM, 256, 0, stream>>>(a2, scl, zb);

    // 9. Newton-Schulz iterations
    const long sM = (long)MM * MM;
    const int ewBlocks = BHH * MM * MM / 256;
    float* zcur = zb;
    float* znew = z2;
    for (int it = 0; it < 6; ++it) {
        gemm64<EPI_NONE, false><<<dim3(4, 4, BHH), 256, 0, stream>>>(
            a2, zcur, az, MM, MM, MM, sM, sM, sM, 1.0f);
        ew_aI_minus_kernel<<<ewBlocks, 256, 0, stream>>>(az, gb, 7.0f);
        gemm64<EPI_NONE, false><<<dim3(4, 4, BHH), 256, 0, stream>>>(
            az, gb, tb, MM, MM, MM, sM, sM, sM, 1.0f);
        ew_aI_minus_kernel<<<ewBlocks, 256, 0, stream>>>(tb, gb, 15.0f);
        gemm64<EPI_NONE, false><<<dim3(4, 4, BHH), 256, 0, stream>>>(
            az, gb, tb, MM, MM, MM, sM, sM, sM, 1.0f);
        ew_aI_minus_kernel<<<ewBlocks, 256, 0, stream>>>(tb, gb, 13.0f);
        gemm64<EPI_NONE, false><<<dim3(4, 4, BHH), 256, 0, stream>>>(
            zcur, gb, znew, MM, MM, MM, sM, sM, sM, 0.25f);
        float* tmp = zcur; zcur = znew; znew = tmp;
    }
    // zcur == a2_inv

    // 10. a3v = softmax(q_l . k^T) @ v
    a3v_flash<<<dim3(16, BHH), 256, 0, stream>>>(q_l, kk, vv, opart, lpart);
    a3v_combine<<<BHH * MM * DD / 256, 256, 0, stream>>>(opart, lpart, a3v);

    // 11. w = a2_inv @ a3v
    gemm64<EPI_NONE, false><<<dim3(1, 4, BHH), 256, 0, stream>>>(
        zcur, a3v, wm, MM, DD, MM, sM, (long)MM * DD, (long)MM * DD, 1.0f);

    // 12. attention out -> bf16 ctx
    attn_out_flash<<<dim3(NN / 64, BHH), 256, 0, stream>>>(qq, k_l, wm, ctx_bf);

    // 12b. depthwise conv added into ctx
    conv_kernel<<<dim3(NN / 256, BHH), 256, 0, stream>>>(vv, conv_w, ctx_bf);

    // 13. final: out = x + ctx @ Wout + bout  (MFMA)
    gemm_mfma<EPI_OUT><<<dim3(DIMM / 128, NROW / 128), 256, 0, stream>>>(
        ctx_bf, wot_bf, out, NROW, DIMM, DIMM,
        bout, x, nullptr, nullptr, nullptr);
}

// Round 6
// 847.636 us; speedup vs baseline: 6.3873x; 1.4215x over previous
//
#include <hip/hip_runtime.h>
#include <hip/hip_bf16.h>

// Problem constants
#define BB 4
#define NN 4096
#define DIMM 512
#define HH 8
#define DD 64
#define MM 256
#define LL 16
#define BHH 32
#define NROW (BB*NN)      // 16384
#define KS 33

typedef __attribute__((ext_vector_type(8))) short short8;   // 8 bf16 = 4 VGPR
typedef __attribute__((ext_vector_type(4))) float float4v;  // MFMA C/D

// ---------------------------------------------------------------------------
// LayerNorm: one block per row of [16384, 512] -> bf16 output
__launch_bounds__(256)
__global__ void ln_kernel(const float* __restrict__ x,
                          const float* __restrict__ w,
                          const float* __restrict__ bvec,
                          __hip_bfloat16* __restrict__ xn) {
    int row = blockIdx.x;
    int t = threadIdx.x;
    const float* xr = x + (long)row * DIMM;
    float v0 = xr[t];
    float v1 = xr[t + 256];
    __shared__ float red[256];
    red[t] = v0 + v1;
    __syncthreads();
    for (int off = 128; off > 0; off >>= 1) { if (t < off) red[t] += red[t + off]; __syncthreads(); }
    float mu = red[0] * (1.0f / DIMM);
    __syncthreads();
    float d0 = v0 - mu, d1 = v1 - mu;
    red[t] = d0 * d0 + d1 * d1;
    __syncthreads();
    for (int off = 128; off > 0; off >>= 1) { if (t < off) red[t] += red[t + off]; __syncthreads(); }
    float var = red[0] * (1.0f / DIMM);
    float rs = rsqrtf(var + 1e-5f);
    xn[(long)row * DIMM + t]       = __float2bfloat16(d0 * rs * w[t]       + bvec[t]);
    xn[(long)row * DIMM + t + 256] = __float2bfloat16(d1 * rs * w[t + 256] + bvec[t + 256]);
}

// ---------------------------------------------------------------------------
// Transpose + fp32->bf16: out[N][K] = bf16(in[K][N])
__launch_bounds__(256)
__global__ void transpose_bf16(const float* __restrict__ in, __hip_bfloat16* __restrict__ outp,
                               int K, int N) {
    __shared__ float tile[32][33];
    int k0 = blockIdx.y * 32, n0 = blockIdx.x * 32;
    int tx = threadIdx.x & 31, ty = threadIdx.x >> 5;  // ty 0..7
    #pragma unroll
    for (int i = 0; i < 32; i += 8)
        tile[ty + i][tx] = in[(long)(k0 + ty + i) * N + n0 + tx];
    __syncthreads();
    #pragma unroll
    for (int i = 0; i < 32; i += 8)
        outp[(long)(n0 + ty + i) * K + k0 + tx] = __float2bfloat16(tile[tx][ty + i]);
}

// ---------------------------------------------------------------------------
// bf16 MFMA GEMM: C[M,N] = A[M,K]bf16 @ Bt[N,K]bf16^T, fp32 epilogues.
// 128x128 tile, BK=64, 256 threads = 4 waves (2x2), 4x4 16x16x32 frags/wave.
enum { EPI_NONE = 0, EPI_QKV = 1, EPI_OUT = 2 };

template<int EPI>
__launch_bounds__(256)
__global__ void gemm_mfma(const __hip_bfloat16* __restrict__ A,
                          const __hip_bfloat16* __restrict__ Bt,
                          float* __restrict__ C, int M, int N, int K,
                          const float* __restrict__ bias,
                          const float* __restrict__ resid,
                          float* __restrict__ qp, float* __restrict__ kp, float* __restrict__ vp) {
    __shared__ __hip_bfloat16 As[128][64];
    __shared__ __hip_bfloat16 Bs[128][64];
    const int t = threadIdx.x;
    const int m0 = blockIdx.y * 128, n0 = blockIdx.x * 128;
    const int wave = t >> 6, lane = t & 63;
    const int wrow = wave >> 1, wcol = wave & 1;
    const int lm = lane & 15, quad = lane >> 4;

    float4v acc[4][4] = {};

    for (int k0 = 0; k0 < K; k0 += 64) {
        #pragma unroll
        for (int p = 0; p < 4; ++p) {
            int idx = t + p * 256;
            int r = idx >> 3, c8 = (idx & 7) * 8;
            *(uint4*)&As[r][c8] = *(const uint4*)&A[(long)(m0 + r) * K + k0 + c8];
            *(uint4*)&Bs[r][c8] = *(const uint4*)&Bt[(long)(n0 + r) * K + k0 + c8];
        }
        __syncthreads();
        #pragma unroll
        for (int ks = 0; ks < 64; ks += 32) {
            short8 af[4], bfr[4];
            #pragma unroll
            for (int i = 0; i < 4; ++i) {
                af[i]  = *(const short8*)&As[wrow * 64 + i * 16 + lm][ks + quad * 8];
                bfr[i] = *(const short8*)&Bs[wcol * 64 + i * 16 + lm][ks + quad * 8];
            }
            #pragma unroll
            for (int i = 0; i < 4; ++i)
                #pragma unroll
                for (int j = 0; j < 4; ++j)
                    acc[i][j] = __builtin_amdgcn_mfma_f32_16x16x32_bf16(af[i], bfr[j], acc[i][j], 0, 0, 0);
        }
        __syncthreads();
    }

    #pragma unroll
    for (int i = 0; i < 4; ++i) {
        #pragma unroll
        for (int j = 0; j < 4; ++j) {
            #pragma unroll
            for (int r = 0; r < 4; ++r) {
                int row = m0 + wrow * 64 + i * 16 + quad * 4 + r;
                int col = n0 + wcol * 64 + j * 16 + lm;
                float val = acc[i][j][r];
                if (EPI == EPI_QKV) {
                    int b = row >> 12, ii = row & (NN - 1);
                    int which = col >> 9, rem = col & 511;
                    int h = rem >> 6, dd = rem & 63;
                    long dst = (((long)(b * HH + h) * NN + ii) * DD + dd);
                    if (which == 0) qp[dst] = val * 0.125f;   // q * DHEAD^-0.5
                    else if (which == 1) kp[dst] = val;
                    else vp[dst] = val;
                } else { // EPI_OUT
                    C[(long)row * N + col] = val + bias[col] + resid[(long)row * N + col];
                }
            }
        }
    }
}

// ---------------------------------------------------------------------------
// Batched bf16 MFMA GEMM for pinv: 32 batches of 256x256x256.
// C[m][n] = scale * sum_k A[m][k]*Bt[n][k].
// Outputs (optional): CnBf = bf16(C) natural; CnF = fp32 C natural;
// CTbf[n][m] = bf16(diag*(m==n) + sgn*C[m][n])  (the transposed next operand).
__launch_bounds__(256)
__global__ void gemm_pinv(const __hip_bfloat16* __restrict__ A,
                          const __hip_bfloat16* __restrict__ Bt,
                          __hip_bfloat16* __restrict__ CnBf,
                          float* __restrict__ CnF,
                          __hip_bfloat16* __restrict__ CTbf,
                          float diag, float sgn, float scale) {
    __shared__ __hip_bfloat16 As[64][64];
    __shared__ __hip_bfloat16 Bs[64][64];
    __shared__ __hip_bfloat16 Tls[64][65];
    const int t = threadIdx.x;
    const long base = (long)blockIdx.z << 16;
    const int m0 = blockIdx.y * 64, n0 = blockIdx.x * 64;
    const int wave = t >> 6, lane = t & 63;
    const int wr = wave >> 1, wc = wave & 1;
    const int lm = lane & 15, quad = lane >> 4;
    const __hip_bfloat16* Ab = A + base;
    const __hip_bfloat16* Bb = Bt + base;

    float4v acc[2][2] = {};

    for (int k0 = 0; k0 < 256; k0 += 64) {
        #pragma unroll
        for (int p = 0; p < 2; ++p) {
            int idx = t + p * 256;
            int r = idx >> 3, c8 = (idx & 7) * 8;
            *(uint4*)&As[r][c8] = *(const uint4*)&Ab[(long)(m0 + r) * 256 + k0 + c8];
            *(uint4*)&Bs[r][c8] = *(const uint4*)&Bb[(long)(n0 + r) * 256 + k0 + c8];
        }
        __syncthreads();
        #pragma unroll
        for (int ks = 0; ks < 64; ks += 32) {
            short8 af[2], bfr[2];
            #pragma unroll
            for (int i = 0; i < 2; ++i) {
                af[i]  = *(const short8*)&As[wr * 32 + i * 16 + lm][ks + quad * 8];
                bfr[i] = *(const short8*)&Bs[wc * 32 + i * 16 + lm][ks + quad * 8];
            }
            #pragma unroll
            for (int i = 0; i < 2; ++i)
                #pragma unroll
                for (int j = 0; j < 2; ++j)
                    acc[i][j] = __builtin_amdgcn_mfma_f32_16x16x32_bf16(af[i], bfr[j], acc[i][j], 0, 0, 0);
        }
        __syncthreads();
    }

    #pragma unroll
    for (int i = 0; i < 2; ++i) {
        #pragma unroll
        for (int j = 0; j < 2; ++j) {
            #pragma unroll
            for (int r = 0; r < 4; ++r) {
                int row = wr * 32 + i * 16 + quad * 4 + r;
                int col = wc * 32 + j * 16 + lm;
                float v = acc[i][j][r] * scale;
                long off = base + (long)(m0 + row) * 256 + n0 + col;
                if (CnBf) CnBf[off] = __float2bfloat16(v);
                if (CnF)  CnF[off]  = v;
                float tv = sgn * v + ((m0 + row) == (n0 + col) ? diag : 0.0f);
                Tls[row][col] = __float2bfloat16(tv);
            }
        }
    }
    __syncthreads();
    if (CTbf) {
        int r = t & 63;
        #pragma unroll
        for (int u = 0; u < 16; ++u) {
            int c = u * 4 + (t >> 6);
            CTbf[base + (long)(n0 + c) * 256 + m0 + r] = Tls[r][c];
        }
    }
}

// ---------------------------------------------------------------------------
// pinv prep: a2_bf = bf16(a2); z0T = bf16(s*a2); z0n = bf16(s*a2^T). grid (4,4,32).
__launch_bounds__(256)
__global__ void pinv_prep(const float* __restrict__ a2, const float* __restrict__ scl,
                          __hip_bfloat16* __restrict__ a2bf, __hip_bfloat16* __restrict__ z0T,
                          __hip_bfloat16* __restrict__ z0n) {
    __shared__ float tl[64][65];
    const int t = threadIdx.x;
    const long base = (long)blockIdx.z << 16;
    const int i0 = blockIdx.y * 64, j0 = blockIdx.x * 64;
    float s = scl[0];
    #pragma unroll
    for (int p = 0; p < 16; ++p) {
        int idx = t + p * 256;
        int r = idx >> 6, c = idx & 63;
        long off = base + (long)(i0 + r) * 256 + j0 + c;
        float v = a2[off];
        a2bf[off] = __float2bfloat16(v);
        float zv = v * s;
        z0T[off] = __float2bfloat16(zv);
        tl[r][c] = zv;
    }
    __syncthreads();
    int r = t & 63;
    #pragma unroll
    for (int u = 0; u < 16; ++u) {
        int c = u * 4 + (t >> 6);
        z0n[base + (long)(j0 + c) * 256 + i0 + r] = __float2bfloat16(tl[r][c]);
    }
}

// ---------------------------------------------------------------------------
// Generic fp32 tiled GEMM (kept for sim2 / final pinv iter / wm). 64x64 tile, BK=16.
template<int EPI, bool TRANSB>
__launch_bounds__(256)
__global__ void gemm64(const float* __restrict__ A, const float* __restrict__ Bm,
                       float* __restrict__ C,
                       int M, int N, int K, long sA, long sB, long sC, float alpha) {
    const int bz = blockIdx.z;
    const float* Ab = A + (long)bz * sA;
    const float* Bb = Bm + (long)bz * sB;
    float* Cb = C + (long)bz * sC;

    __shared__ float As[16][64];
    __shared__ float Bs[16][64];

    const int tid = threadIdx.x;
    const int tx = tid & 15;
    const int ty = tid >> 4;
    const int m0 = blockIdx.y * 64;
    const int n0 = blockIdx.x * 64;

    float acc[4][4] = {};

    for (int k0 = 0; k0 < K; k0 += 16) {
        {
            int r  = tid >> 2;
            int kk = (tid & 3) * 4;
            float4 va = *(const float4*)(Ab + (long)(m0 + r) * K + k0 + kk);
            As[kk + 0][r] = va.x; As[kk + 1][r] = va.y; As[kk + 2][r] = va.z; As[kk + 3][r] = va.w;
        }
        if (!TRANSB) {
            int kk = tid >> 4;
            int j  = (tid & 15) * 4;
            float4 vb = *(const float4*)(Bb + (long)(k0 + kk) * N + n0 + j);
            Bs[kk][j + 0] = vb.x; Bs[kk][j + 1] = vb.y; Bs[kk][j + 2] = vb.z; Bs[kk][j + 3] = vb.w;
        } else {
            int j  = tid >> 2;
            int kk = (tid & 3) * 4;
            float4 vb = *(const float4*)(Bb + (long)(n0 + j) * K + k0 + kk);
            Bs[kk + 0][j] = vb.x; Bs[kk + 1][j] = vb.y; Bs[kk + 2][j] = vb.z; Bs[kk + 3][j] = vb.w;
        }
        __syncthreads();
        #pragma unroll
        for (int kk = 0; kk < 16; ++kk) {
            float a0 = As[kk][ty * 4 + 0], a1 = As[kk][ty * 4 + 1];
            float a2 = As[kk][ty * 4 + 2], a3 = As[kk][ty * 4 + 3];
            float b0 = Bs[kk][tx * 4 + 0], b1 = Bs[kk][tx * 4 + 1];
            float b2 = Bs[kk][tx * 4 + 2], b3 = Bs[kk][tx * 4 + 3];
            acc[0][0] += a0 * b0; acc[0][1] += a0 * b1; acc[0][2] += a0 * b2; acc[0][3] += a0 * b3;
            acc[1][0] += a1 * b0; acc[1][1] += a1 * b1; acc[1][2] += a1 * b2; acc[1][3] += a1 * b3;
            acc[2][0] += a2 * b0; acc[2][1] += a2 * b1; acc[2][2] += a2 * b2; acc[2][3] += a2 * b3;
            acc[3][0] += a3 * b0; acc[3][1] += a3 * b1; acc[3][2] += a3 * b2; acc[3][3] += a3 * b3;
        }
        __syncthreads();
    }

    #pragma unroll
    for (int r = 0; r < 4; ++r)
        #pragma unroll
        for (int c = 0; c < 4; ++c)
            Cb[(long)(m0 + ty * 4 + r) * N + n0 + tx * 4 + c] = acc[r][c] * alpha;
}

// ---------------------------------------------------------------------------
// Landmark means
__global__ void landmark_kernel(const float* __restrict__ qq, const float* __restrict__ kk,
                                float* __restrict__ q_l, float* __restrict__ k_l) {
    int bh = blockIdx.x >> 8;
    int m  = blockIdx.x & 255;
    int d  = threadIdx.x;     // 64
    const float* src = (blockIdx.y ? kk : qq) + ((long)bh * NN + m * LL) * DD + d;
    float s = 0.f;
    #pragma unroll
    for (int t = 0; t < LL; ++t) s += src[(long)t * DD];
    float* dst = blockIdx.y ? k_l : q_l;
    dst[((long)bh * MM + m) * DD + d] = s * (1.0f / LL);
}

// ---------------------------------------------------------------------------
__launch_bounds__(256)
__global__ void softmax256_kernel(float* __restrict__ a) {
    long row = blockIdx.x;
    int t = threadIdx.x;
    float* r = a + row * 256;
    float v = r[t];
    __shared__ float red[256];
    red[t] = v;
    __syncthreads();
    for (int off = 128; off > 0; off >>= 1) { if (t < off) red[t] = fmaxf(red[t], red[t + off]); __syncthreads(); }
    float mx = red[0];
    __syncthreads();
    float e = __expf(v - mx);
    red[t] = e;
    __syncthreads();
    for (int off = 128; off > 0; off >>= 1) { if (t < off) red[t] += red[t + off]; __syncthreads(); }
    r[t] = e / red[0];
}

// ---------------------------------------------------------------------------
__launch_bounds__(256)
__global__ void redmax_kernel(const float* __restrict__ a2, float* __restrict__ red) {
    int bh = blockIdx.x;
    int t = threadIdx.x;
    const float* Ab = a2 + ((long)bh << 16);
    float rs = 0.f, cs = 0.f;
    for (int c = 0; c < 256; ++c) rs += Ab[t * 256 + c];
    for (int r = 0; r < 256; ++r) cs += Ab[r * 256 + t];
    __shared__ float m1[256], m2[256];
    m1[t] = rs; m2[t] = cs;
    __syncthreads();
    for (int off = 128; off > 0; off >>= 1) {
        if (t < off) { m1[t] = fmaxf(m1[t], m1[t + off]); m2[t] = fmaxf(m2[t], m2[t + off]); }
        __syncthreads();
    }
    if (t == 0) { red[bh] = m1[0]; red[32 + bh] = m2[0]; }
}

__global__ void scale_kernel(const float* __restrict__ red, float* __restrict__ scl) {
    __shared__ float a[32], b[32];
    int t = threadIdx.x;  // 32
    a[t] = red[t]; b[t] = red[32 + t];
    __syncthreads();
    for (int off = 16; off > 0; off >>= 1) {
        if (t < off) { a[t] = fmaxf(a[t], a[t + off]); b[t] = fmaxf(b[t], b[t + off]); }
        __syncthreads();
    }
    if (t == 0) scl[0] = 1.0f / (a[0] * b[0]);
}

__global__ void ew_aI_minus_kernel(const float* __restrict__ X, float* __restrict__ Y, float alpha) {
    long idx = (long)blockIdx.x * 256 + threadIdx.x;
    int e = (int)(idx & 65535);
    int i = e >> 8, j = e & 255;
    Y[idx] = ((i == j) ? alpha : 0.0f) - X[idx];
}

// ---------------------------------------------------------------------------
// a3v flash-style, stage 1. (verified rounds 3-5; qs/Ks padded to kill 16-way conflicts)
__launch_bounds__(256)
__global__ void a3v_flash(const float* __restrict__ q_l, const float* __restrict__ kk,
                          const float* __restrict__ vv,
                          float* __restrict__ opart, float* __restrict__ lpart) {
    const int bh = blockIdx.y;
    const int mt = blockIdx.x >> 2;
    const int ns = blockIdx.x & 3;
    const int t  = threadIdx.x;
    const int tx = t & 15;
    const int ty = t >> 4;

    __shared__ float qs[64][65];
    __shared__ float Ks[64][65];
    __shared__ float Vs[64][64];
    __shared__ float Ps[64][64];
    __shared__ float lred[64][16];

    const float* qbase = q_l + ((long)bh * MM + mt * 64) * DD;
    #pragma unroll
    for (int i = 0; i < 4; ++i) {
        int idx4 = t + 256 * i;
        int r = idx4 >> 4, d4 = (idx4 & 15) << 2;
        float4 v4 = *(const float4*)(qbase + r * DD + d4);
        qs[d4 + 0][r] = v4.x; qs[d4 + 1][r] = v4.y; qs[d4 + 2][r] = v4.z; qs[d4 + 3][r] = v4.w;
    }

    float acc_o[4][4] = {};
    float lacc[4] = {};
    const float* kbase = kk + ((long)bh * NN + ns * 1024) * DD;
    const float* vbase = vv + ((long)bh * NN + ns * 1024) * DD;
    __syncthreads();

    for (int ch = 0; ch < 16; ++ch) {
        #pragma unroll
        for (int i = 0; i < 4; ++i) {
            int idx4 = t + 256 * i;
            int c = idx4 >> 4, d4 = (idx4 & 15) << 2;
            float4 kv = *(const float4*)(kbase + (long)(ch * 64 + c) * DD + d4);
            float4 vv4 = *(const float4*)(vbase + (long)(ch * 64 + c) * DD + d4);
            Ks[d4 + 0][c] = kv.x; Ks[d4 + 1][c] = kv.y; Ks[d4 + 2][c] = kv.z; Ks[d4 + 3][c] = kv.w;
            *(float4*)&Vs[c][d4] = vv4;
        }
        __syncthreads();

        float s[4][4] = {};
        #pragma unroll 16
        for (int d = 0; d < 64; ++d) {
            float a0 = qs[d][ty * 4 + 0], a1 = qs[d][ty * 4 + 1];
            float a2 = qs[d][ty * 4 + 2], a3 = qs[d][ty * 4 + 3];
            float b0 = Ks[d][tx * 4 + 0], b1 = Ks[d][tx * 4 + 1];
            float b2 = Ks[d][tx * 4 + 2], b3 = Ks[d][tx * 4 + 3];
            s[0][0] += a0 * b0; s[0][1] += a0 * b1; s[0][2] += a0 * b2; s[0][3] += a0 * b3;
            s[1][0] += a1 * b0; s[1][1] += a1 * b1; s[1][2] += a1 * b2; s[1][3] += a1 * b3;
            s[2][0] += a2 * b0; s[2][1] += a2 * b1; s[2][2] += a2 * b2; s[2][3] += a2 * b3;
            s[3][0] += a3 * b0; s[3][1] += a3 * b1; s[3][2] += a3 * b2; s[3][3] += a3 * b3;
        }
        #pragma unroll
        for (int i = 0; i < 4; ++i) {
            float e0 = __expf(s[i][0]), e1 = __expf(s[i][1]);
            float e2 = __expf(s[i][2]), e3 = __expf(s[i][3]);
            lacc[i] += e0 + e1 + e2 + e3;
            float4 p4; p4.x = e0; p4.y = e1; p4.z = e2; p4.w = e3;
            *(float4*)&Ps[ty * 4 + i][tx * 4] = p4;
        }
        __syncthreads();

        #pragma unroll 16
        for (int c = 0; c < 64; ++c) {
            float a0 = Ps[ty * 4 + 0][c], a1 = Ps[ty * 4 + 1][c];
            float a2 = Ps[ty * 4 + 2][c], a3 = Ps[ty * 4 + 3][c];
            float b0 = Vs[c][tx * 4 + 0], b1 = Vs[c][tx * 4 + 1];
            float b2 = Vs[c][tx * 4 + 2], b3 = Vs[c][tx * 4 + 3];
            acc_o[0][0] += a0 * b0; acc_o[0][1] += a0 * b1; acc_o[0][2] += a0 * b2; acc_o[0][3] += a0 * b3;
            acc_o[1][0] += a1 * b0; acc_o[1][1] += a1 * b1; acc_o[1][2] += a1 * b2; acc_o[1][3] += a1 * b3;
            acc_o[2][0] += a2 * b0; acc_o[2][1] += a2 * b1; acc_o[2][2] += a2 * b2; acc_o[2][3] += a2 * b3;
            acc_o[3][0] += a3 * b0; acc_o[3][1] += a3 * b1; acc_o[3][2] += a3 * b2; acc_o[3][3] += a3 * b3;
        }
        __syncthreads();
    }

    const long pbase = ((long)((bh * 4 + mt) * 4 + ns)) << 12;
    #pragma unroll
    for (int i = 0; i < 4; ++i) {
        float4 w4; w4.x = acc_o[i][0]; w4.y = acc_o[i][1]; w4.z = acc_o[i][2]; w4.w = acc_o[i][3];
        *(float4*)(opart + pbase + (ty * 4 + i) * 64 + tx * 4) = w4;
        lred[ty * 4 + i][tx] = lacc[i];
    }
    __syncthreads();
    if (t < 64) {
        float sum = 0.f;
        #pragma unroll
        for (int u = 0; u < 16; ++u) sum += lred[t][u];
        lpart[((bh * 4 + mt) * 4 + ns) * 64 + t] = sum;
    }
}

__global__ void a3v_combine(const float* __restrict__ opart, const float* __restrict__ lpart,
                            float* __restrict__ a3v) {
    int idx = blockIdx.x * 256 + threadIdx.x;
    int d  = idx & 63;
    int m  = (idx >> 6) & 255;
    int bh = idx >> 14;
    int mt = m >> 6, r = m & 63;
    int pb = (bh * 4 + mt) * 4;
    float osum = 0.f, lsum = 0.f;
    #pragma unroll
    for (int ns = 0; ns < 4; ++ns) {
        osum += opart[(((long)(pb + ns)) << 12) + r * 64 + d];
        lsum += lpart[(pb + ns) * 64 + r];
    }
    a3v[((long)bh * MM + m) * DD + d] = osum / lsum;
}

// ---------------------------------------------------------------------------
// attn_out flash-style: writes bf16 ctx. Kt padded [64][65]; Ps separate.
__launch_bounds__(256)
__global__ void attn_out_flash(const float* __restrict__ qq, const float* __restrict__ k_l,
                               const float* __restrict__ wmat,
                               __hip_bfloat16* __restrict__ ctx) {
    const int bh = blockIdx.y;
    const int b  = bh >> 3, h = bh & 7;
    const int i0 = blockIdx.x * 64;
    const int t  = threadIdx.x;
    const int tx = t & 15;
    const int ty = t >> 4;

    __shared__ float qs[64][65];
    __shared__ float Kt[64][65];
    __shared__ float Ps[64][64];
    __shared__ float Ws[64][64];
    __shared__ float lred[64][16];
    __shared__ float dsum[64];

    const float* qbase = qq + ((long)bh * NN + i0) * DD;
    #pragma unroll
    for (int i = 0; i < 4; ++i) {
        int idx4 = t + 256 * i;
        int r = idx4 >> 4, d4 = (idx4 & 15) << 2;
        float4 v4 = *(const float4*)(qbase + r * DD + d4);
        qs[d4 + 0][r] = v4.x; qs[d4 + 1][r] = v4.y; qs[d4 + 2][r] = v4.z; qs[d4 + 3][r] = v4.w;
    }

    float acc_o[4][4] = {};
    float lacc[4] = {};
    const float* klbase = k_l + ((long)bh * MM) * DD;
    const float* wbase  = wmat + ((long)bh * MM) * DD;

    for (int ch = 0; ch < 4; ++ch) {
        __syncthreads();
        #pragma unroll
        for (int i = 0; i < 4; ++i) {
            int idx4 = t + 256 * i;
            int c = idx4 >> 4, d4 = (idx4 & 15) << 2;
            float4 kv = *(const float4*)(klbase + (long)(ch * 64 + c) * DD + d4);
            float4 wv = *(const float4*)(wbase  + (long)(ch * 64 + c) * DD + d4);
            Kt[d4 + 0][c] = kv.x; Kt[d4 + 1][c] = kv.y; Kt[d4 + 2][c] = kv.z; Kt[d4 + 3][c] = kv.w;
            *(float4*)&Ws[c][d4] = wv;
        }
        __syncthreads();

        float s[4][4] = {};
        #pragma unroll 16
        for (int d = 0; d < 64; ++d) {
            float a0 = qs[d][ty * 4 + 0], a1 = qs[d][ty * 4 + 1];
            float a2 = qs[d][ty * 4 + 2], a3 = qs[d][ty * 4 + 3];
            float b0 = Kt[d][tx * 4 + 0], b1 = Kt[d][tx * 4 + 1];
            float b2 = Kt[d][tx * 4 + 2], b3 = Kt[d][tx * 4 + 3];
            s[0][0] += a0 * b0; s[0][1] += a0 * b1; s[0][2] += a0 * b2; s[0][3] += a0 * b3;
            s[1][0] += a1 * b0; s[1][1] += a1 * b1; s[1][2] += a1 * b2; s[1][3] += a1 * b3;
            s[2][0] += a2 * b0; s[2][1] += a2 * b1; s[2][2] += a2 * b2; s[2][3] += a2 * b3;
            s[3][0] += a3 * b0; s[3][1] += a3 * b1; s[3][2] += a3 * b2; s[3][3] += a3 * b3;
        }
        __syncthreads();

        #pragma unroll
        for (int i = 0; i < 4; ++i) {
            float e0 = __expf(s[i][0]), e1 = __expf(s[i][1]);
            float e2 = __expf(s[i][2]), e3 = __expf(s[i][3]);
            lacc[i] += e0 + e1 + e2 + e3;
            float4 p4; p4.x = e0; p4.y = e1; p4.z = e2; p4.w = e3;
            *(float4*)&Ps[ty * 4 + i][tx * 4] = p4;
        }
        __syncthreads();

        #pragma unroll 16
        for (int c = 0; c < 64; ++c) {
            float a0 = Ps[ty * 4 + 0][c], a1 = Ps[ty * 4 + 1][c];
            float a2 = Ps[ty * 4 + 2][c], a3 = Ps[ty * 4 + 3][c];
            float b0 = Ws[c][tx * 4 + 0], b1 = Ws[c][tx * 4 + 1];
            float b2 = Ws[c][tx * 4 + 2], b3 = Ws[c][tx * 4 + 3];
            acc_o[0][0] += a0 * b0; acc_o[0][1] += a0 * b1; acc_o[0][2] += a0 * b2; acc_o[0][3] += a0 * b3;
            acc_o[1][0] += a1 * b0; acc_o[1][1] += a1 * b1; acc_o[1][2] += a1 * b2; acc_o[1][3] += a1 * b3;
            acc_o[2][0] += a2 * b0; acc_o[2][1] += a2 * b1; acc_o[2][2] += a2 * b2; acc_o[2][3] += a2 * b3;
            acc_o[3][0] += a3 * b0; acc_o[3][1] += a3 * b1; acc_o[3][2] += a3 * b2; acc_o[3][3] += a3 * b3;
        }
    }
    __syncthreads();

    #pragma unroll
    for (int i = 0; i < 4; ++i) lred[ty * 4 + i][tx] = lacc[i];
    __syncthreads();
    if (t < 64) {
        float ssum = 0.f;
        #pragma unroll
        for (int u = 0; u < 16; ++u) ssum += lred[t][u];
        dsum[t] = 1.0f / ssum;
    }
    __syncthreads();

    #pragma unroll
    for (int i = 0; i < 4; ++i) {
        float inv = dsum[ty * 4 + i];
        float4 o4; o4.x = acc_o[i][0] * inv; o4.y = acc_o[i][1] * inv;
        o4.z = acc_o[i][2] * inv; o4.w = acc_o[i][3] * inv;
        *(float4*)&Ps[ty * 4 + i][tx * 4] = o4;
    }
    __syncthreads();

    const int d = t & 63, rsub = t >> 6;
    __hip_bfloat16* cbase = ctx + ((long)b * NN + i0) * DIMM + h * DD + d;
    #pragma unroll
    for (int p = 0; p < 16; ++p) {
        int r = p * 4 + rsub;
        cbase[(long)r * DIMM] = __float2bfloat16(Ps[r][d]);
    }
}

// ---------------------------------------------------------------------------
// Depthwise 33-tap seq conv on v, added into bf16 ctx.
__launch_bounds__(256)
__global__ void conv_kernel(const float* __restrict__ vv, const float* __restrict__ convw,
                            __hip_bfloat16* __restrict__ ctx) {
    __shared__ float vs[256 + 32][DD];   // 73.7 KB
    __shared__ float cw[KS];
    const int bh = blockIdx.y;
    const int b = bh >> 3, h = bh & 7;
    const int s0 = blockIdx.x * 256;
    const int t = threadIdx.x;
    if (t < KS) cw[t] = convw[h * KS + t];
    const int d = t & 63, sub = t >> 6;
    const float* vb = vv + (long)bh * NN * DD;
    for (int r = sub; r < 256 + 32; r += 4) {
        int s = s0 - 16 + r;
        vs[r][d] = (s >= 0 && s < NN) ? vb[(long)s * DD + d] : 0.0f;
    }
    __syncthreads();
    __hip_bfloat16* cb = ctx + ((long)b * NN + s0) * DIMM + h * DD + d;
    for (int r0 = sub * 64; r0 < sub * 64 + 64; ++r0) {
        float o = 0.f;
        #pragma unroll
        for (int k = 0; k < KS; ++k) o += cw[k] * vs[r0 + k][d];
        long off = (long)r0 * DIMM;
        cb[off] = __float2bfloat16(__bfloat162float(cb[off]) + o);
    }
}

// ---------------------------------------------------------------------------
extern "C" void kernel_launch(void* const* d_in, const int* in_sizes, int n_in,
                              void* d_out, int out_size, void* d_ws, size_t ws_size,
                              hipStream_t stream) {
    const float* x      = (const float*)d_in[0];
    const float* norm_w = (const float*)d_in[1];
    const float* norm_b = (const float*)d_in[2];
    const float* Wqkv   = (const float*)d_in[3];
    const float* Wout   = (const float*)d_in[4];
    const float* bout   = (const float*)d_in[5];
    const float* conv_w = (const float*)d_in[6];
    float* out = (float*)d_out;

    float* ws = (float*)d_ws;
    size_t o = 0;
    auto alloc = [&](size_t n) { float* p = ws + o; o += n; return p; };
    auto allocb = [&](size_t n) { return (__hip_bfloat16*)alloc((n + 1) / 2); };

    __hip_bfloat16* xn_bf  = allocb((size_t)NROW * DIMM);
    __hip_bfloat16* wqt_bf = allocb((size_t)3 * DIMM * DIMM);
    __hip_bfloat16* wot_bf = allocb((size_t)DIMM * DIMM);
    __hip_bfloat16* ctx_bf = allocb((size_t)NROW * DIMM);
    float* qq   = alloc((size_t)BHH * NN * DD);
    float* kk   = alloc((size_t)BHH * NN * DD);
    float* vv   = alloc((size_t)BHH * NN * DD);
    float* q_l  = alloc((size_t)BHH * MM * DD);
    float* k_l  = alloc((size_t)BHH * MM * DD);
    float* a2   = alloc((size_t)BHH * MM * MM);
    float* zb   = alloc((size_t)BHH * MM * MM);
    float* az   = alloc((size_t)BHH * MM * MM);
    float* gb   = alloc((size_t)BHH * MM * MM);
    float* tb   = alloc((size_t)BHH * MM * MM);
    float* z2   = alloc((size_t)BHH * MM * MM);
    float* a3v  = alloc((size_t)BHH * MM * DD);
    float* wm   = alloc((size_t)BHH * MM * DD);
    float* opart = alloc((size_t)BHH * 4 * 4 * 64 * 64);
    float* lpart = alloc((size_t)BHH * 4 * 4 * 64);
    float* red  = alloc(64);
    float* scl  = alloc(64);

    // bf16 pinv buffers aliased onto fp32 buffers dead during the bf16 phase.
    // Each is 32*256*256 bf16 = 1,048,576 floats of space.
    const size_t HB = 1048576;
    __hip_bfloat16* a2bf = (__hip_bfloat16*)az;
    __hip_bfloat16* znA  = (__hip_bfloat16*)(az + HB);
    __hip_bfloat16* znB  = (__hip_bfloat16*)gb;
    __hip_bfloat16* zTA  = (__hip_bfloat16*)(gb + HB);
    __hip_bfloat16* zTB  = (__hip_bfloat16*)tb;
    __hip_bfloat16* azbf = (__hip_bfloat16*)(tb + HB);
    __hip_bfloat16* g1T  = (__hip_bfloat16*)z2;
    __hip_bfloat16* g2T  = (__hip_bfloat16*)(z2 + HB);
    __hip_bfloat16* g3T  = (__hip_bfloat16*)opart;

    // 1. LayerNorm -> bf16
    ln_kernel<<<NROW, 256, 0, stream>>>(x, norm_w, norm_b, xn_bf);

    // 1b. transpose+convert weights
    transpose_bf16<<<dim3(3 * DIMM / 32, DIMM / 32), 256, 0, stream>>>(Wqkv, wqt_bf, DIMM, 3 * DIMM);
    transpose_bf16<<<dim3(DIMM / 32, DIMM / 32), 256, 0, stream>>>(Wout, wot_bf, DIMM, DIMM);

    // 2. QKV GEMM (MFMA) with scatter epilogue
    gemm_mfma<EPI_QKV><<<dim3(3 * DIMM / 128, NROW / 128), 256, 0, stream>>>(
        xn_bf, wqt_bf, nullptr, NROW, 3 * DIMM, DIMM,
        nullptr, nullptr, qq, kk, vv);

    // 3. Landmarks
    landmark_kernel<<<dim3(BHH * MM, 2), 64, 0, stream>>>(qq, kk, q_l, k_l);

    // 4. sim2 = q_l @ k_l^T
    gemm64<EPI_NONE, true><<<dim3(4, 4, BHH), 256, 0, stream>>>(
        q_l, k_l, a2, MM, MM, DD, (long)MM * DD, (long)MM * DD, (long)MM * MM, 1.0f);

    // 5. softmax rows -> a2
    softmax256_kernel<<<BHH * MM, 256, 0, stream>>>(a2);

    // 6-7. pinv normalization scalar
    redmax_kernel<<<BHH, 256, 0, stream>>>(a2, red);
    scale_kernel<<<1, 32, 0, stream>>>(red, scl);

    // 8. pinv prep: a2_bf, z0^T, z0 (bf16)
    dim3 g512(4, 4, BHH);
    pinv_prep<<<g512, 256, 0, stream>>>(a2, scl, a2bf, zTA, znA);

    // 9. Newton-Schulz: iters 0-4 bf16 MFMA with fused aI - X^T epilogues
    __hip_bfloat16 *zn = znA, *zT = zTA, *zn2 = znB, *zT2 = zTB;
    for (int it = 0; it < 5; ++it) {
        gemm_pinv<<<g512, 256, 0, stream>>>(a2bf, zT, azbf, nullptr, g1T, 7.0f, -1.0f, 1.0f);
        gemm_pinv<<<g512, 256, 0, stream>>>(azbf, g1T, nullptr, nullptr, g2T, 15.0f, -1.0f, 1.0f);
        gemm_pinv<<<g512, 256, 0, stream>>>(azbf, g2T, nullptr, nullptr, g3T, 13.0f, -1.0f, 1.0f);
        gemm_pinv<<<g512, 256, 0, stream>>>(zn, g3T, zn2, (it == 4) ? zb : nullptr, zT2,
                                            0.0f, 1.0f, 0.25f);
        __hip_bfloat16* tmp;
        tmp = zn; zn = zn2; zn2 = tmp;
        tmp = zT; zT = zT2; zT2 = tmp;
    }

    // 9b. final iteration in fp32 (cleans up bf16 noise; NS is contractive)
    const long sM = (long)MM * MM;
    const int ewBlocks = BHH * MM * MM / 256;
    gemm64<EPI_NONE, false><<<g512, 256, 0, stream>>>(
        a2, zb, az, MM, MM, MM, sM, sM, sM, 1.0f);
    ew_aI_minus_kernel<<<ewBlocks, 256, 0, stream>>>(az, gb, 7.0f);
    gemm64<EPI_NONE, false><<<g512, 256, 0, stream>>>(
        az, gb, tb, MM, MM, MM, sM, sM, sM, 1.0f);
    ew_aI_minus_kernel<<<ewBlocks, 256, 0, stream>>>(tb, gb, 15.0f);
    gemm64<EPI_NONE, false><<<g512, 256, 0, stream>>>(
        az, gb, tb, MM, MM, MM, sM, sM, sM, 1.0f);
    ew_aI_minus_kernel<<<ewBlocks, 256, 0, stream>>>(tb, gb, 13.0f);
    gemm64<EPI_NONE, false><<<g512, 256, 0, stream>>>(
        zb, gb, z2, MM, MM, MM, sM, sM, sM, 0.25f);
    float* zcur = z2;   // a2_inv (fp32)

    // 10. a3v = softmax(q_l . k^T) @ v
    a3v_flash<<<dim3(16, BHH), 256, 0, stream>>>(q_l, kk, vv, opart, lpart);
    a3v_combine<<<BHH * MM * DD / 256, 256, 0, stream>>>(opart, lpart, a3v);

    // 11. w = a2_inv @ a3v
    gemm64<EPI_NONE, false><<<dim3(1, 4, BHH), 256, 0, stream>>>(
        zcur, a3v, wm, MM, DD, MM, sM, (long)MM * DD, (long)MM * DD, 1.0f);

    // 12. attention out -> bf16 ctx
    attn_out_flash<<<dim3(NN / 64, BHH), 256, 0, stream>>>(qq, k_l, wm, ctx_bf);

    // 12b. depthwise conv added into ctx
    conv_kernel<<<dim3(NN / 256, BHH), 256, 0, stream>>>(vv, conv_w, ctx_bf);

    // 13. final: out = x + ctx @ Wout + bout  (MFMA)
    gemm_mfma<EPI_OUT><<<dim3(DIMM / 128, NROW / 128), 256, 0, stream>>>(
        ctx_bf, wot_bf, out, NROW, DIMM, DIMM,
        bout, x, nullptr, nullptr, nullptr);
}

// Round 7
// 571.759 us; speedup vs baseline: 9.4692x; 1.4825x over previous
//
#include <hip/hip_runtime.h>
#include <hip/hip_bf16.h>

// Problem constants
#define BB 4
#define NN 4096
#define DIMM 512
#define HH 8
#define DD 64
#define MM 256
#define LL 16
#define BHH 32
#define NROW (BB*NN)      // 16384
#define KS 33

typedef __attribute__((ext_vector_type(8))) short short8;   // 8 bf16 = 4 VGPR
typedef __attribute__((ext_vector_type(4))) float float4v;  // MFMA C/D

static __device__ __forceinline__ unsigned short bf16_bits(float v) {
    __hip_bfloat16 h = __float2bfloat16(v);
    return *reinterpret_cast<unsigned short*>(&h);
}

// ---------------------------------------------------------------------------
// LayerNorm: one block per row of [16384, 512] -> bf16 output
__launch_bounds__(256)
__global__ void ln_kernel(const float* __restrict__ x,
                          const float* __restrict__ w,
                          const float* __restrict__ bvec,
                          __hip_bfloat16* __restrict__ xn) {
    int row = blockIdx.x;
    int t = threadIdx.x;
    const float* xr = x + (long)row * DIMM;
    float v0 = xr[t];
    float v1 = xr[t + 256];
    __shared__ float red[256];
    red[t] = v0 + v1;
    __syncthreads();
    for (int off = 128; off > 0; off >>= 1) { if (t < off) red[t] += red[t + off]; __syncthreads(); }
    float mu = red[0] * (1.0f / DIMM);
    __syncthreads();
    float d0 = v0 - mu, d1 = v1 - mu;
    red[t] = d0 * d0 + d1 * d1;
    __syncthreads();
    for (int off = 128; off > 0; off >>= 1) { if (t < off) red[t] += red[t + off]; __syncthreads(); }
    float var = red[0] * (1.0f / DIMM);
    float rs = rsqrtf(var + 1e-5f);
    xn[(long)row * DIMM + t]       = __float2bfloat16(d0 * rs * w[t]       + bvec[t]);
    xn[(long)row * DIMM + t + 256] = __float2bfloat16(d1 * rs * w[t + 256] + bvec[t + 256]);
}

// ---------------------------------------------------------------------------
// Transpose + fp32->bf16: out[N][K] = bf16(in[K][N])
__launch_bounds__(256)
__global__ void transpose_bf16(const float* __restrict__ in, __hip_bfloat16* __restrict__ outp,
                               int K, int N) {
    __shared__ float tile[32][33];
    int k0 = blockIdx.y * 32, n0 = blockIdx.x * 32;
    int tx = threadIdx.x & 31, ty = threadIdx.x >> 5;  // ty 0..7
    #pragma unroll
    for (int i = 0; i < 32; i += 8)
        tile[ty + i][tx] = in[(long)(k0 + ty + i) * N + n0 + tx];
    __syncthreads();
    #pragma unroll
    for (int i = 0; i < 32; i += 8)
        outp[(long)(n0 + ty + i) * K + k0 + tx] = __float2bfloat16(tile[tx][ty + i]);
}

// ---------------------------------------------------------------------------
// bf16 MFMA GEMM: C[M,N] = A[M,K]bf16 @ Bt[N,K]bf16^T.
// 128x128 tile, BK=64, 256 threads = 4 waves (2x2), 4x4 16x16x32 frags/wave.
// EPI_QKV: scatter q,k bf16 [bh][seq][d] and v transposed bf16 vt[bh][dd][seq].
enum { EPI_NONE = 0, EPI_QKV = 1, EPI_OUT = 2 };

template<int EPI>
__launch_bounds__(256)
__global__ void gemm_mfma(const __hip_bfloat16* __restrict__ A,
                          const __hip_bfloat16* __restrict__ Bt,
                          float* __restrict__ C, int M, int N, int K,
                          const float* __restrict__ bias,
                          const float* __restrict__ resid,
                          __hip_bfloat16* __restrict__ qb,
                          __hip_bfloat16* __restrict__ kb,
                          __hip_bfloat16* __restrict__ vtb) {
    __shared__ __hip_bfloat16 As[128][64];
    __shared__ __hip_bfloat16 Bs[128][64];
    const int t = threadIdx.x;
    const int m0 = blockIdx.y * 128, n0 = blockIdx.x * 128;
    const int wave = t >> 6, lane = t & 63;
    const int wrow = wave >> 1, wcol = wave & 1;
    const int lm = lane & 15, quad = lane >> 4;

    float4v acc[4][4] = {};

    for (int k0 = 0; k0 < K; k0 += 64) {
        #pragma unroll
        for (int p = 0; p < 4; ++p) {
            int idx = t + p * 256;
            int r = idx >> 3, c8 = (idx & 7) * 8;
            *(uint4*)&As[r][c8] = *(const uint4*)&A[(long)(m0 + r) * K + k0 + c8];
            *(uint4*)&Bs[r][c8] = *(const uint4*)&Bt[(long)(n0 + r) * K + k0 + c8];
        }
        __syncthreads();
        #pragma unroll
        for (int ks = 0; ks < 64; ks += 32) {
            short8 af[4], bfr[4];
            #pragma unroll
            for (int i = 0; i < 4; ++i) {
                af[i]  = *(const short8*)&As[wrow * 64 + i * 16 + lm][ks + quad * 8];
                bfr[i] = *(const short8*)&Bs[wcol * 64 + i * 16 + lm][ks + quad * 8];
            }
            #pragma unroll
            for (int i = 0; i < 4; ++i)
                #pragma unroll
                for (int j = 0; j < 4; ++j)
                    acc[i][j] = __builtin_amdgcn_mfma_f32_16x16x32_bf16(af[i], bfr[j], acc[i][j], 0, 0, 0);
        }
        __syncthreads();
    }

    #pragma unroll
    for (int i = 0; i < 4; ++i) {
        #pragma unroll
        for (int j = 0; j < 4; ++j) {
            int rowb = m0 + wrow * 64 + i * 16 + quad * 4;
            int col  = n0 + wcol * 64 + j * 16 + lm;
            if (EPI == EPI_QKV) {
                int b = rowb >> 12, seq = rowb & (NN - 1);
                int which = col >> 9, rem = col & 511;
                int h = rem >> 6, dd = rem & 63;
                int bh = b * HH + h;
                if (which == 0) {
                    #pragma unroll
                    for (int r = 0; r < 4; ++r)
                        qb[((long)bh * NN + seq + r) * DD + dd] = __float2bfloat16(acc[i][j][r] * 0.125f);
                } else if (which == 1) {
                    #pragma unroll
                    for (int r = 0; r < 4; ++r)
                        kb[((long)bh * NN + seq + r) * DD + dd] = __float2bfloat16(acc[i][j][r]);
                } else {
                    union { unsigned long long u; unsigned short s[4]; } pk;
                    #pragma unroll
                    for (int r = 0; r < 4; ++r) pk.s[r] = bf16_bits(acc[i][j][r]);
                    *(unsigned long long*)&vtb[((long)bh * DD + dd) * NN + seq] = pk.u;
                }
            } else { // EPI_OUT
                #pragma unroll
                for (int r = 0; r < 4; ++r) {
                    int row = rowb + r;
                    C[(long)row * N + col] = acc[i][j][r] + bias[col] + resid[(long)row * N + col];
                }
            }
        }
    }
}

// ---------------------------------------------------------------------------
// Batched bf16 MFMA GEMM for pinv: 32 batches of 256x256x256.
// C[m][n] = scale * sum_k A[m][k]*Bt[n][k].
// Outputs (optional): CnBf = bf16(C) natural; CnF = fp32 C natural;
// CTbf[n][m] = bf16(diag*(m==n) + sgn*C[m][n]).
__launch_bounds__(256)
__global__ void gemm_pinv(const __hip_bfloat16* __restrict__ A,
                          const __hip_bfloat16* __restrict__ Bt,
                          __hip_bfloat16* __restrict__ CnBf,
                          float* __restrict__ CnF,
                          __hip_bfloat16* __restrict__ CTbf,
                          float diag, float sgn, float scale) {
    __shared__ __hip_bfloat16 As[64][64];
    __shared__ __hip_bfloat16 Bs[64][64];
    __shared__ __hip_bfloat16 Tls[64][65];
    const int t = threadIdx.x;
    const long base = (long)blockIdx.z << 16;
    const int m0 = blockIdx.y * 64, n0 = blockIdx.x * 64;
    const int wave = t >> 6, lane = t & 63;
    const int wr = wave >> 1, wc = wave & 1;
    const int lm = lane & 15, quad = lane >> 4;
    const __hip_bfloat16* Ab = A + base;
    const __hip_bfloat16* Bb = Bt + base;

    float4v acc[2][2] = {};

    for (int k0 = 0; k0 < 256; k0 += 64) {
        #pragma unroll
        for (int p = 0; p < 2; ++p) {
            int idx = t + p * 256;
            int r = idx >> 3, c8 = (idx & 7) * 8;
            *(uint4*)&As[r][c8] = *(const uint4*)&Ab[(long)(m0 + r) * 256 + k0 + c8];
            *(uint4*)&Bs[r][c8] = *(const uint4*)&Bb[(long)(n0 + r) * 256 + k0 + c8];
        }
        __syncthreads();
        #pragma unroll
        for (int ks = 0; ks < 64; ks += 32) {
            short8 af[2], bfr[2];
            #pragma unroll
            for (int i = 0; i < 2; ++i) {
                af[i]  = *(const short8*)&As[wr * 32 + i * 16 + lm][ks + quad * 8];
                bfr[i] = *(const short8*)&Bs[wc * 32 + i * 16 + lm][ks + quad * 8];
            }
            #pragma unroll
            for (int i = 0; i < 2; ++i)
                #pragma unroll
                for (int j = 0; j < 2; ++j)
                    acc[i][j] = __builtin_amdgcn_mfma_f32_16x16x32_bf16(af[i], bfr[j], acc[i][j], 0, 0, 0);
        }
        __syncthreads();
    }

    #pragma unroll
    for (int i = 0; i < 2; ++i) {
        #pragma unroll
        for (int j = 0; j < 2; ++j) {
            #pragma unroll
            for (int r = 0; r < 4; ++r) {
                int row = wr * 32 + i * 16 + quad * 4 + r;
                int col = wc * 32 + j * 16 + lm;
                float v = acc[i][j][r] * scale;
                long off = base + (long)(m0 + row) * 256 + n0 + col;
                if (CnBf) CnBf[off] = __float2bfloat16(v);
                if (CnF)  CnF[off]  = v;
                float tv = sgn * v + ((m0 + row) == (n0 + col) ? diag : 0.0f);
                Tls[row][col] = __float2bfloat16(tv);
            }
        }
    }
    __syncthreads();
    if (CTbf) {
        int r = t & 63;
        #pragma unroll
        for (int u = 0; u < 16; ++u) {
            int c = u * 4 + (t >> 6);
            CTbf[base + (long)(n0 + c) * 256 + m0 + r] = Tls[r][c];
        }
    }
}

// ---------------------------------------------------------------------------
// pinv prep: a2_bf = bf16(a2); z0T = bf16(s*a2); z0n = bf16(s*a2^T). grid (4,4,32).
__launch_bounds__(256)
__global__ void pinv_prep(const float* __restrict__ a2, const float* __restrict__ scl,
                          __hip_bfloat16* __restrict__ a2bf, __hip_bfloat16* __restrict__ z0T,
                          __hip_bfloat16* __restrict__ z0n) {
    __shared__ float tl[64][65];
    const int t = threadIdx.x;
    const long base = (long)blockIdx.z << 16;
    const int i0 = blockIdx.y * 64, j0 = blockIdx.x * 64;
    float s = scl[0];
    #pragma unroll
    for (int p = 0; p < 16; ++p) {
        int idx = t + p * 256;
        int r = idx >> 6, c = idx & 63;
        long off = base + (long)(i0 + r) * 256 + j0 + c;
        float v = a2[off];
        a2bf[off] = __float2bfloat16(v);
        float zv = v * s;
        z0T[off] = __float2bfloat16(zv);
        tl[r][c] = zv;
    }
    __syncthreads();
    int r = t & 63;
    #pragma unroll
    for (int u = 0; u < 16; ++u) {
        int c = u * 4 + (t >> 6);
        z0n[base + (long)(j0 + c) * 256 + i0 + r] = __float2bfloat16(tl[r][c]);
    }
}

// ---------------------------------------------------------------------------
// Generic fp32 tiled GEMM (sim2 / wm). 64x64 tile, BK=16.
template<int EPI, bool TRANSB>
__launch_bounds__(256)
__global__ void gemm64(const float* __restrict__ A, const float* __restrict__ Bm,
                       float* __restrict__ C,
                       int M, int N, int K, long sA, long sB, long sC, float alpha) {
    const int bz = blockIdx.z;
    const float* Ab = A + (long)bz * sA;
    const float* Bb = Bm + (long)bz * sB;
    float* Cb = C + (long)bz * sC;

    __shared__ float As[16][64];
    __shared__ float Bs[16][64];

    const int tid = threadIdx.x;
    const int tx = tid & 15;
    const int ty = tid >> 4;
    const int m0 = blockIdx.y * 64;
    const int n0 = blockIdx.x * 64;

    float acc[4][4] = {};

    for (int k0 = 0; k0 < K; k0 += 16) {
        {
            int r  = tid >> 2;
            int kk = (tid & 3) * 4;
            float4 va = *(const float4*)(Ab + (long)(m0 + r) * K + k0 + kk);
            As[kk + 0][r] = va.x; As[kk + 1][r] = va.y; As[kk + 2][r] = va.z; As[kk + 3][r] = va.w;
        }
        if (!TRANSB) {
            int kk = tid >> 4;
            int j  = (tid & 15) * 4;
            float4 vb = *(const float4*)(Bb + (long)(k0 + kk) * N + n0 + j);
            Bs[kk][j + 0] = vb.x; Bs[kk][j + 1] = vb.y; Bs[kk][j + 2] = vb.z; Bs[kk][j + 3] = vb.w;
        } else {
            int j  = tid >> 2;
            int kk = (tid & 3) * 4;
            float4 vb = *(const float4*)(Bb + (long)(n0 + j) * K + k0 + kk);
            Bs[kk + 0][j] = vb.x; Bs[kk + 1][j] = vb.y; Bs[kk + 2][j] = vb.z; Bs[kk + 3][j] = vb.w;
        }
        __syncthreads();
        #pragma unroll
        for (int kk = 0; kk < 16; ++kk) {
            float a0 = As[kk][ty * 4 + 0], a1 = As[kk][ty * 4 + 1];
            float a2 = As[kk][ty * 4 + 2], a3 = As[kk][ty * 4 + 3];
            float b0 = Bs[kk][tx * 4 + 0], b1 = Bs[kk][tx * 4 + 1];
            float b2 = Bs[kk][tx * 4 + 2], b3 = Bs[kk][tx * 4 + 3];
            acc[0][0] += a0 * b0; acc[0][1] += a0 * b1; acc[0][2] += a0 * b2; acc[0][3] += a0 * b3;
            acc[1][0] += a1 * b0; acc[1][1] += a1 * b1; acc[1][2] += a1 * b2; acc[1][3] += a1 * b3;
            acc[2][0] += a2 * b0; acc[2][1] += a2 * b1; acc[2][2] += a2 * b2; acc[2][3] += a2 * b3;
            acc[3][0] += a3 * b0; acc[3][1] += a3 * b1; acc[3][2] += a3 * b2; acc[3][3] += a3 * b3;
        }
        __syncthreads();
    }

    #pragma unroll
    for (int r = 0; r < 4; ++r)
        #pragma unroll
        for (int c = 0; c < 4; ++c)
            Cb[(long)(m0 + ty * 4 + r) * N + n0 + tx * 4 + c] = acc[r][c] * alpha;
}

// ---------------------------------------------------------------------------
// Landmark means from bf16 q/k; writes fp32 (for sim2) and bf16 (for MFMA flash).
__global__ void landmark_kernel(const __hip_bfloat16* __restrict__ qb,
                                const __hip_bfloat16* __restrict__ kb,
                                float* __restrict__ q_l, float* __restrict__ k_l,
                                __hip_bfloat16* __restrict__ q_lb,
                                __hip_bfloat16* __restrict__ k_lb) {
    int bh = blockIdx.x >> 8;
    int m  = blockIdx.x & 255;
    int d  = threadIdx.x;     // 64
    const __hip_bfloat16* src = (blockIdx.y ? kb : qb) + ((long)bh * NN + m * LL) * DD + d;
    float s = 0.f;
    #pragma unroll
    for (int t = 0; t < LL; ++t) s += __bfloat162float(src[(long)t * DD]);
    s *= (1.0f / LL);
    long off = ((long)bh * MM + m) * DD + d;
    if (blockIdx.y) { k_l[off] = s; k_lb[off] = __float2bfloat16(s); }
    else            { q_l[off] = s; q_lb[off] = __float2bfloat16(s); }
}

// ---------------------------------------------------------------------------
__launch_bounds__(256)
__global__ void softmax256_kernel(float* __restrict__ a) {
    long row = blockIdx.x;
    int t = threadIdx.x;
    float* r = a + row * 256;
    float v = r[t];
    __shared__ float red[256];
    red[t] = v;
    __syncthreads();
    for (int off = 128; off > 0; off >>= 1) { if (t < off) red[t] = fmaxf(red[t], red[t + off]); __syncthreads(); }
    float mx = red[0];
    __syncthreads();
    float e = __expf(v - mx);
    red[t] = e;
    __syncthreads();
    for (int off = 128; off > 0; off >>= 1) { if (t < off) red[t] += red[t + off]; __syncthreads(); }
    r[t] = e / red[0];
}

// ---------------------------------------------------------------------------
__launch_bounds__(256)
__global__ void redmax_kernel(const float* __restrict__ a2, float* __restrict__ red) {
    int bh = blockIdx.x;
    int t = threadIdx.x;
    const float* Ab = a2 + ((long)bh << 16);
    float rs = 0.f, cs = 0.f;
    for (int c = 0; c < 256; ++c) rs += Ab[t * 256 + c];
    for (int r = 0; r < 256; ++r) cs += Ab[r * 256 + t];
    __shared__ float m1[256], m2[256];
    m1[t] = rs; m2[t] = cs;
    __syncthreads();
    for (int off = 128; off > 0; off >>= 1) {
        if (t < off) { m1[t] = fmaxf(m1[t], m1[t + off]); m2[t] = fmaxf(m2[t], m2[t + off]); }
        __syncthreads();
    }
    if (t == 0) { red[bh] = m1[0]; red[32 + bh] = m2[0]; }
}

__global__ void scale_kernel(const float* __restrict__ red, float* __restrict__ scl) {
    __shared__ float a[32], b[32];
    int t = threadIdx.x;  // 32
    a[t] = red[t]; b[t] = red[32 + t];
    __syncthreads();
    for (int off = 16; off > 0; off >>= 1) {
        if (t < off) { a[t] = fmaxf(a[t], a[t + off]); b[t] = fmaxf(b[t], b[t + off]); }
        __syncthreads();
    }
    if (t == 0) scl[0] = 1.0f / (a[0] * b[0]);
}

// ---------------------------------------------------------------------------
// a3v flash MFMA: block = 64 landmark rows x 1024-seq slice (16 chunks of 64).
// No max subtraction (scores sigma~0.25, verified r3-r6). Partials to opart/lpart.
__launch_bounds__(256)
__global__ void a3v_mfma(const __hip_bfloat16* __restrict__ qlb,
                         const __hip_bfloat16* __restrict__ kb,
                         const __hip_bfloat16* __restrict__ vtb,
                         float* __restrict__ opart, float* __restrict__ lpart) {
    const int bh = blockIdx.y;
    const int mt = blockIdx.x >> 2;
    const int ns = blockIdx.x & 3;
    const int t = threadIdx.x;
    const int wave = t >> 6, lane = t & 63;
    const int wr = wave >> 1, wc = wave & 1;
    const int lm = lane & 15, quad = lane >> 4;

    __shared__ __hip_bfloat16 Qs[64][72];
    __shared__ __hip_bfloat16 Ks[64][72];
    __shared__ __hip_bfloat16 Vt[64][72];
    __shared__ __hip_bfloat16 Ps[64][72];
    __shared__ float lred[64][32];

    {
        int r = t >> 3, c8 = (t & 7) * 8;
        const __hip_bfloat16* qbase = qlb + ((long)bh * MM + mt * 64) * DD;
        *(uint4*)&Qs[r][c8]      = *(const uint4*)&qbase[(long)r * DD + c8];
        *(uint4*)&Qs[r + 32][c8] = *(const uint4*)&qbase[(long)(r + 32) * DD + c8];
    }

    float4v acc[2][2] = {};
    float lacc[2][4] = {};
    const __hip_bfloat16* kbase = kb + ((long)bh * NN + ns * 1024) * DD;
    const __hip_bfloat16* vbase = vtb + (long)bh * DD * NN + ns * 1024;
    __syncthreads();

    for (int ch = 0; ch < 16; ++ch) {
        {
            int r = t >> 3, c8 = (t & 7) * 8;
            *(uint4*)&Ks[r][c8]      = *(const uint4*)&kbase[(long)(ch * 64 + r) * DD + c8];
            *(uint4*)&Ks[r + 32][c8] = *(const uint4*)&kbase[(long)(ch * 64 + r + 32) * DD + c8];
            *(uint4*)&Vt[r][c8]      = *(const uint4*)&vbase[(long)r * NN + ch * 64 + c8];
            *(uint4*)&Vt[r + 32][c8] = *(const uint4*)&vbase[(long)(r + 32) * NN + ch * 64 + c8];
        }
        __syncthreads();

        float4v s[2][2] = {};
        #pragma unroll
        for (int ks = 0; ks < 64; ks += 32) {
            short8 af[2], bfr[2];
            #pragma unroll
            for (int i = 0; i < 2; ++i) {
                af[i]  = *(const short8*)&Qs[wr * 32 + i * 16 + lm][ks + quad * 8];
                bfr[i] = *(const short8*)&Ks[wc * 32 + i * 16 + lm][ks + quad * 8];
            }
            #pragma unroll
            for (int i = 0; i < 2; ++i)
                #pragma unroll
                for (int j = 0; j < 2; ++j)
                    s[i][j] = __builtin_amdgcn_mfma_f32_16x16x32_bf16(af[i], bfr[j], s[i][j], 0, 0, 0);
        }
        #pragma unroll
        for (int i = 0; i < 2; ++i)
            #pragma unroll
            for (int j = 0; j < 2; ++j)
                #pragma unroll
                for (int r2 = 0; r2 < 4; ++r2) {
                    float e = __expf(s[i][j][r2]);
                    lacc[i][r2] += e;
                    Ps[wr * 32 + i * 16 + quad * 4 + r2][wc * 32 + j * 16 + lm] = __float2bfloat16(e);
                }
        __syncthreads();

        #pragma unroll
        for (int ks = 0; ks < 64; ks += 32) {
            short8 af[2], bfr[2];
            #pragma unroll
            for (int i = 0; i < 2; ++i) {
                af[i]  = *(const short8*)&Ps[wr * 32 + i * 16 + lm][ks + quad * 8];
                bfr[i] = *(const short8*)&Vt[wc * 32 + i * 16 + lm][ks + quad * 8];
            }
            #pragma unroll
            for (int i = 0; i < 2; ++i)
                #pragma unroll
                for (int j = 0; j < 2; ++j)
                    acc[i][j] = __builtin_amdgcn_mfma_f32_16x16x32_bf16(af[i], bfr[j], acc[i][j], 0, 0, 0);
        }
        __syncthreads();
    }

    #pragma unroll
    for (int i = 0; i < 2; ++i)
        #pragma unroll
        for (int r2 = 0; r2 < 4; ++r2)
            lred[wr * 32 + i * 16 + quad * 4 + r2][wc * 16 + lm] = lacc[i][r2];
    __syncthreads();
    if (t < 64) {
        float s = 0.f;
        #pragma unroll
        for (int u = 0; u < 32; ++u) s += lred[t][u];
        lpart[((bh * 4 + mt) * 4 + ns) * 64 + t] = s;
    }
    const long pbase = ((long)((bh * 4 + mt) * 4 + ns)) << 12;
    #pragma unroll
    for (int i = 0; i < 2; ++i)
        #pragma unroll
        for (int j = 0; j < 2; ++j)
            #pragma unroll
            for (int r2 = 0; r2 < 4; ++r2)
                opart[pbase + (long)(wr * 32 + i * 16 + quad * 4 + r2) * 64 + wc * 32 + j * 16 + lm] = acc[i][j][r2];
}

// stage 2: combine 4 n-split partials
__global__ void a3v_combine(const float* __restrict__ opart, const float* __restrict__ lpart,
                            float* __restrict__ a3v) {
    int idx = blockIdx.x * 256 + threadIdx.x;
    int d  = idx & 63;
    int m  = (idx >> 6) & 255;
    int bh = idx >> 14;
    int mt = m >> 6, r = m & 63;
    int pb = (bh * 4 + mt) * 4;
    float osum = 0.f, lsum = 0.f;
    #pragma unroll
    for (int ns = 0; ns < 4; ++ns) {
        osum += opart[(((long)(pb + ns)) << 12) + r * 64 + d];
        lsum += lpart[(pb + ns) * 64 + r];
    }
    a3v[((long)bh * MM + m) * DD + d] = osum / lsum;
}

// ---------------------------------------------------------------------------
// wm transpose -> bf16: wtb[bh][dd][m] = bf16(wm[bh][m][dd]). One block per bh.
__launch_bounds__(256)
__global__ void wmT_kernel(const float* __restrict__ wm, __hip_bfloat16* __restrict__ wtb) {
    __shared__ float tile[64][65];
    const int bh = blockIdx.x;
    const int t = threadIdx.x;
    for (int mc = 0; mc < 4; ++mc) {
        #pragma unroll
        for (int p = 0; p < 16; ++p) {
            int idx = t + p * 256;
            int r = idx >> 6, c = idx & 63;
            tile[r][c] = wm[((long)bh * MM + mc * 64 + r) * DD + c];
        }
        __syncthreads();
        #pragma unroll
        for (int p = 0; p < 16; ++p) {
            int idx = t + p * 256;
            int dd = idx >> 6, m = idx & 63;
            wtb[((long)bh * DD + dd) * MM + mc * 64 + m] = __float2bfloat16(tile[m][dd]);
        }
        __syncthreads();
    }
}

// ---------------------------------------------------------------------------
// attn_out flash MFMA: block = 64 seq rows x full 256 landmarks (4 chunks).
__launch_bounds__(256)
__global__ void attn_out_mfma(const __hip_bfloat16* __restrict__ qb,
                              const __hip_bfloat16* __restrict__ klb,
                              const __hip_bfloat16* __restrict__ wtb,
                              __hip_bfloat16* __restrict__ ctx) {
    const int bh = blockIdx.y;
    const int b = bh >> 3, h = bh & 7;
    const int i0 = blockIdx.x * 64;
    const int t = threadIdx.x;
    const int wave = t >> 6, lane = t & 63;
    const int wr = wave >> 1, wc = wave & 1;
    const int lm = lane & 15, quad = lane >> 4;

    __shared__ __hip_bfloat16 Qs[64][72];
    __shared__ __hip_bfloat16 Ks[64][72];
    __shared__ __hip_bfloat16 Wt[64][72];
    __shared__ __hip_bfloat16 Ps[64][72];
    __shared__ float lred[64][32];
    __shared__ float dsum[64];

    {
        int r = t >> 3, c8 = (t & 7) * 8;
        const __hip_bfloat16* qbase = qb + ((long)bh * NN + i0) * DD;
        *(uint4*)&Qs[r][c8]      = *(const uint4*)&qbase[(long)r * DD + c8];
        *(uint4*)&Qs[r + 32][c8] = *(const uint4*)&qbase[(long)(r + 32) * DD + c8];
    }

    float4v acc[2][2] = {};
    float lacc[2][4] = {};
    const __hip_bfloat16* klbase = klb + (long)bh * MM * DD;
    const __hip_bfloat16* wbase  = wtb + (long)bh * DD * MM;
    __syncthreads();

    for (int ch = 0; ch < 4; ++ch) {
        {
            int r = t >> 3, c8 = (t & 7) * 8;
            *(uint4*)&Ks[r][c8]      = *(const uint4*)&klbase[(long)(ch * 64 + r) * DD + c8];
            *(uint4*)&Ks[r + 32][c8] = *(const uint4*)&klbase[(long)(ch * 64 + r + 32) * DD + c8];
            *(uint4*)&Wt[r][c8]      = *(const uint4*)&wbase[(long)r * MM + ch * 64 + c8];
            *(uint4*)&Wt[r + 32][c8] = *(const uint4*)&wbase[(long)(r + 32) * MM + ch * 64 + c8];
        }
        __syncthreads();

        float4v s[2][2] = {};
        #pragma unroll
        for (int ks = 0; ks < 64; ks += 32) {
            short8 af[2], bfr[2];
            #pragma unroll
            for (int i = 0; i < 2; ++i) {
                af[i]  = *(const short8*)&Qs[wr * 32 + i * 16 + lm][ks + quad * 8];
                bfr[i] = *(const short8*)&Ks[wc * 32 + i * 16 + lm][ks + quad * 8];
            }
            #pragma unroll
            for (int i = 0; i < 2; ++i)
                #pragma unroll
                for (int j = 0; j < 2; ++j)
                    s[i][j] = __builtin_amdgcn_mfma_f32_16x16x32_bf16(af[i], bfr[j], s[i][j], 0, 0, 0);
        }
        #pragma unroll
        for (int i = 0; i < 2; ++i)
            #pragma unroll
            for (int j = 0; j < 2; ++j)
                #pragma unroll
                for (int r2 = 0; r2 < 4; ++r2) {
                    float e = __expf(s[i][j][r2]);
                    lacc[i][r2] += e;
                    Ps[wr * 32 + i * 16 + quad * 4 + r2][wc * 32 + j * 16 + lm] = __float2bfloat16(e);
                }
        __syncthreads();

        #pragma unroll
        for (int ks = 0; ks < 64; ks += 32) {
            short8 af[2], bfr[2];
            #pragma unroll
            for (int i = 0; i < 2; ++i) {
                af[i]  = *(const short8*)&Ps[wr * 32 + i * 16 + lm][ks + quad * 8];
                bfr[i] = *(const short8*)&Wt[wc * 32 + i * 16 + lm][ks + quad * 8];
            }
            #pragma unroll
            for (int i = 0; i < 2; ++i)
                #pragma unroll
                for (int j = 0; j < 2; ++j)
                    acc[i][j] = __builtin_amdgcn_mfma_f32_16x16x32_bf16(af[i], bfr[j], acc[i][j], 0, 0, 0);
        }
        __syncthreads();
    }

    #pragma unroll
    for (int i = 0; i < 2; ++i)
        #pragma unroll
        for (int r2 = 0; r2 < 4; ++r2)
            lred[wr * 32 + i * 16 + quad * 4 + r2][wc * 16 + lm] = lacc[i][r2];
    __syncthreads();
    if (t < 64) {
        float s = 0.f;
        #pragma unroll
        for (int u = 0; u < 32; ++u) s += lred[t][u];
        dsum[t] = 1.0f / s;
    }
    __syncthreads();

    #pragma unroll
    for (int i = 0; i < 2; ++i)
        #pragma unroll
        for (int j = 0; j < 2; ++j)
            #pragma unroll
            for (int r2 = 0; r2 < 4; ++r2) {
                int row = wr * 32 + i * 16 + quad * 4 + r2;
                int col = wc * 32 + j * 16 + lm;
                ctx[((long)b * NN + i0 + row) * DIMM + h * DD + col] =
                    __float2bfloat16(acc[i][j][r2] * dsum[row]);
            }
}

// ---------------------------------------------------------------------------
// Depthwise 33-tap seq conv on vt (bf16, [bh][dd][seq]), added into bf16 ctx.
// vs rows padded to 290 shorts (145 words, odd) -> 2-way LDS reads (free).
__launch_bounds__(256)
__global__ void conv_kernel(const __hip_bfloat16* __restrict__ vtb,
                            const float* __restrict__ convw,
                            __hip_bfloat16* __restrict__ ctx) {
    __shared__ __hip_bfloat16 vs[64][290];
    __shared__ float cw[KS];
    const int bh = blockIdx.y;
    const int b = bh >> 3, h = bh & 7;
    const int s0 = blockIdx.x * 256;
    const int t = threadIdx.x;
    if (t < KS) cw[t] = convw[h * KS + t];
    {
        int rowsel = t >> 3, inner = t & 7;
        #pragma unroll
        for (int p = 0; p < 2; ++p) {
            int dd = rowsel + 32 * p;
            const __hip_bfloat16* vrow = vtb + ((long)bh * DD + dd) * NN;
            for (int u = inner; u < 36; u += 8) {
                int g0 = s0 - 16 + u * 8;
                __align__(16) __hip_bfloat16 tmp[8];
                if (g0 >= 0 && g0 + 8 <= NN) {
                    *(uint4*)tmp = *(const uint4*)&vrow[g0];
                } else {
                    #pragma unroll
                    for (int e = 0; e < 8; ++e) {
                        int g = g0 + e;
                        tmp[e] = (g >= 0 && g < NN) ? vrow[g] : __float2bfloat16(0.f);
                    }
                }
                #pragma unroll
                for (int q = 0; q < 4; ++q)
                    *(unsigned int*)&vs[dd][u * 8 + q * 2] = *(unsigned int*)&tmp[q * 2];
            }
        }
    }
    __syncthreads();
    const int dd = t & 63, sub = t >> 6;
    __hip_bfloat16* cb = ctx + ((long)b * NN + s0) * DIMM + h * DD + dd;
    for (int u = 0; u < 64; ++u) {
        int p = sub * 64 + u;
        float o = 0.f;
        #pragma unroll
        for (int k = 0; k < KS; ++k) o += cw[k] * __bfloat162float(vs[dd][p + k]);
        long off = (long)p * DIMM;
        cb[off] = __float2bfloat16(__bfloat162float(cb[off]) + o);
    }
}

// ---------------------------------------------------------------------------
extern "C" void kernel_launch(void* const* d_in, const int* in_sizes, int n_in,
                              void* d_out, int out_size, void* d_ws, size_t ws_size,
                              hipStream_t stream) {
    const float* x      = (const float*)d_in[0];
    const float* norm_w = (const float*)d_in[1];
    const float* norm_b = (const float*)d_in[2];
    const float* Wqkv   = (const float*)d_in[3];
    const float* Wout   = (const float*)d_in[4];
    const float* bout   = (const float*)d_in[5];
    const float* conv_w = (const float*)d_in[6];
    float* out = (float*)d_out;

    float* ws = (float*)d_ws;
    size_t o = 0;
    auto alloc = [&](size_t n) { float* p = ws + o; o += n; return p; };
    auto allocb = [&](size_t n) { return (__hip_bfloat16*)alloc((n + 1) / 2); };

    __hip_bfloat16* xn_bf  = allocb((size_t)NROW * DIMM);
    __hip_bfloat16* wqt_bf = allocb((size_t)3 * DIMM * DIMM);
    __hip_bfloat16* wot_bf = allocb((size_t)DIMM * DIMM);
    __hip_bfloat16* ctx_bf = allocb((size_t)NROW * DIMM);
    __hip_bfloat16* q_bf   = allocb((size_t)BHH * NN * DD);
    __hip_bfloat16* k_bf   = allocb((size_t)BHH * NN * DD);
    __hip_bfloat16* vt_bf  = allocb((size_t)BHH * DD * NN);
    __hip_bfloat16* qlb    = allocb((size_t)BHH * MM * DD);
    __hip_bfloat16* klb    = allocb((size_t)BHH * MM * DD);
    __hip_bfloat16* wt_bf  = allocb((size_t)BHH * DD * MM);
    float* q_l  = alloc((size_t)BHH * MM * DD);
    float* k_l  = alloc((size_t)BHH * MM * DD);
    float* a2   = alloc((size_t)BHH * MM * MM);
    float* zb   = alloc((size_t)BHH * MM * MM);
    float* az   = alloc((size_t)BHH * MM * MM);
    float* gb   = alloc((size_t)BHH * MM * MM);
    float* tb   = alloc((size_t)BHH * MM * MM);
    float* z2   = alloc((size_t)BHH * MM * MM);
    float* a3v  = alloc((size_t)BHH * MM * DD);
    float* wm   = alloc((size_t)BHH * MM * DD);
    float* opart = alloc((size_t)BHH * 4 * 4 * 64 * 64);
    float* lpart = alloc((size_t)BHH * 4 * 4 * 64);
    float* red  = alloc(64);
    float* scl  = alloc(64);

    // bf16 pinv buffers aliased onto fp32 buffers dead during the bf16 phase.
    const size_t HB = 1048576;
    __hip_bfloat16* a2bf = (__hip_bfloat16*)az;
    __hip_bfloat16* znA  = (__hip_bfloat16*)(az + HB);
    __hip_bfloat16* znB  = (__hip_bfloat16*)gb;
    __hip_bfloat16* zTA  = (__hip_bfloat16*)(gb + HB);
    __hip_bfloat16* zTB  = (__hip_bfloat16*)tb;
    __hip_bfloat16* azbf = (__hip_bfloat16*)(tb + HB);
    __hip_bfloat16* g1T  = (__hip_bfloat16*)z2;
    __hip_bfloat16* g2T  = (__hip_bfloat16*)(z2 + HB);
    __hip_bfloat16* g3T  = (__hip_bfloat16*)opart;   // dead until a3v

    // 1. LayerNorm -> bf16
    ln_kernel<<<NROW, 256, 0, stream>>>(x, norm_w, norm_b, xn_bf);

    // 1b. transpose+convert weights
    transpose_bf16<<<dim3(3 * DIMM / 32, DIMM / 32), 256, 0, stream>>>(Wqkv, wqt_bf, DIMM, 3 * DIMM);
    transpose_bf16<<<dim3(DIMM / 32, DIMM / 32), 256, 0, stream>>>(Wout, wot_bf, DIMM, DIMM);

    // 2. QKV GEMM (MFMA): q,k bf16 natural; v transposed bf16
    gemm_mfma<EPI_QKV><<<dim3(3 * DIMM / 128, NROW / 128), 256, 0, stream>>>(
        xn_bf, wqt_bf, nullptr, NROW, 3 * DIMM, DIMM,
        nullptr, nullptr, q_bf, k_bf, vt_bf);

    // 3. Landmarks (fp32 + bf16)
    landmark_kernel<<<dim3(BHH * MM, 2), 64, 0, stream>>>(q_bf, k_bf, q_l, k_l, qlb, klb);

    // 4. sim2 = q_l @ k_l^T (fp32)
    gemm64<EPI_NONE, true><<<dim3(4, 4, BHH), 256, 0, stream>>>(
        q_l, k_l, a2, MM, MM, DD, (long)MM * DD, (long)MM * DD, (long)MM * MM, 1.0f);

    // 5. softmax rows -> a2
    softmax256_kernel<<<BHH * MM, 256, 0, stream>>>(a2);

    // 6-7. pinv normalization scalar
    redmax_kernel<<<BHH, 256, 0, stream>>>(a2, red);
    scale_kernel<<<1, 32, 0, stream>>>(red, scl);

    // 8. pinv prep
    dim3 g512(4, 4, BHH);
    pinv_prep<<<g512, 256, 0, stream>>>(a2, scl, a2bf, zTA, znA);

    // 9. Newton-Schulz: all 6 iterations bf16 MFMA; final gemm emits fp32 zb
    __hip_bfloat16 *zn = znA, *zT = zTA, *zn2 = znB, *zT2 = zTB;
    for (int it = 0; it < 6; ++it) {
        gemm_pinv<<<g512, 256, 0, stream>>>(a2bf, zT, azbf, nullptr, g1T, 7.0f, -1.0f, 1.0f);
        gemm_pinv<<<g512, 256, 0, stream>>>(azbf, g1T, nullptr, nullptr, g2T, 15.0f, -1.0f, 1.0f);
        gemm_pinv<<<g512, 256, 0, stream>>>(azbf, g2T, nullptr, nullptr, g3T, 13.0f, -1.0f, 1.0f);
        gemm_pinv<<<g512, 256, 0, stream>>>(zn, g3T, zn2, (it == 5) ? zb : nullptr, zT2,
                                            0.0f, 1.0f, 0.25f);
        __hip_bfloat16* tmp;
        tmp = zn; zn = zn2; zn2 = tmp;
        tmp = zT; zT = zT2; zT2 = tmp;
    }
    // zb = a2_inv (fp32)

    // 10. a3v = softmax(q_l . k^T) @ v   (MFMA flash)
    a3v_mfma<<<dim3(16, BHH), 256, 0, stream>>>(qlb, k_bf, vt_bf, opart, lpart);
    a3v_combine<<<BHH * MM * DD / 256, 256, 0, stream>>>(opart, lpart, a3v);

    // 11. wm = a2_inv @ a3v (fp32), then transpose -> bf16
    gemm64<EPI_NONE, false><<<dim3(1, 4, BHH), 256, 0, stream>>>(
        zb, a3v, wm, MM, DD, MM, (long)MM * MM, (long)MM * DD, (long)MM * DD, 1.0f);
    wmT_kernel<<<BHH, 256, 0, stream>>>(wm, wt_bf);

    // 12. attention out (MFMA flash) -> bf16 ctx
    attn_out_mfma<<<dim3(NN / 64, BHH), 256, 0, stream>>>(q_bf, klb, wt_bf, ctx_bf);

    // 12b. depthwise conv added into ctx
    conv_kernel<<<dim3(NN / 256, BHH), 256, 0, stream>>>(vt_bf, conv_w, ctx_bf);

    // 13. final: out = x + ctx @ Wout + bout  (MFMA)
    gemm_mfma<EPI_OUT><<<dim3(DIMM / 128, NROW / 128), 256, 0, stream>>>(
        ctx_bf, wot_bf, out, NROW, DIMM, DIMM,
        bout, x, nullptr, nullptr, nullptr);
}

// Round 8
// 512.038 us; speedup vs baseline: 10.5737x; 1.1166x over previous
//
#include <hip/hip_runtime.h>
#include <hip/hip_bf16.h>

// Problem constants
#define BB 4
#define NN 4096
#define DIMM 512
#define HH 8
#define DD 64
#define MM 256
#define LL 16
#define BHH 32
#define NROW (BB*NN)      // 16384
#define KS 33

typedef __attribute__((ext_vector_type(8))) short short8;   // 8 bf16 = 4 VGPR
typedef __attribute__((ext_vector_type(4))) float float4v;  // MFMA C/D

static __device__ __forceinline__ unsigned short bf16_bits(float v) {
    __hip_bfloat16 h = __float2bfloat16(v);
    return *reinterpret_cast<unsigned short*>(&h);
}

// async global->LDS 16B per lane; lds base must be wave-uniform (lane i lands at +16*i)
static __device__ __forceinline__ void gl_lds16(const void* g, void* l) {
    __builtin_amdgcn_global_load_lds((const __attribute__((address_space(1))) void*)g,
                                     (__attribute__((address_space(3))) void*)l, 16, 0, 0);
}

// ---------------------------------------------------------------------------
// LayerNorm: one block per row of [16384, 512] -> bf16 output
__launch_bounds__(256)
__global__ void ln_kernel(const float* __restrict__ x,
                          const float* __restrict__ w,
                          const float* __restrict__ bvec,
                          __hip_bfloat16* __restrict__ xn) {
    int row = blockIdx.x;
    int t = threadIdx.x;
    const float* xr = x + (long)row * DIMM;
    float v0 = xr[t];
    float v1 = xr[t + 256];
    __shared__ float red[256];
    red[t] = v0 + v1;
    __syncthreads();
    for (int off = 128; off > 0; off >>= 1) { if (t < off) red[t] += red[t + off]; __syncthreads(); }
    float mu = red[0] * (1.0f / DIMM);
    __syncthreads();
    float d0 = v0 - mu, d1 = v1 - mu;
    red[t] = d0 * d0 + d1 * d1;
    __syncthreads();
    for (int off = 128; off > 0; off >>= 1) { if (t < off) red[t] += red[t + off]; __syncthreads(); }
    float var = red[0] * (1.0f / DIMM);
    float rs = rsqrtf(var + 1e-5f);
    xn[(long)row * DIMM + t]       = __float2bfloat16(d0 * rs * w[t]       + bvec[t]);
    xn[(long)row * DIMM + t + 256] = __float2bfloat16(d1 * rs * w[t + 256] + bvec[t + 256]);
}

// ---------------------------------------------------------------------------
// Transpose + fp32->bf16: out[N][K] = bf16(in[K][N])
__launch_bounds__(256)
__global__ void transpose_bf16(const float* __restrict__ in, __hip_bfloat16* __restrict__ outp,
                               int K, int N) {
    __shared__ float tile[32][33];
    int k0 = blockIdx.y * 32, n0 = blockIdx.x * 32;
    int tx = threadIdx.x & 31, ty = threadIdx.x >> 5;  // ty 0..7
    #pragma unroll
    for (int i = 0; i < 32; i += 8)
        tile[ty + i][tx] = in[(long)(k0 + ty + i) * N + n0 + tx];
    __syncthreads();
    #pragma unroll
    for (int i = 0; i < 32; i += 8)
        outp[(long)(n0 + ty + i) * K + k0 + tx] = __float2bfloat16(tile[tx][ty + i]);
}

// ---------------------------------------------------------------------------
// bf16 MFMA GEMM: C[M,N] = A[M,K]bf16 @ Bt[N,K]bf16^T.
// 128x128 tile, BK=64, 256 threads = 4 waves (2x2), 4x4 16x16x32 frags/wave.
// Staging via global_load_lds (16B/lane, lane-linear LDS mapping).
enum { EPI_NONE = 0, EPI_QKV = 1, EPI_OUT = 2 };

template<int EPI>
__launch_bounds__(256)
__global__ void gemm_mfma(const __hip_bfloat16* __restrict__ A,
                          const __hip_bfloat16* __restrict__ Bt,
                          float* __restrict__ C, int M, int N, int K,
                          const float* __restrict__ bias,
                          const float* __restrict__ resid,
                          __hip_bfloat16* __restrict__ qb,
                          __hip_bfloat16* __restrict__ kb,
                          __hip_bfloat16* __restrict__ vtb) {
    __shared__ __hip_bfloat16 As[128][64];
    __shared__ __hip_bfloat16 Bs[128][64];
    const int t = threadIdx.x;
    const int m0 = blockIdx.y * 128, n0 = blockIdx.x * 128;
    const int wave = t >> 6, lane = t & 63;
    const int wrow = wave >> 1, wcol = wave & 1;
    const int lm = lane & 15, quad = lane >> 4;
    const int wbase = wave * 64;   // wave's chunk base within a 256-chunk group

    float4v acc[4][4] = {};

    for (int k0 = 0; k0 < K; k0 += 64) {
        #pragma unroll
        for (int p = 0; p < 4; ++p) {
            int idx = t + p * 256;
            int r = idx >> 3, c8 = (idx & 7) * 8;
            int cb = (p * 256 + wbase) * 8;   // wave-uniform LDS element base
            gl_lds16(&A[(long)(m0 + r) * K + k0 + c8], &As[0][0] + cb);
            gl_lds16(&Bt[(long)(n0 + r) * K + k0 + c8], &Bs[0][0] + cb);
        }
        __syncthreads();
        #pragma unroll
        for (int ks = 0; ks < 64; ks += 32) {
            short8 af[4], bfr[4];
            #pragma unroll
            for (int i = 0; i < 4; ++i) {
                af[i]  = *(const short8*)&As[wrow * 64 + i * 16 + lm][ks + quad * 8];
                bfr[i] = *(const short8*)&Bs[wcol * 64 + i * 16 + lm][ks + quad * 8];
            }
            #pragma unroll
            for (int i = 0; i < 4; ++i)
                #pragma unroll
                for (int j = 0; j < 4; ++j)
                    acc[i][j] = __builtin_amdgcn_mfma_f32_16x16x32_bf16(af[i], bfr[j], acc[i][j], 0, 0, 0);
        }
        __syncthreads();
    }

    #pragma unroll
    for (int i = 0; i < 4; ++i) {
        #pragma unroll
        for (int j = 0; j < 4; ++j) {
            int rowb = m0 + wrow * 64 + i * 16 + quad * 4;
            int col  = n0 + wcol * 64 + j * 16 + lm;
            if (EPI == EPI_QKV) {
                int b = rowb >> 12, seq = rowb & (NN - 1);
                int which = col >> 9, rem = col & 511;
                int h = rem >> 6, dd = rem & 63;
                int bh = b * HH + h;
                if (which == 0) {
                    #pragma unroll
                    for (int r = 0; r < 4; ++r)
                        qb[((long)bh * NN + seq + r) * DD + dd] = __float2bfloat16(acc[i][j][r] * 0.125f);
                } else if (which == 1) {
                    #pragma unroll
                    for (int r = 0; r < 4; ++r)
                        kb[((long)bh * NN + seq + r) * DD + dd] = __float2bfloat16(acc[i][j][r]);
                } else {
                    union { unsigned long long u; unsigned short s[4]; } pk;
                    #pragma unroll
                    for (int r = 0; r < 4; ++r) pk.s[r] = bf16_bits(acc[i][j][r]);
                    *(unsigned long long*)&vtb[((long)bh * DD + dd) * NN + seq] = pk.u;
                }
            } else { // EPI_OUT
                #pragma unroll
                for (int r = 0; r < 4; ++r) {
                    int row = rowb + r;
                    C[(long)row * N + col] = acc[i][j][r] + bias[col] + resid[(long)row * N + col];
                }
            }
        }
    }
}

// ---------------------------------------------------------------------------
// Batched bf16 MFMA GEMM for pinv: 32 batches of 256x256x256.
__launch_bounds__(256)
__global__ void gemm_pinv(const __hip_bfloat16* __restrict__ A,
                          const __hip_bfloat16* __restrict__ Bt,
                          __hip_bfloat16* __restrict__ CnBf,
                          float* __restrict__ CnF,
                          __hip_bfloat16* __restrict__ CTbf,
                          float diag, float sgn, float scale) {
    __shared__ __hip_bfloat16 As[64][64];
    __shared__ __hip_bfloat16 Bs[64][64];
    __shared__ __hip_bfloat16 Tls[64][65];
    const int t = threadIdx.x;
    const long base = (long)blockIdx.z << 16;
    const int m0 = blockIdx.y * 64, n0 = blockIdx.x * 64;
    const int wave = t >> 6, lane = t & 63;
    const int wr = wave >> 1, wc = wave & 1;
    const int lm = lane & 15, quad = lane >> 4;
    const int wbase = wave * 64;
    const __hip_bfloat16* Ab = A + base;
    const __hip_bfloat16* Bb = Bt + base;

    float4v acc[2][2] = {};

    for (int k0 = 0; k0 < 256; k0 += 64) {
        #pragma unroll
        for (int p = 0; p < 2; ++p) {
            int idx = t + p * 256;
            int r = idx >> 3, c8 = (idx & 7) * 8;
            int cb = (p * 256 + wbase) * 8;
            gl_lds16(&Ab[(long)(m0 + r) * 256 + k0 + c8], &As[0][0] + cb);
            gl_lds16(&Bb[(long)(n0 + r) * 256 + k0 + c8], &Bs[0][0] + cb);
        }
        __syncthreads();
        #pragma unroll
        for (int ks = 0; ks < 64; ks += 32) {
            short8 af[2], bfr[2];
            #pragma unroll
            for (int i = 0; i < 2; ++i) {
                af[i]  = *(const short8*)&As[wr * 32 + i * 16 + lm][ks + quad * 8];
                bfr[i] = *(const short8*)&Bs[wc * 32 + i * 16 + lm][ks + quad * 8];
            }
            #pragma unroll
            for (int i = 0; i < 2; ++i)
                #pragma unroll
                for (int j = 0; j < 2; ++j)
                    acc[i][j] = __builtin_amdgcn_mfma_f32_16x16x32_bf16(af[i], bfr[j], acc[i][j], 0, 0, 0);
        }
        __syncthreads();
    }

    #pragma unroll
    for (int i = 0; i < 2; ++i) {
        #pragma unroll
        for (int j = 0; j < 2; ++j) {
            #pragma unroll
            for (int r = 0; r < 4; ++r) {
                int row = wr * 32 + i * 16 + quad * 4 + r;
                int col = wc * 32 + j * 16 + lm;
                float v = acc[i][j][r] * scale;
                long off = base + (long)(m0 + row) * 256 + n0 + col;
                if (CnBf) CnBf[off] = __float2bfloat16(v);
                if (CnF)  CnF[off]  = v;
                float tv = sgn * v + ((m0 + row) == (n0 + col) ? diag : 0.0f);
                Tls[row][col] = __float2bfloat16(tv);
            }
        }
    }
    __syncthreads();
    if (CTbf) {
        int r = t & 63;
        #pragma unroll
        for (int u = 0; u < 16; ++u) {
            int c = u * 4 + (t >> 6);
            CTbf[base + (long)(n0 + c) * 256 + m0 + r] = Tls[r][c];
        }
    }
}

// ---------------------------------------------------------------------------
// pinv prep: a2_bf = bf16(a2); z0T = bf16(s*a2); z0n = bf16(s*a2^T). grid (4,4,32).
__launch_bounds__(256)
__global__ void pinv_prep(const float* __restrict__ a2, const float* __restrict__ scl,
                          __hip_bfloat16* __restrict__ a2bf, __hip_bfloat16* __restrict__ z0T,
                          __hip_bfloat16* __restrict__ z0n) {
    __shared__ float tl[64][65];
    const int t = threadIdx.x;
    const long base = (long)blockIdx.z << 16;
    const int i0 = blockIdx.y * 64, j0 = blockIdx.x * 64;
    float s = scl[0];
    #pragma unroll
    for (int p = 0; p < 16; ++p) {
        int idx = t + p * 256;
        int r = idx >> 6, c = idx & 63;
        long off = base + (long)(i0 + r) * 256 + j0 + c;
        float v = a2[off];
        a2bf[off] = __float2bfloat16(v);
        float zv = v * s;
        z0T[off] = __float2bfloat16(zv);
        tl[r][c] = zv;
    }
    __syncthreads();
    int r = t & 63;
    #pragma unroll
    for (int u = 0; u < 16; ++u) {
        int c = u * 4 + (t >> 6);
        z0n[base + (long)(j0 + c) * 256 + i0 + r] = __float2bfloat16(tl[r][c]);
    }
}

// ---------------------------------------------------------------------------
// Generic fp32 tiled GEMM (sim2 / wm). 64x64 tile, BK=16.
template<int EPI, bool TRANSB>
__launch_bounds__(256)
__global__ void gemm64(const float* __restrict__ A, const float* __restrict__ Bm,
                       float* __restrict__ C,
                       int M, int N, int K, long sA, long sB, long sC, float alpha) {
    const int bz = blockIdx.z;
    const float* Ab = A + (long)bz * sA;
    const float* Bb = Bm + (long)bz * sB;
    float* Cb = C + (long)bz * sC;

    __shared__ float As[16][64];
    __shared__ float Bs[16][64];

    const int tid = threadIdx.x;
    const int tx = tid & 15;
    const int ty = tid >> 4;
    const int m0 = blockIdx.y * 64;
    const int n0 = blockIdx.x * 64;

    float acc[4][4] = {};

    for (int k0 = 0; k0 < K; k0 += 16) {
        {
            int r  = tid >> 2;
            int kk = (tid & 3) * 4;
            float4 va = *(const float4*)(Ab + (long)(m0 + r) * K + k0 + kk);
            As[kk + 0][r] = va.x; As[kk + 1][r] = va.y; As[kk + 2][r] = va.z; As[kk + 3][r] = va.w;
        }
        if (!TRANSB) {
            int kk = tid >> 4;
            int j  = (tid & 15) * 4;
            float4 vb = *(const float4*)(Bb + (long)(k0 + kk) * N + n0 + j);
            Bs[kk][j + 0] = vb.x; Bs[kk][j + 1] = vb.y; Bs[kk][j + 2] = vb.z; Bs[kk][j + 3] = vb.w;
        } else {
            int j  = tid >> 2;
            int kk = (tid & 3) * 4;
            float4 vb = *(const float4*)(Bb + (long)(n0 + j) * K + k0 + kk);
            Bs[kk + 0][j] = vb.x; Bs[kk + 1][j] = vb.y; Bs[kk + 2][j] = vb.z; Bs[kk + 3][j] = vb.w;
        }
        __syncthreads();
        #pragma unroll
        for (int kk = 0; kk < 16; ++kk) {
            float a0 = As[kk][ty * 4 + 0], a1 = As[kk][ty * 4 + 1];
            float a2 = As[kk][ty * 4 + 2], a3 = As[kk][ty * 4 + 3];
            float b0 = Bs[kk][tx * 4 + 0], b1 = Bs[kk][tx * 4 + 1];
            float b2 = Bs[kk][tx * 4 + 2], b3 = Bs[kk][tx * 4 + 3];
            acc[0][0] += a0 * b0; acc[0][1] += a0 * b1; acc[0][2] += a0 * b2; acc[0][3] += a0 * b3;
            acc[1][0] += a1 * b0; acc[1][1] += a1 * b1; acc[1][2] += a1 * b2; acc[1][3] += a1 * b3;
            acc[2][0] += a2 * b0; acc[2][1] += a2 * b1; acc[2][2] += a2 * b2; acc[2][3] += a2 * b3;
            acc[3][0] += a3 * b0; acc[3][1] += a3 * b1; acc[3][2] += a3 * b2; acc[3][3] += a3 * b3;
        }
        __syncthreads();
    }

    #pragma unroll
    for (int r = 0; r < 4; ++r)
        #pragma unroll
        for (int c = 0; c < 4; ++c)
            Cb[(long)(m0 + ty * 4 + r) * N + n0 + tx * 4 + c] = acc[r][c] * alpha;
}

// ---------------------------------------------------------------------------
// Landmark means from bf16 q/k; writes fp32 (for sim2) and bf16 (for MFMA flash).
__global__ void landmark_kernel(const __hip_bfloat16* __restrict__ qb,
                                const __hip_bfloat16* __restrict__ kb,
                                float* __restrict__ q_l, float* __restrict__ k_l,
                                __hip_bfloat16* __restrict__ q_lb,
                                __hip_bfloat16* __restrict__ k_lb) {
    int bh = blockIdx.x >> 8;
    int m  = blockIdx.x & 255;
    int d  = threadIdx.x;     // 64
    const __hip_bfloat16* src = (blockIdx.y ? kb : qb) + ((long)bh * NN + m * LL) * DD + d;
    float s = 0.f;
    #pragma unroll
    for (int t = 0; t < LL; ++t) s += __bfloat162float(src[(long)t * DD]);
    s *= (1.0f / LL);
    long off = ((long)bh * MM + m) * DD + d;
    if (blockIdx.y) { k_l[off] = s; k_lb[off] = __float2bfloat16(s); }
    else            { q_l[off] = s; q_lb[off] = __float2bfloat16(s); }
}

// ---------------------------------------------------------------------------
__launch_bounds__(256)
__global__ void softmax256_kernel(float* __restrict__ a) {
    long row = blockIdx.x;
    int t = threadIdx.x;
    float* r = a + row * 256;
    float v = r[t];
    __shared__ float red[256];
    red[t] = v;
    __syncthreads();
    for (int off = 128; off > 0; off >>= 1) { if (t < off) red[t] = fmaxf(red[t], red[t + off]); __syncthreads(); }
    float mx = red[0];
    __syncthreads();
    float e = __expf(v - mx);
    red[t] = e;
    __syncthreads();
    for (int off = 128; off > 0; off >>= 1) { if (t < off) red[t] += red[t + off]; __syncthreads(); }
    r[t] = e / red[0];
}

// ---------------------------------------------------------------------------
__launch_bounds__(256)
__global__ void redmax_kernel(const float* __restrict__ a2, float* __restrict__ red) {
    int bh = blockIdx.x;
    int t = threadIdx.x;
    const float* Ab = a2 + ((long)bh << 16);
    float rs = 0.f, cs = 0.f;
    for (int c = 0; c < 256; ++c) rs += Ab[t * 256 + c];
    for (int r = 0; r < 256; ++r) cs += Ab[r * 256 + t];
    __shared__ float m1[256], m2[256];
    m1[t] = rs; m2[t] = cs;
    __syncthreads();
    for (int off = 128; off > 0; off >>= 1) {
        if (t < off) { m1[t] = fmaxf(m1[t], m1[t + off]); m2[t] = fmaxf(m2[t], m2[t + off]); }
        __syncthreads();
    }
    if (t == 0) { red[bh] = m1[0]; red[32 + bh] = m2[0]; }
}

__global__ void scale_kernel(const float* __restrict__ red, float* __restrict__ scl) {
    __shared__ float a[32], b[32];
    int t = threadIdx.x;  // 32
    a[t] = red[t]; b[t] = red[32 + t];
    __syncthreads();
    for (int off = 16; off > 0; off >>= 1) {
        if (t < off) { a[t] = fmaxf(a[t], a[t + off]); b[t] = fmaxf(b[t], b[t + off]); }
        __syncthreads();
    }
    if (t == 0) scl[0] = 1.0f / (a[0] * b[0]);
}

// ---------------------------------------------------------------------------
// a3v flash MFMA: block = 64 landmark rows x 1024-seq slice (16 chunks of 64).
__launch_bounds__(256)
__global__ void a3v_mfma(const __hip_bfloat16* __restrict__ qlb,
                         const __hip_bfloat16* __restrict__ kb,
                         const __hip_bfloat16* __restrict__ vtb,
                         float* __restrict__ opart, float* __restrict__ lpart) {
    const int bh = blockIdx.y;
    const int mt = blockIdx.x >> 2;
    const int ns = blockIdx.x & 3;
    const int t = threadIdx.x;
    const int wave = t >> 6, lane = t & 63;
    const int wr = wave >> 1, wc = wave & 1;
    const int lm = lane & 15, quad = lane >> 4;

    __shared__ __hip_bfloat16 Qs[64][72];
    __shared__ __hip_bfloat16 Ks[64][72];
    __shared__ __hip_bfloat16 Vt[64][72];
    __shared__ __hip_bfloat16 Ps[64][72];
    __shared__ float lred[64][32];

    {
        int r = t >> 3, c8 = (t & 7) * 8;
        const __hip_bfloat16* qbase = qlb + ((long)bh * MM + mt * 64) * DD;
        *(uint4*)&Qs[r][c8]      = *(const uint4*)&qbase[(long)r * DD + c8];
        *(uint4*)&Qs[r + 32][c8] = *(const uint4*)&qbase[(long)(r + 32) * DD + c8];
    }

    float4v acc[2][2] = {};
    float lacc[2][4] = {};
    const __hip_bfloat16* kbase = kb + ((long)bh * NN + ns * 1024) * DD;
    const __hip_bfloat16* vbase = vtb + (long)bh * DD * NN + ns * 1024;
    __syncthreads();

    for (int ch = 0; ch < 16; ++ch) {
        {
            int r = t >> 3, c8 = (t & 7) * 8;
            *(uint4*)&Ks[r][c8]      = *(const uint4*)&kbase[(long)(ch * 64 + r) * DD + c8];
            *(uint4*)&Ks[r + 32][c8] = *(const uint4*)&kbase[(long)(ch * 64 + r + 32) * DD + c8];
            *(uint4*)&Vt[r][c8]      = *(const uint4*)&vbase[(long)r * NN + ch * 64 + c8];
            *(uint4*)&Vt[r + 32][c8] = *(const uint4*)&vbase[(long)(r + 32) * NN + ch * 64 + c8];
        }
        __syncthreads();

        float4v s[2][2] = {};
        #pragma unroll
        for (int ks = 0; ks < 64; ks += 32) {
            short8 af[2], bfr[2];
            #pragma unroll
            for (int i = 0; i < 2; ++i) {
                af[i]  = *(const short8*)&Qs[wr * 32 + i * 16 + lm][ks + quad * 8];
                bfr[i] = *(const short8*)&Ks[wc * 32 + i * 16 + lm][ks + quad * 8];
            }
            #pragma unroll
            for (int i = 0; i < 2; ++i)
                #pragma unroll
                for (int j = 0; j < 2; ++j)
                    s[i][j] = __builtin_amdgcn_mfma_f32_16x16x32_bf16(af[i], bfr[j], s[i][j], 0, 0, 0);
        }
        #pragma unroll
        for (int i = 0; i < 2; ++i)
            #pragma unroll
            for (int j = 0; j < 2; ++j)
                #pragma unroll
                for (int r2 = 0; r2 < 4; ++r2) {
                    float e = __expf(s[i][j][r2]);
                    lacc[i][r2] += e;
                    Ps[wr * 32 + i * 16 + quad * 4 + r2][wc * 32 + j * 16 + lm] = __float2bfloat16(e);
                }
        __syncthreads();

        #pragma unroll
        for (int ks = 0; ks < 64; ks += 32) {
            short8 af[2], bfr[2];
            #pragma unroll
            for (int i = 0; i < 2; ++i) {
                af[i]  = *(const short8*)&Ps[wr * 32 + i * 16 + lm][ks + quad * 8];
                bfr[i] = *(const short8*)&Vt[wc * 32 + i * 16 + lm][ks + quad * 8];
            }
            #pragma unroll
            for (int i = 0; i < 2; ++i)
                #pragma unroll
                for (int j = 0; j < 2; ++j)
                    acc[i][j] = __builtin_amdgcn_mfma_f32_16x16x32_bf16(af[i], bfr[j], acc[i][j], 0, 0, 0);
        }
        __syncthreads();
    }

    #pragma unroll
    for (int i = 0; i < 2; ++i)
        #pragma unroll
        for (int r2 = 0; r2 < 4; ++r2)
            lred[wr * 32 + i * 16 + quad * 4 + r2][wc * 16 + lm] = lacc[i][r2];
    __syncthreads();
    if (t < 64) {
        float s = 0.f;
        #pragma unroll
        for (int u = 0; u < 32; ++u) s += lred[t][u];
        lpart[((bh * 4 + mt) * 4 + ns) * 64 + t] = s;
    }
    const long pbase = ((long)((bh * 4 + mt) * 4 + ns)) << 12;
    #pragma unroll
    for (int i = 0; i < 2; ++i)
        #pragma unroll
        for (int j = 0; j < 2; ++j)
            #pragma unroll
            for (int r2 = 0; r2 < 4; ++r2)
                opart[pbase + (long)(wr * 32 + i * 16 + quad * 4 + r2) * 64 + wc * 32 + j * 16 + lm] = acc[i][j][r2];
}

// stage 2: combine 4 n-split partials
__global__ void a3v_combine(const float* __restrict__ opart, const float* __restrict__ lpart,
                            float* __restrict__ a3v) {
    int idx = blockIdx.x * 256 + threadIdx.x;
    int d  = idx & 63;
    int m  = (idx >> 6) & 255;
    int bh = idx >> 14;
    int mt = m >> 6, r = m & 63;
    int pb = (bh * 4 + mt) * 4;
    float osum = 0.f, lsum = 0.f;
    #pragma unroll
    for (int ns = 0; ns < 4; ++ns) {
        osum += opart[(((long)(pb + ns)) << 12) + r * 64 + d];
        lsum += lpart[(pb + ns) * 64 + r];
    }
    a3v[((long)bh * MM + m) * DD + d] = osum / lsum;
}

// ---------------------------------------------------------------------------
// wm transpose -> bf16: wtb[bh][dd][m] = bf16(wm[bh][m][dd]). One block per bh.
__launch_bounds__(256)
__global__ void wmT_kernel(const float* __restrict__ wm, __hip_bfloat16* __restrict__ wtb) {
    __shared__ float tile[64][65];
    const int bh = blockIdx.x;
    const int t = threadIdx.x;
    for (int mc = 0; mc < 4; ++mc) {
        #pragma unroll
        for (int p = 0; p < 16; ++p) {
            int idx = t + p * 256;
            int r = idx >> 6, c = idx & 63;
            tile[r][c] = wm[((long)bh * MM + mc * 64 + r) * DD + c];
        }
        __syncthreads();
        #pragma unroll
        for (int p = 0; p < 16; ++p) {
            int idx = t + p * 256;
            int dd = idx >> 6, m = idx & 63;
            wtb[((long)bh * DD + dd) * MM + mc * 64 + m] = __float2bfloat16(tile[m][dd]);
        }
        __syncthreads();
    }
}

// ---------------------------------------------------------------------------
// attn_out flash MFMA + fused depthwise conv epilogue (register FIR).
// Block = 64 seq rows x full 256 landmarks (4 chunks); conv tile matches exactly.
__launch_bounds__(256)
__global__ void attn_out_mfma(const __hip_bfloat16* __restrict__ qb,
                              const __hip_bfloat16* __restrict__ klb,
                              const __hip_bfloat16* __restrict__ wtb,
                              const __hip_bfloat16* __restrict__ vtb,
                              const float* __restrict__ convw,
                              __hip_bfloat16* __restrict__ ctx) {
    const int bh = blockIdx.y;
    const int b = bh >> 3, h = bh & 7;
    const int i0 = blockIdx.x * 64;
    const int t = threadIdx.x;
    const int wave = t >> 6, lane = t & 63;
    const int wr = wave >> 1, wc = wave & 1;
    const int lm = lane & 15, quad = lane >> 4;

    __shared__ __hip_bfloat16 Qs[64][72];
    __shared__ __hip_bfloat16 Ks[64][72];
    __shared__ __hip_bfloat16 Wt[64][72];
    __shared__ __hip_bfloat16 Ps[64][72];
    __shared__ __hip_bfloat16 Vc[64][104];   // v window [i0-16, i0+80), stride 104 (16B-aligned rows)
    __shared__ float lred[64][32];
    __shared__ float dsum[64];
    __shared__ float cwS[KS];

    if (t < KS) cwS[t] = convw[h * KS + t];

    {   // stage Q tile
        int r = t >> 3, c8 = (t & 7) * 8;
        const __hip_bfloat16* qbase = qb + ((long)bh * NN + i0) * DD;
        *(uint4*)&Qs[r][c8]      = *(const uint4*)&qbase[(long)r * DD + c8];
        *(uint4*)&Qs[r + 32][c8] = *(const uint4*)&qbase[(long)(r + 32) * DD + c8];
    }
    {   // stage V conv window: 64 dd x 12 chunks of 8 bf16
        for (int c = t; c < 768; c += 256) {
            int dd = c / 12, u = c - dd * 12;
            int g0 = i0 - 16 + u * 8;
            const __hip_bfloat16* vrow = vtb + ((long)bh * DD + dd) * NN;
            __align__(16) __hip_bfloat16 tmp[8];
            if (g0 >= 0 && g0 + 8 <= NN) {
                *(uint4*)tmp = *(const uint4*)&vrow[g0];
            } else {
                #pragma unroll
                for (int e = 0; e < 8; ++e) {
                    int g = g0 + e;
                    tmp[e] = (g >= 0 && g < NN) ? vrow[g] : __float2bfloat16(0.f);
                }
            }
            *(uint4*)&Vc[dd][u * 8] = *(uint4*)tmp;
        }
    }

    float4v acc[2][2] = {};
    float lacc[2][4] = {};
    const __hip_bfloat16* klbase = klb + (long)bh * MM * DD;
    const __hip_bfloat16* wbase  = wtb + (long)bh * DD * MM;
    __syncthreads();

    float cwr[KS];
    #pragma unroll
    for (int k = 0; k < KS; ++k) cwr[k] = cwS[k];

    for (int ch = 0; ch < 4; ++ch) {
        {
            int r = t >> 3, c8 = (t & 7) * 8;
            *(uint4*)&Ks[r][c8]      = *(const uint4*)&klbase[(long)(ch * 64 + r) * DD + c8];
            *(uint4*)&Ks[r + 32][c8] = *(const uint4*)&klbase[(long)(ch * 64 + r + 32) * DD + c8];
            *(uint4*)&Wt[r][c8]      = *(const uint4*)&wbase[(long)r * MM + ch * 64 + c8];
            *(uint4*)&Wt[r + 32][c8] = *(const uint4*)&wbase[(long)(r + 32) * MM + ch * 64 + c8];
        }
        __syncthreads();

        float4v s[2][2] = {};
        #pragma unroll
        for (int ks = 0; ks < 64; ks += 32) {
            short8 af[2], bfr[2];
            #pragma unroll
            for (int i = 0; i < 2; ++i) {
                af[i]  = *(const short8*)&Qs[wr * 32 + i * 16 + lm][ks + quad * 8];
                bfr[i] = *(const short8*)&Ks[wc * 32 + i * 16 + lm][ks + quad * 8];
            }
            #pragma unroll
            for (int i = 0; i < 2; ++i)
                #pragma unroll
                for (int j = 0; j < 2; ++j)
                    s[i][j] = __builtin_amdgcn_mfma_f32_16x16x32_bf16(af[i], bfr[j], s[i][j], 0, 0, 0);
        }
        #pragma unroll
        for (int i = 0; i < 2; ++i)
            #pragma unroll
            for (int j = 0; j < 2; ++j)
                #pragma unroll
                for (int r2 = 0; r2 < 4; ++r2) {
                    float e = __expf(s[i][j][r2]);
                    lacc[i][r2] += e;
                    Ps[wr * 32 + i * 16 + quad * 4 + r2][wc * 32 + j * 16 + lm] = __float2bfloat16(e);
                }
        __syncthreads();

        #pragma unroll
        for (int ks = 0; ks < 64; ks += 32) {
            short8 af[2], bfr[2];
            #pragma unroll
            for (int i = 0; i < 2; ++i) {
                af[i]  = *(const short8*)&Ps[wr * 32 + i * 16 + lm][ks + quad * 8];
                bfr[i] = *(const short8*)&Wt[wc * 32 + i * 16 + lm][ks + quad * 8];
            }
            #pragma unroll
            for (int i = 0; i < 2; ++i)
                #pragma unroll
                for (int j = 0; j < 2; ++j)
                    acc[i][j] = __builtin_amdgcn_mfma_f32_16x16x32_bf16(af[i], bfr[j], acc[i][j], 0, 0, 0);
        }
        __syncthreads();
    }

    #pragma unroll
    for (int i = 0; i < 2; ++i)
        #pragma unroll
        for (int r2 = 0; r2 < 4; ++r2)
            lred[wr * 32 + i * 16 + quad * 4 + r2][wc * 16 + lm] = lacc[i][r2];
    __syncthreads();
    if (t < 64) {
        float s = 0.f;
        #pragma unroll
        for (int u = 0; u < 32; ++u) s += lred[t][u];
        dsum[t] = 1.0f / s;
    }
    __syncthreads();

    // epilogue: normalize + register-FIR depthwise conv + single ctx write
    #pragma unroll
    for (int j = 0; j < 2; ++j) {
        int dd = wc * 32 + j * 16 + lm;
        #pragma unroll
        for (int i = 0; i < 2; ++i) {
            int R = wr * 32 + i * 16 + quad * 4;   // first of 4 consecutive rows
            float X[36];
            #pragma unroll
            for (int u = 0; u < 36; ++u) X[u] = __bfloat162float(Vc[dd][R + u]);
            float co[4] = {};
            #pragma unroll
            for (int k = 0; k < KS; ++k) {
                float c = cwr[k];
                co[0] += c * X[k + 0];
                co[1] += c * X[k + 1];
                co[2] += c * X[k + 2];
                co[3] += c * X[k + 3];
            }
            #pragma unroll
            for (int r2 = 0; r2 < 4; ++r2) {
                int row = R + r2;
                ctx[((long)b * NN + i0 + row) * DIMM + h * DD + dd] =
                    __float2bfloat16(acc[i][j][r2] * dsum[row] + co[r2]);
            }
        }
    }
}

// ---------------------------------------------------------------------------
extern "C" void kernel_launch(void* const* d_in, const int* in_sizes, int n_in,
                              void* d_out, int out_size, void* d_ws, size_t ws_size,
                              hipStream_t stream) {
    const float* x      = (const float*)d_in[0];
    const float* norm_w = (const float*)d_in[1];
    const float* norm_b = (const float*)d_in[2];
    const float* Wqkv   = (const float*)d_in[3];
    const float* Wout   = (const float*)d_in[4];
    const float* bout   = (const float*)d_in[5];
    const float* conv_w = (const float*)d_in[6];
    float* out = (float*)d_out;

    float* ws = (float*)d_ws;
    size_t o = 0;
    auto alloc = [&](size_t n) { float* p = ws + o; o += n; return p; };
    auto allocb = [&](size_t n) { return (__hip_bfloat16*)alloc((n + 1) / 2); };

    __hip_bfloat16* xn_bf  = allocb((size_t)NROW * DIMM);
    __hip_bfloat16* wqt_bf = allocb((size_t)3 * DIMM * DIMM);
    __hip_bfloat16* wot_bf = allocb((size_t)DIMM * DIMM);
    __hip_bfloat16* ctx_bf = allocb((size_t)NROW * DIMM);
    __hip_bfloat16* q_bf   = allocb((size_t)BHH * NN * DD);
    __hip_bfloat16* k_bf   = allocb((size_t)BHH * NN * DD);
    __hip_bfloat16* vt_bf  = allocb((size_t)BHH * DD * NN);
    __hip_bfloat16* qlb    = allocb((size_t)BHH * MM * DD);
    __hip_bfloat16* klb    = allocb((size_t)BHH * MM * DD);
    __hip_bfloat16* wt_bf  = allocb((size_t)BHH * DD * MM);
    float* q_l  = alloc((size_t)BHH * MM * DD);
    float* k_l  = alloc((size_t)BHH * MM * DD);
    float* a2   = alloc((size_t)BHH * MM * MM);
    float* zb   = alloc((size_t)BHH * MM * MM);
    float* az   = alloc((size_t)BHH * MM * MM);
    float* gb   = alloc((size_t)BHH * MM * MM);
    float* tb   = alloc((size_t)BHH * MM * MM);
    float* z2   = alloc((size_t)BHH * MM * MM);
    float* a3v  = alloc((size_t)BHH * MM * DD);
    float* wm   = alloc((size_t)BHH * MM * DD);
    float* opart = alloc((size_t)BHH * 4 * 4 * 64 * 64);
    float* lpart = alloc((size_t)BHH * 4 * 4 * 64);
    float* red  = alloc(64);
    float* scl  = alloc(64);

    // bf16 pinv buffers aliased onto fp32 buffers dead during the bf16 phase.
    const size_t HB = 1048576;
    __hip_bfloat16* a2bf = (__hip_bfloat16*)az;
    __hip_bfloat16* znA  = (__hip_bfloat16*)(az + HB);
    __hip_bfloat16* znB  = (__hip_bfloat16*)gb;
    __hip_bfloat16* zTA  = (__hip_bfloat16*)(gb + HB);
    __hip_bfloat16* zTB  = (__hip_bfloat16*)tb;
    __hip_bfloat16* azbf = (__hip_bfloat16*)(tb + HB);
    __hip_bfloat16* g1T  = (__hip_bfloat16*)z2;
    __hip_bfloat16* g2T  = (__hip_bfloat16*)(z2 + HB);
    __hip_bfloat16* g3T  = (__hip_bfloat16*)opart;   // dead until a3v

    // 1. LayerNorm -> bf16
    ln_kernel<<<NROW, 256, 0, stream>>>(x, norm_w, norm_b, xn_bf);

    // 1b. transpose+convert weights
    transpose_bf16<<<dim3(3 * DIMM / 32, DIMM / 32), 256, 0, stream>>>(Wqkv, wqt_bf, DIMM, 3 * DIMM);
    transpose_bf16<<<dim3(DIMM / 32, DIMM / 32), 256, 0, stream>>>(Wout, wot_bf, DIMM, DIMM);

    // 2. QKV GEMM (MFMA): q,k bf16 natural; v transposed bf16
    gemm_mfma<EPI_QKV><<<dim3(3 * DIMM / 128, NROW / 128), 256, 0, stream>>>(
        xn_bf, wqt_bf, nullptr, NROW, 3 * DIMM, DIMM,
        nullptr, nullptr, q_bf, k_bf, vt_bf);

    // 3. Landmarks (fp32 + bf16)
    landmark_kernel<<<dim3(BHH * MM, 2), 64, 0, stream>>>(q_bf, k_bf, q_l, k_l, qlb, klb);

    // 4. sim2 = q_l @ k_l^T (fp32)
    gemm64<EPI_NONE, true><<<dim3(4, 4, BHH), 256, 0, stream>>>(
        q_l, k_l, a2, MM, MM, DD, (long)MM * DD, (long)MM * DD, (long)MM * MM, 1.0f);

    // 5. softmax rows -> a2
    softmax256_kernel<<<BHH * MM, 256, 0, stream>>>(a2);

    // 6-7. pinv normalization scalar
    redmax_kernel<<<BHH, 256, 0, stream>>>(a2, red);
    scale_kernel<<<1, 32, 0, stream>>>(red, scl);

    // 8. pinv prep
    dim3 g512(4, 4, BHH);
    pinv_prep<<<g512, 256, 0, stream>>>(a2, scl, a2bf, zTA, znA);

    // 9. Newton-Schulz: all 6 iterations bf16 MFMA; final gemm emits fp32 zb
    __hip_bfloat16 *zn = znA, *zT = zTA, *zn2 = znB, *zT2 = zTB;
    for (int it = 0; it < 6; ++it) {
        gemm_pinv<<<g512, 256, 0, stream>>>(a2bf, zT, azbf, nullptr, g1T, 7.0f, -1.0f, 1.0f);
        gemm_pinv<<<g512, 256, 0, stream>>>(azbf, g1T, nullptr, nullptr, g2T, 15.0f, -1.0f, 1.0f);
        gemm_pinv<<<g512, 256, 0, stream>>>(azbf, g2T, nullptr, nullptr, g3T, 13.0f, -1.0f, 1.0f);
        gemm_pinv<<<g512, 256, 0, stream>>>(zn, g3T, zn2, (it == 5) ? zb : nullptr, zT2,
                                            0.0f, 1.0f, 0.25f);
        __hip_bfloat16* tmp;
        tmp = zn; zn = zn2; zn2 = tmp;
        tmp = zT; zT = zT2; zT2 = tmp;
    }
    // zb = a2_inv (fp32)

    // 10. a3v = softmax(q_l . k^T) @ v   (MFMA flash)
    a3v_mfma<<<dim3(16, BHH), 256, 0, stream>>>(qlb, k_bf, vt_bf, opart, lpart);
    a3v_combine<<<BHH * MM * DD / 256, 256, 0, stream>>>(opart, lpart, a3v);

    // 11. wm = a2_inv @ a3v (fp32), then transpose -> bf16
    gemm64<EPI_NONE, false><<<dim3(1, 4, BHH), 256, 0, stream>>>(
        zb, a3v, wm, MM, DD, MM, (long)MM * MM, (long)MM * DD, (long)MM * DD, 1.0f);
    wmT_kernel<<<BHH, 256, 0, stream>>>(wm, wt_bf);

    // 12. attention out + fused depthwise conv -> bf16 ctx
    attn_out_mfma<<<dim3(NN / 64, BHH), 256, 0, stream>>>(
        q_bf, klb, wt_bf, vt_bf, conv_w, ctx_bf);

    // 13. final: out = x + ctx @ Wout + bout  (MFMA)
    gemm_mfma<EPI_OUT><<<dim3(DIMM / 128, NROW / 128), 256, 0, stream>>>(
        ctx_bf, wot_bf, out, NROW, DIMM, DIMM,
        bout, x, nullptr, nullptr, nullptr);
}